// Round 1
// baseline (4620.342 us; speedup 1.0000x reference)
//
#include <hip/hip_runtime.h>
#include <stdint.h>

// PM25 transformer forward, MI355X/gfx950.
// Round 1: correctness-first bf16-MFMA implementation.
//   - residual stream x kept fp32; LN/softmax/head fp32; GEMM inputs bf16.
//   - weights transposed+cast to bf16 W^T[M][K] in ws once per call.
// ws layout (bytes):
//   x      fp32 [36864,384]   @ 0           (56,623,104)
//   h      bf16 [36864,384]   @ 56,623,104  (28,311,552)
//   q      bf16 [36864,384]   @ 84,934,656
//   k      bf16 [36864,384]   @ 113,246,208
//   v      bf16 [36864,384]   @ 141,557,760
//   o      bf16 [36864,384]   @ 169,869,312
//   ffn    bf16 [36864,1536]  aliases q..o region (@84,934,656, 113,246,208 B)
//   wq_t/wk_t/wv_t/wo_t bf16 [6,384,384]  @ 198,180,864 (+1,769,472 each)
//   w1_t   bf16 [6,1536,384]  @ 205,258,752 (7,077,888)
//   w2_t   bf16 [6,384,1536]  @ 212,336,640 (7,077,888)
//   accums fp32 [4]           @ 219,414,528
// total ~219.4 MB.

#define EDIM   384
#define NHEAD  6
#define DHEAD  64
#define NLAYER 6
#define TBLK   36
#define SNUM   210
#define BSZ    1024
#define NTOK   (BSZ*TBLK)

typedef __attribute__((ext_vector_type(8))) short short8;
typedef __attribute__((ext_vector_type(4))) float floatx4;

static __device__ __forceinline__ unsigned short f2bf(float f){
  union { float fv; unsigned int u; } v; v.fv = f;
  unsigned int r = v.u + 0x7FFFu + ((v.u >> 16) & 1u);
  return (unsigned short)(r >> 16);
}
static __device__ __forceinline__ float bf2f(unsigned short u){
  union { unsigned int u; float fv; } v; v.u = ((unsigned int)u) << 16;
  return v.fv;
}

// ---------------- weight transpose + bf16 cast: out[m][k] = bf16(in[k][m]) ----
__global__ __launch_bounds__(256) void wt_transpose(const float* __restrict__ in,
    unsigned short* __restrict__ out, int K, int M){
  __shared__ float tile[32][33];
  const int mat = blockIdx.z;
  const float* src = in + (size_t)mat*K*M;
  unsigned short* dst = out + (size_t)mat*K*M;
  const int m0 = blockIdx.x*32, k0 = blockIdx.y*32;
  const int tx = threadIdx.x, ty = threadIdx.y;
  for(int i=ty;i<32;i+=8) tile[i][tx] = src[(size_t)(k0+i)*M + m0+tx];
  __syncthreads();
  for(int i=ty;i<32;i+=8) dst[(size_t)(m0+i)*K + k0+tx] = f2bf(tile[tx][i]);
}

// ---------------- embedding: x = pm25/500 @ Wp + bp + fire_emb + stat_emb + pe -
__global__ __launch_bounds__(384) void embed_kernel(const int* __restrict__ idx,
    const int* __restrict__ stn_p, const float* __restrict__ Wp,
    const float* __restrict__ bp, const float* __restrict__ stat_emb,
    const float* __restrict__ fire_emb, float* __restrict__ x){
  __shared__ float pm[TBLK*212];   // stride 212 (mult of 4), pad zeros
  __shared__ int fire[TBLK];
  const int b = blockIdx.x, tid = threadIdx.x;
  const int stn = stn_p[0];
  const int* ib = idx + (size_t)b*TBLK*SNUM*2;
  for(int i=tid;i<TBLK*212;i+=384){
    int t = i/212, s = i - t*212;
    pm[i] = (s < SNUM) ? (float)ib[(t*SNUM+s)*2] * (1.f/500.f) : 0.f;
  }
  if(tid < TBLK) fire[tid] = ib[(tid*SNUM+stn)*2+1];
  __syncthreads();
  const int e = tid;
  float acc[TBLK];
  const float basev = bp[e] + stat_emb[(size_t)stn*EDIM+e];
  const float freq = __expf(-(float)(2*(e>>1)) * (9.210340371976184f/384.f));
  #pragma unroll
  for(int t=0;t<TBLK;t++){
    float ang = (float)t * freq;
    float pe = (e & 1) ? __cosf(ang) : __sinf(ang);
    acc[t] = basev + pe + fire_emb[(size_t)fire[t]*EDIM+e];
  }
  for(int sb=0; sb<53; sb++){
    int s = sb*4;
    float w0 = (s+0<SNUM)? Wp[(size_t)(s+0)*EDIM+e] : 0.f;
    float w1 = (s+1<SNUM)? Wp[(size_t)(s+1)*EDIM+e] : 0.f;
    float w2 = (s+2<SNUM)? Wp[(size_t)(s+2)*EDIM+e] : 0.f;
    float w3 = (s+3<SNUM)? Wp[(size_t)(s+3)*EDIM+e] : 0.f;
    #pragma unroll
    for(int t=0;t<TBLK;t++){
      float4 p4 = *(const float4*)&pm[t*212 + s];
      acc[t] = fmaf(p4.x, w0, acc[t]);
      acc[t] = fmaf(p4.y, w1, acc[t]);
      acc[t] = fmaf(p4.z, w2, acc[t]);
      acc[t] = fmaf(p4.w, w3, acc[t]);
    }
  }
  float* xb = x + (size_t)b*TBLK*EDIM;
  #pragma unroll
  for(int t=0;t<TBLK;t++) xb[t*EDIM + e] = acc[t];
}

// ---------------- layernorm fp32 -> bf16, one wave per row --------------------
__global__ __launch_bounds__(256) void ln_bf16(const float* __restrict__ x,
    const float* __restrict__ g, const float* __restrict__ b,
    unsigned short* __restrict__ out){
  const int wave = threadIdx.x >> 6, lane = threadIdx.x & 63;
  const int row = blockIdx.x*4 + wave;
  const float* xr = x + (size_t)row*EDIM;
  float v[6]; float s=0.f, sq=0.f;
  #pragma unroll
  for(int j=0;j<6;j++){ v[j]=xr[j*64+lane]; s+=v[j]; sq+=v[j]*v[j]; }
  #pragma unroll
  for(int m=1;m<64;m<<=1){ s += __shfl_xor(s,m); sq += __shfl_xor(sq,m); }
  const float mean = s*(1.f/384.f);
  const float var  = sq*(1.f/384.f) - mean*mean;
  const float rstd = rsqrtf(var + 1e-5f);
  unsigned short* orow = out + (size_t)row*EDIM;
  #pragma unroll
  for(int j=0;j<6;j++){
    int e = j*64+lane;
    orow[e] = f2bf((v[j]-mean)*rstd*g[e] + b[e]);
  }
}

// ---------------- bf16 MFMA GEMM: C[N,M] = A[N,K] @ Wt[M,K]^T -----------------
// grid (M/128, N/128), block 256 (4 waves, 2x2, each 64x64 via 4x4 MFMA tiles)
template<bool RELU, bool RESID>
__global__ __launch_bounds__(256) void gemm_k(const unsigned short* __restrict__ A,
    const unsigned short* __restrict__ Wt, const float* __restrict__ bias,
    unsigned short* __restrict__ outb, float* __restrict__ resid, int M, int K){
  __shared__ __align__(16) unsigned short As[128*32];
  __shared__ __align__(16) unsigned short Bs[128*32];
  const int tid  = threadIdx.x;
  const int m0   = blockIdx.x * 128;
  const int n0   = blockIdx.y * 128;
  const int wave = tid >> 6, lane = tid & 63;
  const int wr = wave >> 1, wc = wave & 1;
  const int lrow = lane & 15, quad = lane >> 4;
  floatx4 acc[4][4];
  #pragma unroll
  for(int i=0;i<4;i++)
    #pragma unroll
    for(int j=0;j<4;j++) acc[i][j] = (floatx4){0.f,0.f,0.f,0.f};

  for(int kk=0; kk<K; kk+=32){
    __syncthreads();
    #pragma unroll
    for(int p=0;p<2;p++){
      int i = tid + p*256;
      int r = i >> 2, c = (i & 3) * 8;
      *(float4*)(&As[r*32+c]) = *(const float4*)(&A [(size_t)(n0+r)*K + kk + c]);
      *(float4*)(&Bs[r*32+c]) = *(const float4*)(&Wt[(size_t)(m0+r)*K + kk + c]);
    }
    __syncthreads();
    short8 af[4], bfv[4];
    #pragma unroll
    for(int ti=0;ti<4;ti++) af[ti]  = *(const short8*)(&As[(wr*64+ti*16+lrow)*32 + quad*8]);
    #pragma unroll
    for(int tj=0;tj<4;tj++) bfv[tj] = *(const short8*)(&Bs[(wc*64+tj*16+lrow)*32 + quad*8]);
    #pragma unroll
    for(int ti=0;ti<4;ti++)
      #pragma unroll
      for(int tj=0;tj<4;tj++)
        acc[ti][tj] = __builtin_amdgcn_mfma_f32_16x16x32_bf16(af[ti], bfv[tj], acc[ti][tj], 0,0,0);
  }
  // epilogue: C/D layout col=lane&15, row=quad*4+r  (verified m89/m91)
  #pragma unroll
  for(int ti=0;ti<4;ti++){
    #pragma unroll
    for(int r=0;r<4;r++){
      int row = n0 + wr*64 + ti*16 + quad*4 + r;
      #pragma unroll
      for(int tj=0;tj<4;tj++){
        int col = m0 + wc*64 + tj*16 + lrow;
        float val = acc[ti][tj][r];
        if(bias) val += bias[col];
        if(RELU) val = fmaxf(val, 0.f);
        if(RESID) resid[(size_t)row*M + col] += val;
        else      outb [(size_t)row*M + col] = f2bf(val);
      }
    }
  }
}

// ---------------- causal attention, one wave per (batch, head) ----------------
__global__ __launch_bounds__(64) void attn_kernel(const unsigned short* __restrict__ q,
    const unsigned short* __restrict__ k, const unsigned short* __restrict__ v,
    unsigned short* __restrict__ o){
  const int bh = blockIdx.x;
  const int b = bh / NHEAD, h = bh % NHEAD;
  const int lane = threadIdx.x;
  __shared__ float qs[TBLK*64], ks[TBLK*65], vs[TBLK*65], ps[TBLK*64];
  const size_t base = (size_t)b*TBLK*EDIM + h*DHEAD;
  for(int t=0;t<TBLK;t++){
    qs[t*64+lane] = bf2f(q[base + (size_t)t*EDIM + lane]);
    ks[t*65+lane] = bf2f(k[base + (size_t)t*EDIM + lane]);
    vs[t*65+lane] = bf2f(v[base + (size_t)t*EDIM + lane]);
  }
  __syncthreads();
  const float scale = 0.125f;   // 64^-0.5
  for(int t=0;t<TBLK;t++){
    float val;
    const int s = lane;
    if(s <= t){
      float d = 0.f;
      #pragma unroll 16
      for(int dd=0; dd<64; dd++) d = fmaf(qs[t*64+dd], ks[s*65+dd], d);
      val = d * scale;
    } else val = -INFINITY;
    float mx = val;
    #pragma unroll
    for(int m=1;m<64;m<<=1) mx = fmaxf(mx, __shfl_xor(mx,m));
    float p = __expf(val - mx);            // exp(-inf)=0 for masked lanes
    float sum = p;
    #pragma unroll
    for(int m=1;m<64;m<<=1) sum += __shfl_xor(sum,m);
    ps[t*64+lane] = p / sum;
  }
  __syncthreads();
  for(int t=0;t<TBLK;t++){
    float acc = 0.f;
    for(int s=0;s<=t;s++) acc = fmaf(ps[t*64+s], vs[s*65+lane], acc);
    o[base + (size_t)t*EDIM + lane] = f2bf(acc);
  }
}

// ---------------- head: LNf + sigmoid(x@Wh+bh)*500 + loss partials ------------
__global__ __launch_bounds__(256) void head_kernel(const float* __restrict__ x,
    const float* __restrict__ g, const float* __restrict__ b,
    const float* __restrict__ Wh, const float* __restrict__ bh,
    const int* __restrict__ targets, float* __restrict__ out,
    float* __restrict__ accums){
  const int wave = threadIdx.x >> 6, lane = threadIdx.x & 63;
  const int row = blockIdx.x*4 + wave;
  const float* xr = x + (size_t)row*EDIM;
  float v[6]; float s=0.f, sq=0.f;
  #pragma unroll
  for(int j=0;j<6;j++){ v[j]=xr[j*64+lane]; s+=v[j]; sq+=v[j]*v[j]; }
  #pragma unroll
  for(int m=1;m<64;m<<=1){ s += __shfl_xor(s,m); sq += __shfl_xor(sq,m); }
  const float mean = s*(1.f/384.f);
  const float var  = sq*(1.f/384.f) - mean*mean;
  const float rstd = rsqrtf(var + 1e-5f);
  float dot = 0.f;
  #pragma unroll
  for(int j=0;j<6;j++){
    int e = j*64+lane;
    float hh = (v[j]-mean)*rstd*g[e] + b[e];
    dot = fmaf(hh, Wh[e], dot);
  }
  #pragma unroll
  for(int m=1;m<64;m<<=1) dot += __shfl_xor(dot,m);
  __shared__ float part[4][4];
  if(lane == 0){
    float logit = 1.f/(1.f + __expf(-(dot + bh[0])));
    float den = logit * 500.f;
    out[row] = den;
    float tgt = (float)targets[(size_t)row*2];
    float nt  = tgt * (1.f/500.f);
    part[wave][0] = (logit-nt)*(logit-nt);   // mse numerator
    part[wave][1] = (tgt-den)*(tgt-den);     // See
    part[wave][2] = tgt;                     // Sy
    part[wave][3] = tgt*tgt;                 // Syy
  }
  __syncthreads();
  if(threadIdx.x < 4){
    float t0 = part[0][threadIdx.x] + part[1][threadIdx.x]
             + part[2][threadIdx.x] + part[3][threadIdx.x];
    atomicAdd(&accums[threadIdx.x], t0);
  }
}

__global__ void init_acc(float* accums){ if(threadIdx.x < 4) accums[threadIdx.x] = 0.f; }

__global__ void finalize_kernel(const float* __restrict__ acc, float* __restrict__ out){
  const float n = (float)NTOK;
  out[NTOK]   = acc[0] / n;
  float denom = acc[3] - acc[2]*acc[2]/n;
  out[NTOK+1] = 1.f - acc[1]/denom;
}

// =============================================================================
extern "C" void kernel_launch(void* const* d_in, const int* in_sizes, int n_in,
                              void* d_out, int out_size, void* d_ws, size_t ws_size,
                              hipStream_t stream){
  (void)in_sizes; (void)n_in; (void)out_size; (void)ws_size;
  const int*   idx      = (const int*)  d_in[0];
  const int*   targets  = (const int*)  d_in[1];
  const int*   stn_ix   = (const int*)  d_in[3];
  const float* Wp       = (const float*)d_in[4];
  const float* bp       = (const float*)d_in[5];
  const float* stat_emb = (const float*)d_in[6];
  const float* fire_emb = (const float*)d_in[7];
  const float* ln1_g    = (const float*)d_in[8];
  const float* ln1_b    = (const float*)d_in[9];
  const float* Wq       = (const float*)d_in[10];
  const float* Wk       = (const float*)d_in[11];
  const float* Wv       = (const float*)d_in[12];
  const float* Wo       = (const float*)d_in[13];
  const float* bo       = (const float*)d_in[14];
  const float* ln2_g    = (const float*)d_in[15];
  const float* ln2_b    = (const float*)d_in[16];
  const float* W1       = (const float*)d_in[17];
  const float* b1       = (const float*)d_in[18];
  const float* W2       = (const float*)d_in[19];
  const float* b2       = (const float*)d_in[20];
  const float* lnf_g    = (const float*)d_in[21];
  const float* lnf_b    = (const float*)d_in[22];
  const float* Wh       = (const float*)d_in[23];
  const float* bh       = (const float*)d_in[24];
  float* out = (float*)d_out;

  char* ws = (char*)d_ws;
  float*          x    = (float*)         (ws + 0);
  unsigned short* h    = (unsigned short*)(ws + 56623104);
  unsigned short* q    = (unsigned short*)(ws + 84934656);
  unsigned short* kbuf = (unsigned short*)(ws + 113246208);
  unsigned short* vbuf = (unsigned short*)(ws + 141557760);
  unsigned short* obuf = (unsigned short*)(ws + 169869312);
  unsigned short* ffn  = q;   // aliases q..o region after attention is done
  unsigned short* wq_t = (unsigned short*)(ws + 198180864);
  unsigned short* wk_t = (unsigned short*)(ws + 199950336);
  unsigned short* wv_t = (unsigned short*)(ws + 201719808);
  unsigned short* wo_t = (unsigned short*)(ws + 203489280);
  unsigned short* w1_t = (unsigned short*)(ws + 205258752);
  unsigned short* w2_t = (unsigned short*)(ws + 212336640);
  float*          accs = (float*)         (ws + 219414528);

  const dim3 tb(32,8);
  wt_transpose<<<dim3(12,12,6), tb, 0, stream>>>(Wq, wq_t, 384,  384);
  wt_transpose<<<dim3(12,12,6), tb, 0, stream>>>(Wk, wk_t, 384,  384);
  wt_transpose<<<dim3(12,12,6), tb, 0, stream>>>(Wv, wv_t, 384,  384);
  wt_transpose<<<dim3(12,12,6), tb, 0, stream>>>(Wo, wo_t, 384,  384);
  wt_transpose<<<dim3(48,12,6), tb, 0, stream>>>(W1, w1_t, 384, 1536);
  wt_transpose<<<dim3(12,48,6), tb, 0, stream>>>(W2, w2_t, 1536, 384);

  embed_kernel<<<BSZ, 384, 0, stream>>>(idx, stn_ix, Wp, bp, stat_emb, fire_emb, x);

  const dim3 gE(3, 288);    // M=384
  const dim3 gF(12, 288);   // M=1536
  for(int l=0; l<NLAYER; l++){
    ln_bf16<<<NTOK/4, 256, 0, stream>>>(x, ln1_g + l*EDIM, ln1_b + l*EDIM, h);
    gemm_k<false,false><<<gE, 256, 0, stream>>>(h, wq_t + (size_t)l*384*384, nullptr, q,    nullptr, 384, 384);
    gemm_k<false,false><<<gE, 256, 0, stream>>>(h, wk_t + (size_t)l*384*384, nullptr, kbuf, nullptr, 384, 384);
    gemm_k<false,false><<<gE, 256, 0, stream>>>(h, wv_t + (size_t)l*384*384, nullptr, vbuf, nullptr, 384, 384);
    attn_kernel<<<BSZ*NHEAD, 64, 0, stream>>>(q, kbuf, vbuf, obuf);
    gemm_k<false,true ><<<gE, 256, 0, stream>>>(obuf, wo_t + (size_t)l*384*384, bo + l*EDIM, nullptr, x, 384, 384);
    ln_bf16<<<NTOK/4, 256, 0, stream>>>(x, ln2_g + l*EDIM, ln2_b + l*EDIM, h);
    gemm_k<true ,false><<<gF, 256, 0, stream>>>(h,   w1_t + (size_t)l*1536*384, b1 + l*1536, ffn, nullptr, 1536, 384);
    gemm_k<false,true ><<<gE, 256, 0, stream>>>(ffn, w2_t + (size_t)l*1536*384, b2 + l*EDIM, nullptr, x, 384, 1536);
  }

  init_acc<<<1, 64, 0, stream>>>(accs);
  head_kernel<<<NTOK/4, 256, 0, stream>>>(x, lnf_g, lnf_b, Wh, bh, targets, out, accs);
  finalize_kernel<<<1, 1, 0, stream>>>(accs, out);
}

// Round 2
// 3543.034 us; speedup vs baseline: 1.3041x; 1.3041x over previous
//
#include <hip/hip_runtime.h>
#include <stdint.h>

// PM25 transformer forward, MI355X/gfx950. Round 2:
//   - attention: 4 waves/block share one (b,h); K/V register-resident; zero-filled
//     causal P -> branch-free PV; LDS 27 KB.
//   - GEMM: global_load_lds width=16 staging (m97 ladder step); QKV fused (M=1152).
// ws layout (bytes):
//   x      fp32 [36864,384]   @ 0
//   h      bf16 [36864,384]   @ 56,623,104
//   qkv    bf16 [36864,1152]  @ 84,934,656   (q|k|v by 384-col parts)
//   obuf   bf16 [36864,384]   @ 169,869,312
//   ffn    bf16 [36864,1536]  @ 84,934,656   (aliases qkv+obuf after attn+Wo done)
//   wqkv_t bf16 [6,1152,384]  @ 198,180,864
//   wo_t   bf16 [6,384,384]   @ 203,489,280
//   w1_t   bf16 [6,1536,384]  @ 205,258,752
//   w2_t   bf16 [6,384,1536]  @ 212,336,640
//   accums fp32 [4]           @ 219,414,528

#define EDIM   384
#define NHEAD  6
#define DHEAD  64
#define NLAYER 6
#define TBLK   36
#define SNUM   210
#define BSZ    1024
#define NTOK   (BSZ*TBLK)
#define QKVSTR 1152

typedef __attribute__((ext_vector_type(8))) short short8;
typedef __attribute__((ext_vector_type(4))) float floatx4;

static __device__ __forceinline__ unsigned short f2bf(float f){
  union { float fv; unsigned int u; } v; v.fv = f;
  unsigned int r = v.u + 0x7FFFu + ((v.u >> 16) & 1u);
  return (unsigned short)(r >> 16);
}
static __device__ __forceinline__ float bf2f(unsigned short u){
  union { unsigned int u; float fv; } v; v.u = ((unsigned int)u) << 16;
  return v.fv;
}
static __device__ __forceinline__ void gld_lds16(const void* g, void* l){
  __builtin_amdgcn_global_load_lds(
      (const __attribute__((address_space(1))) void*)g,
      (__attribute__((address_space(3))) void*)l, 16, 0, 0);
}

// ---------------- weight transpose + bf16 cast: out[m][k] = bf16(in[k][m]) ----
__global__ __launch_bounds__(256) void wt_transpose(const float* __restrict__ in,
    unsigned short* __restrict__ out, int K, int M, long outStride){
  __shared__ float tile[32][33];
  const int mat = blockIdx.z;
  const float* src = in + (size_t)mat*K*M;
  unsigned short* dst = out + (size_t)mat*outStride;
  const int m0 = blockIdx.x*32, k0 = blockIdx.y*32;
  const int tx = threadIdx.x, ty = threadIdx.y;
  for(int i=ty;i<32;i+=8) tile[i][tx] = src[(size_t)(k0+i)*M + m0+tx];
  __syncthreads();
  for(int i=ty;i<32;i+=8) dst[(size_t)(m0+i)*K + k0+tx] = f2bf(tile[tx][i]);
}

// ---------------- embedding ---------------------------------------------------
__global__ __launch_bounds__(384) void embed_kernel(const int* __restrict__ idx,
    const int* __restrict__ stn_p, const float* __restrict__ Wp,
    const float* __restrict__ bp, const float* __restrict__ stat_emb,
    const float* __restrict__ fire_emb, float* __restrict__ x){
  __shared__ float pm[TBLK*212];
  __shared__ int fire[TBLK];
  const int b = blockIdx.x, tid = threadIdx.x;
  const int stn = stn_p[0];
  const int* ib = idx + (size_t)b*TBLK*SNUM*2;
  for(int i=tid;i<TBLK*212;i+=384){
    int t = i/212, s = i - t*212;
    pm[i] = (s < SNUM) ? (float)ib[(t*SNUM+s)*2] * (1.f/500.f) : 0.f;
  }
  if(tid < TBLK) fire[tid] = ib[(tid*SNUM+stn)*2+1];
  __syncthreads();
  const int e = tid;
  float acc[TBLK];
  const float basev = bp[e] + stat_emb[(size_t)stn*EDIM+e];
  const float freq = __expf(-(float)(2*(e>>1)) * (9.210340371976184f/384.f));
  #pragma unroll
  for(int t=0;t<TBLK;t++){
    float ang = (float)t * freq;
    float pe = (e & 1) ? __cosf(ang) : __sinf(ang);
    acc[t] = basev + pe + fire_emb[(size_t)fire[t]*EDIM+e];
  }
  for(int sb=0; sb<53; sb++){
    int s = sb*4;
    float w0 = (s+0<SNUM)? Wp[(size_t)(s+0)*EDIM+e] : 0.f;
    float w1 = (s+1<SNUM)? Wp[(size_t)(s+1)*EDIM+e] : 0.f;
    float w2 = (s+2<SNUM)? Wp[(size_t)(s+2)*EDIM+e] : 0.f;
    float w3 = (s+3<SNUM)? Wp[(size_t)(s+3)*EDIM+e] : 0.f;
    #pragma unroll
    for(int t=0;t<TBLK;t++){
      float4 p4 = *(const float4*)&pm[t*212 + s];
      acc[t] = fmaf(p4.x, w0, acc[t]);
      acc[t] = fmaf(p4.y, w1, acc[t]);
      acc[t] = fmaf(p4.z, w2, acc[t]);
      acc[t] = fmaf(p4.w, w3, acc[t]);
    }
  }
  float* xb = x + (size_t)b*TBLK*EDIM;
  #pragma unroll
  for(int t=0;t<TBLK;t++) xb[t*EDIM + e] = acc[t];
}

// ---------------- layernorm fp32 -> bf16, one wave per row --------------------
__global__ __launch_bounds__(256) void ln_bf16(const float* __restrict__ x,
    const float* __restrict__ g, const float* __restrict__ b,
    unsigned short* __restrict__ out){
  const int wave = threadIdx.x >> 6, lane = threadIdx.x & 63;
  const int row = blockIdx.x*4 + wave;
  const float* xr = x + (size_t)row*EDIM;
  float v[6]; float s=0.f, sq=0.f;
  #pragma unroll
  for(int j=0;j<6;j++){ v[j]=xr[j*64+lane]; s+=v[j]; sq+=v[j]*v[j]; }
  #pragma unroll
  for(int m=1;m<64;m<<=1){ s += __shfl_xor(s,m); sq += __shfl_xor(sq,m); }
  const float mean = s*(1.f/384.f);
  const float var  = sq*(1.f/384.f) - mean*mean;
  const float rstd = rsqrtf(var + 1e-5f);
  unsigned short* orow = out + (size_t)row*EDIM;
  #pragma unroll
  for(int j=0;j<6;j++){
    int e = j*64+lane;
    orow[e] = f2bf((v[j]-mean)*rstd*g[e] + b[e]);
  }
}

// ---------------- bf16 MFMA GEMM: C[N,M] = A[N,K] @ Wt[M,K]^T -----------------
// grid (M/128, N/128), block 256. Staging via global_load_lds width=16 (m97).
template<bool RELU, bool RESID>
__global__ __launch_bounds__(256) void gemm_k(const unsigned short* __restrict__ A,
    const unsigned short* __restrict__ Wt, const float* __restrict__ bias,
    unsigned short* __restrict__ outb, float* __restrict__ resid, int M, int K){
  __shared__ __align__(16) unsigned short As[128*32];
  __shared__ __align__(16) unsigned short Bs[128*32];
  const int tid  = threadIdx.x;
  const int m0   = blockIdx.x * 128;
  const int n0   = blockIdx.y * 128;
  const int wave = tid >> 6, lane = tid & 63;
  const int wr = wave >> 1, wc = wave & 1;
  const int lrow = lane & 15, quad = lane >> 4;
  floatx4 acc[4][4];
  #pragma unroll
  for(int i=0;i<4;i++)
    #pragma unroll
    for(int j=0;j<4;j++) acc[i][j] = (floatx4){0.f,0.f,0.f,0.f};

  for(int kk=0; kk<K; kk+=32){
    __syncthreads();
    #pragma unroll
    for(int p=0;p<2;p++){
      int i = tid + p*256;
      int r = i >> 2, c = (i & 3) * 8;
      gld_lds16(&A [(size_t)(n0+r)*K + kk + c], &As[i*8]);
      gld_lds16(&Wt[(size_t)(m0+r)*K + kk + c], &Bs[i*8]);
    }
    __syncthreads();
    short8 af[4], bfv[4];
    #pragma unroll
    for(int ti=0;ti<4;ti++) af[ti]  = *(const short8*)(&As[(wr*64+ti*16+lrow)*32 + quad*8]);
    #pragma unroll
    for(int tj=0;tj<4;tj++) bfv[tj] = *(const short8*)(&Bs[(wc*64+tj*16+lrow)*32 + quad*8]);
    #pragma unroll
    for(int ti=0;ti<4;ti++)
      #pragma unroll
      for(int tj=0;tj<4;tj++)
        acc[ti][tj] = __builtin_amdgcn_mfma_f32_16x16x32_bf16(af[ti], bfv[tj], acc[ti][tj], 0,0,0);
  }
  #pragma unroll
  for(int ti=0;ti<4;ti++){
    #pragma unroll
    for(int r=0;r<4;r++){
      int row = n0 + wr*64 + ti*16 + quad*4 + r;
      #pragma unroll
      for(int tj=0;tj<4;tj++){
        int col = m0 + wc*64 + tj*16 + lrow;
        float val = acc[ti][tj][r];
        if(bias) val += bias[col];
        if(RELU) val = fmaxf(val, 0.f);
        if(RESID) resid[(size_t)row*M + col] += val;
        else      outb [(size_t)row*M + col] = f2bf(val);
      }
    }
  }
}

// ---------------- causal attention v2: block=256 (4 waves) per (b,h) ----------
// qkv layout [36864][1152]: q cols 0..383, k 384..767, v 768..1151.
__global__ __launch_bounds__(256) void attn_kernel(const unsigned short* __restrict__ qkv,
    unsigned short* __restrict__ o){
  const int bh = blockIdx.x;
  const int b = bh / NHEAD, h = bh % NHEAD;
  const int wave = threadIdx.x >> 6, lane = threadIdx.x & 63;
  const int tid = threadIdx.x;
  __shared__ float qs[TBLK*64];   // stride 64; read as float4 broadcast
  __shared__ float ks[TBLK*65];   // +1 pad: per-lane row gather conflict-free
  __shared__ float ps[TBLK*64];   // zero-filled by mask -> branch-free PV
  const size_t base = (size_t)b*TBLK*QKVSTR + h*DHEAD;
  const unsigned short* qp = qkv + base;
  const unsigned short* kp = qkv + base + 384;
  const unsigned short* vp = qkv + base + 768;
  // cooperative load Q,K -> LDS fp32 (coalesced)
  for(int i=tid; i<TBLK*64; i+=256){
    int t = i >> 6, dd = i & 63;
    qs[i]          = bf2f(qp[(size_t)t*QKVSTR + dd]);
    ks[t*65 + dd]  = bf2f(kp[(size_t)t*QKVSTR + dd]);
  }
  // V column into regs (global, coalesced; lane = d)
  float vreg[TBLK];
  #pragma unroll
  for(int s2=0;s2<TBLK;s2++) vreg[s2] = bf2f(vp[(size_t)s2*QKVSTR + lane]);
  __syncthreads();
  // K row into regs (lane = s; clamped rows for lanes >= 36, masked anyway)
  const int krow = (lane < TBLK) ? lane : (TBLK-1);
  float kreg[64];
  #pragma unroll
  for(int dd=0;dd<64;dd++) kreg[dd] = ks[krow*65 + dd];
  const float scale = 0.125f;   // 64^-0.5
  // pass1: scores + softmax; wave w handles t = w + 4*j
  #pragma unroll
  for(int j=0;j<9;j++){
    const int t = wave + 4*j;
    float d = 0.f;
    #pragma unroll
    for(int g=0;g<16;g++){
      float4 q4 = *(const float4*)&qs[t*64 + g*4];   // LDS broadcast
      d = fmaf(q4.x, kreg[g*4+0], d);
      d = fmaf(q4.y, kreg[g*4+1], d);
      d = fmaf(q4.z, kreg[g*4+2], d);
      d = fmaf(q4.w, kreg[g*4+3], d);
    }
    float val = (lane <= t) ? d*scale : -INFINITY;
    float mx = val;
    #pragma unroll
    for(int m=1;m<64;m<<=1) mx = fmaxf(mx, __shfl_xor(mx,m));
    float p = __expf(val - mx);          // 0 for masked lanes
    float sum = p;
    #pragma unroll
    for(int m=1;m<64;m<<=1) sum += __shfl_xor(sum,m);
    ps[t*64 + lane] = p / sum;
  }
  __syncthreads();
  // pass2: PV; lane = d; P is zero beyond t so loop is branch-free
  #pragma unroll
  for(int j=0;j<9;j++){
    const int t = wave + 4*j;
    float acc = 0.f;
    #pragma unroll
    for(int g=0;g<9;g++){
      float4 p4 = *(const float4*)&ps[t*64 + g*4];   // LDS broadcast
      acc = fmaf(p4.x, vreg[g*4+0], acc);
      acc = fmaf(p4.y, vreg[g*4+1], acc);
      acc = fmaf(p4.z, vreg[g*4+2], acc);
      acc = fmaf(p4.w, vreg[g*4+3], acc);
    }
    o[(size_t)b*TBLK*EDIM + (size_t)t*EDIM + h*DHEAD + lane] = f2bf(acc);
  }
}

// ---------------- head: LNf + sigmoid(x@Wh+bh)*500 + loss partials ------------
__global__ __launch_bounds__(256) void head_kernel(const float* __restrict__ x,
    const float* __restrict__ g, const float* __restrict__ b,
    const float* __restrict__ Wh, const float* __restrict__ bh,
    const int* __restrict__ targets, float* __restrict__ out,
    float* __restrict__ accums){
  const int wave = threadIdx.x >> 6, lane = threadIdx.x & 63;
  const int row = blockIdx.x*4 + wave;
  const float* xr = x + (size_t)row*EDIM;
  float v[6]; float s=0.f, sq=0.f;
  #pragma unroll
  for(int j=0;j<6;j++){ v[j]=xr[j*64+lane]; s+=v[j]; sq+=v[j]*v[j]; }
  #pragma unroll
  for(int m=1;m<64;m<<=1){ s += __shfl_xor(s,m); sq += __shfl_xor(sq,m); }
  const float mean = s*(1.f/384.f);
  const float var  = sq*(1.f/384.f) - mean*mean;
  const float rstd = rsqrtf(var + 1e-5f);
  float dot = 0.f;
  #pragma unroll
  for(int j=0;j<6;j++){
    int e = j*64+lane;
    float hh = (v[j]-mean)*rstd*g[e] + b[e];
    dot = fmaf(hh, Wh[e], dot);
  }
  #pragma unroll
  for(int m=1;m<64;m<<=1) dot += __shfl_xor(dot,m);
  __shared__ float part[4][4];
  if(lane == 0){
    float logit = 1.f/(1.f + __expf(-(dot + bh[0])));
    float den = logit * 500.f;
    out[row] = den;
    float tgt = (float)targets[(size_t)row*2];
    float nt  = tgt * (1.f/500.f);
    part[wave][0] = (logit-nt)*(logit-nt);
    part[wave][1] = (tgt-den)*(tgt-den);
    part[wave][2] = tgt;
    part[wave][3] = tgt*tgt;
  }
  __syncthreads();
  if(threadIdx.x < 4){
    float t0 = part[0][threadIdx.x] + part[1][threadIdx.x]
             + part[2][threadIdx.x] + part[3][threadIdx.x];
    atomicAdd(&accums[threadIdx.x], t0);
  }
}

__global__ void init_acc(float* accums){ if(threadIdx.x < 4) accums[threadIdx.x] = 0.f; }

__global__ void finalize_kernel(const float* __restrict__ acc, float* __restrict__ out){
  const float n = (float)NTOK;
  out[NTOK]   = acc[0] / n;
  float denom = acc[3] - acc[2]*acc[2]/n;
  out[NTOK+1] = 1.f - acc[1]/denom;
}

// =============================================================================
extern "C" void kernel_launch(void* const* d_in, const int* in_sizes, int n_in,
                              void* d_out, int out_size, void* d_ws, size_t ws_size,
                              hipStream_t stream){
  (void)in_sizes; (void)n_in; (void)out_size; (void)ws_size;
  const int*   idx      = (const int*)  d_in[0];
  const int*   targets  = (const int*)  d_in[1];
  const int*   stn_ix   = (const int*)  d_in[3];
  const float* Wp       = (const float*)d_in[4];
  const float* bp       = (const float*)d_in[5];
  const float* stat_emb = (const float*)d_in[6];
  const float* fire_emb = (const float*)d_in[7];
  const float* ln1_g    = (const float*)d_in[8];
  const float* ln1_b    = (const float*)d_in[9];
  const float* Wq       = (const float*)d_in[10];
  const float* Wk       = (const float*)d_in[11];
  const float* Wv       = (const float*)d_in[12];
  const float* Wo       = (const float*)d_in[13];
  const float* bo       = (const float*)d_in[14];
  const float* ln2_g    = (const float*)d_in[15];
  const float* ln2_b    = (const float*)d_in[16];
  const float* W1       = (const float*)d_in[17];
  const float* b1       = (const float*)d_in[18];
  const float* W2       = (const float*)d_in[19];
  const float* b2       = (const float*)d_in[20];
  const float* lnf_g    = (const float*)d_in[21];
  const float* lnf_b    = (const float*)d_in[22];
  const float* Wh       = (const float*)d_in[23];
  const float* bh       = (const float*)d_in[24];
  float* out = (float*)d_out;

  char* ws = (char*)d_ws;
  float*          x      = (float*)         (ws + 0);
  unsigned short* h      = (unsigned short*)(ws + 56623104);
  unsigned short* qkv    = (unsigned short*)(ws + 84934656);
  unsigned short* obuf   = (unsigned short*)(ws + 169869312);
  unsigned short* ffn    = qkv;   // aliases qkv+obuf after attn & Wo gemm done
  unsigned short* wqkv_t = (unsigned short*)(ws + 198180864);
  unsigned short* wo_t   = (unsigned short*)(ws + 203489280);
  unsigned short* w1_t   = (unsigned short*)(ws + 205258752);
  unsigned short* w2_t   = (unsigned short*)(ws + 212336640);
  float*          accs   = (float*)         (ws + 219414528);

  const dim3 tb(32,8);
  wt_transpose<<<dim3(12,12,6), tb, 0, stream>>>(Wq, wqkv_t,            384,  384, 442368);
  wt_transpose<<<dim3(12,12,6), tb, 0, stream>>>(Wk, wqkv_t + 147456,   384,  384, 442368);
  wt_transpose<<<dim3(12,12,6), tb, 0, stream>>>(Wv, wqkv_t + 294912,   384,  384, 442368);
  wt_transpose<<<dim3(12,12,6), tb, 0, stream>>>(Wo, wo_t,              384,  384, 147456);
  wt_transpose<<<dim3(48,12,6), tb, 0, stream>>>(W1, w1_t,              384, 1536, 589824);
  wt_transpose<<<dim3(12,48,6), tb, 0, stream>>>(W2, w2_t,             1536,  384, 589824);

  embed_kernel<<<BSZ, 384, 0, stream>>>(idx, stn_ix, Wp, bp, stat_emb, fire_emb, x);

  const dim3 gQKV(9, 288);   // M=1152
  const dim3 gE(3, 288);     // M=384
  const dim3 gF(12, 288);    // M=1536
  for(int l=0; l<NLAYER; l++){
    ln_bf16<<<NTOK/4, 256, 0, stream>>>(x, ln1_g + l*EDIM, ln1_b + l*EDIM, h);
    gemm_k<false,false><<<gQKV, 256, 0, stream>>>(h, wqkv_t + (size_t)l*442368, nullptr, qkv, nullptr, 1152, 384);
    attn_kernel<<<BSZ*NHEAD, 256, 0, stream>>>(qkv, obuf);
    gemm_k<false,true ><<<gE, 256, 0, stream>>>(obuf, wo_t + (size_t)l*147456, bo + l*EDIM, nullptr, x, 384, 384);
    ln_bf16<<<NTOK/4, 256, 0, stream>>>(x, ln2_g + l*EDIM, ln2_b + l*EDIM, h);
    gemm_k<true ,false><<<gF, 256, 0, stream>>>(h,   w1_t + (size_t)l*589824, b1 + l*1536, ffn, nullptr, 1536, 384);
    gemm_k<false,true ><<<gE, 256, 0, stream>>>(ffn, w2_t + (size_t)l*589824, b2 + l*EDIM, nullptr, x, 384, 1536);
  }

  init_acc<<<1, 64, 0, stream>>>(accs);
  head_kernel<<<NTOK/4, 256, 0, stream>>>(x, lnf_g, lnf_b, Wh, bh, targets, out, accs);
  finalize_kernel<<<1, 1, 0, stream>>>(accs, out);
}

// Round 3
// 3062.057 us; speedup vs baseline: 1.5089x; 1.1571x over previous
//
#include <hip/hip_runtime.h>
#include <stdint.h>

// PM25 transformer forward, MI355X/gfx950. Round 3:
//   - embedding via MFMA GEMM (pm25 cast to bf16 [36864,224], K-padded) with
//     fused epilogue (bp + station_emb + pos_emb + fire_emb gathers).
//   - Wo/W2 residual GEMMs -> full-row-tile gemm_row_ln: epilogue does residual
//     add + LayerNorm (shfl+LDS reduction) and writes x fp32 + h bf16. Removes
//     12 standalone LN dispatches.
// ws layout (bytes):
//   x      fp32 [36864,384]   @ 0
//   h      bf16 [36864,384]   @ 56,623,104
//   qkv    bf16 [36864,1152]  @ 84,934,656
//   obuf   bf16 [36864,384]   @ 169,869,312
//   ffn    bf16 [36864,1536]  @ 84,934,656   (aliases qkv+obuf)
//   embed scratch (aliases obuf region, used before layer 0 only):
//     pm    bf16 [36864,224]  @ 169,869,312
//     fire  int  [36864]      @ 186,384,384
//     wp_t  bf16 [384,224]    @ 186,531,840
//     pe    fp32 [36,384]     @ 186,703,872
//   wqkv_t bf16 [6,1152,384]  @ 198,180,864
//   wo_t   bf16 [6,384,384]   @ 203,489,280
//   w1_t   bf16 [6,1536,384]  @ 205,258,752
//   w2_t   bf16 [6,384,1536]  @ 212,336,640
//   accums fp32 [4]           @ 219,414,528

#define EDIM   384
#define NHEAD  6
#define DHEAD  64
#define NLAYER 6
#define TBLK   36
#define SNUM   210
#define BSZ    1024
#define NTOK   (BSZ*TBLK)
#define QKVSTR 1152
#define KPM    224

typedef __attribute__((ext_vector_type(8))) short short8;
typedef __attribute__((ext_vector_type(4))) float floatx4;

static __device__ __forceinline__ unsigned short f2bf(float f){
  union { float fv; unsigned int u; } v; v.fv = f;
  unsigned int r = v.u + 0x7FFFu + ((v.u >> 16) & 1u);
  return (unsigned short)(r >> 16);
}
static __device__ __forceinline__ float bf2f(unsigned short u){
  union { unsigned int u; float fv; } v; v.u = ((unsigned int)u) << 16;
  return v.fv;
}
static __device__ __forceinline__ void gld_lds16(const void* g, void* l){
  __builtin_amdgcn_global_load_lds(
      (const __attribute__((address_space(1))) void*)g,
      (__attribute__((address_space(3))) void*)l, 16, 0, 0);
}

// ---------------- weight transpose + bf16 cast: out[m][k] = bf16(in[k][m]) ----
__global__ __launch_bounds__(256) void wt_transpose(const float* __restrict__ in,
    unsigned short* __restrict__ out, int K, int M, long outStride){
  __shared__ float tile[32][33];
  const int mat = blockIdx.z;
  const float* src = in + (size_t)mat*K*M;
  unsigned short* dst = out + (size_t)mat*outStride;
  const int m0 = blockIdx.x*32, k0 = blockIdx.y*32;
  const int tx = threadIdx.x, ty = threadIdx.y;
  for(int i=ty;i<32;i+=8) tile[i][tx] = src[(size_t)(k0+i)*M + m0+tx];
  __syncthreads();
  for(int i=ty;i<32;i+=8) dst[(size_t)(m0+i)*K + k0+tx] = f2bf(tile[tx][i]);
}

// Wp [210,384] -> wp_t bf16 [384,224] (K zero-padded 210->224)
__global__ __launch_bounds__(256) void wp_transpose(const float* __restrict__ Wp,
    unsigned short* __restrict__ wp_t){
  const int m = blockIdx.x, k = threadIdx.x;
  if(k < KPM)
    wp_t[(size_t)m*KPM + k] = (k < SNUM) ? f2bf(Wp[(size_t)k*EDIM + m]) : 0;
}

// pm bf16 [36864,224]: pm[row][s] = bf16(idx[row][s][0]/500), 0 beyond 210
__global__ __launch_bounds__(256) void prep_pm(const int* __restrict__ idx,
    unsigned short* __restrict__ pm){
  const int i = blockIdx.x*256 + threadIdx.x;
  if(i >= NTOK*KPM) return;
  const int row = i / KPM, s = i - row*KPM;
  float v = 0.f;
  if(s < SNUM) v = (float)idx[((size_t)row*SNUM + s)*2] * (1.f/500.f);
  pm[i] = f2bf(v);
}

__global__ __launch_bounds__(256) void prep_fire(const int* __restrict__ idx,
    const int* __restrict__ stn_p, int* __restrict__ fire){
  const int row = blockIdx.x*256 + threadIdx.x;
  if(row < NTOK) fire[row] = idx[((size_t)row*SNUM + stn_p[0])*2 + 1];
}

__global__ __launch_bounds__(384) void pe_kernel(float* __restrict__ pe){
  const int t = blockIdx.x, e = threadIdx.x;
  const float freq = __expf(-(float)(2*(e>>1)) * (9.210340371976184f/384.f));
  const float ang = (float)t * freq;
  pe[t*EDIM + e] = (e & 1) ? __cosf(ang) : __sinf(ang);
}

// ---------------- layernorm fp32 -> bf16 (layer-0 ln1 only) -------------------
__global__ __launch_bounds__(256) void ln_bf16(const float* __restrict__ x,
    const float* __restrict__ g, const float* __restrict__ b,
    unsigned short* __restrict__ out){
  const int wave = threadIdx.x >> 6, lane = threadIdx.x & 63;
  const int row = blockIdx.x*4 + wave;
  const float* xr = x + (size_t)row*EDIM;
  float v[6]; float s=0.f, sq=0.f;
  #pragma unroll
  for(int j=0;j<6;j++){ v[j]=xr[j*64+lane]; s+=v[j]; sq+=v[j]*v[j]; }
  #pragma unroll
  for(int m=1;m<64;m<<=1){ s += __shfl_xor(s,m); sq += __shfl_xor(sq,m); }
  const float mean = s*(1.f/384.f);
  const float var  = sq*(1.f/384.f) - mean*mean;
  const float rstd = rsqrtf(var + 1e-5f);
  unsigned short* orow = out + (size_t)row*EDIM;
  #pragma unroll
  for(int j=0;j<6;j++){
    int e = j*64+lane;
    orow[e] = f2bf((v[j]-mean)*rstd*g[e] + b[e]);
  }
}

// ---------------- bf16 MFMA GEMM: C[N,M] = A[N,K] @ Wt[M,K]^T -----------------
// MODE 0: write bf16 (bias opt, RELU opt).  MODE 2: embed epilogue -> fp32 x.
template<int MODE, bool RELU>
__global__ __launch_bounds__(256) void gemm_k(const unsigned short* __restrict__ A,
    const unsigned short* __restrict__ Wt, const float* __restrict__ bias,
    unsigned short* __restrict__ outb, float* __restrict__ xout,
    const int* __restrict__ fire, const float* __restrict__ pe,
    const float* __restrict__ stat_emb, const int* __restrict__ stn_p,
    const float* __restrict__ fire_emb, int M, int K){
  __shared__ __align__(16) unsigned short As[128*32];
  __shared__ __align__(16) unsigned short Bs[128*32];
  const int tid  = threadIdx.x;
  const int m0   = blockIdx.x * 128;
  const int n0   = blockIdx.y * 128;
  const int wave = tid >> 6, lane = tid & 63;
  const int wr = wave >> 1, wc = wave & 1;
  const int lrow = lane & 15, quad = lane >> 4;
  floatx4 acc[4][4];
  #pragma unroll
  for(int i=0;i<4;i++)
    #pragma unroll
    for(int j=0;j<4;j++) acc[i][j] = (floatx4){0.f,0.f,0.f,0.f};

  for(int kk=0; kk<K; kk+=32){
    __syncthreads();
    #pragma unroll
    for(int p=0;p<2;p++){
      int i = tid + p*256;
      int r = i >> 2, c = (i & 3) * 8;
      gld_lds16(&A [(size_t)(n0+r)*K + kk + c], &As[i*8]);
      gld_lds16(&Wt[(size_t)(m0+r)*K + kk + c], &Bs[i*8]);
    }
    __syncthreads();
    short8 af[4], bfv[4];
    #pragma unroll
    for(int ti=0;ti<4;ti++) af[ti]  = *(const short8*)(&As[(wr*64+ti*16+lrow)*32 + quad*8]);
    #pragma unroll
    for(int tj=0;tj<4;tj++) bfv[tj] = *(const short8*)(&Bs[(wc*64+tj*16+lrow)*32 + quad*8]);
    #pragma unroll
    for(int ti=0;ti<4;ti++)
      #pragma unroll
      for(int tj=0;tj<4;tj++)
        acc[ti][tj] = __builtin_amdgcn_mfma_f32_16x16x32_bf16(af[ti], bfv[tj], acc[ti][tj], 0,0,0);
  }
  const int stn = (MODE==2) ? stn_p[0] : 0;
  #pragma unroll
  for(int ti=0;ti<4;ti++){
    #pragma unroll
    for(int r=0;r<4;r++){
      int row = n0 + wr*64 + ti*16 + quad*4 + r;
      int fidx = 0, trow = 0;
      if(MODE==2){ fidx = fire[row]; trow = row % TBLK; }
      #pragma unroll
      for(int tj=0;tj<4;tj++){
        int col = m0 + wc*64 + tj*16 + lrow;
        float val = acc[ti][tj][r];
        if(MODE==0){
          if(bias) val += bias[col];
          if(RELU) val = fmaxf(val, 0.f);
          outb[(size_t)row*M + col] = f2bf(val);
        } else {
          val += bias[col] + stat_emb[(size_t)stn*EDIM + col]
               + pe[trow*EDIM + col] + fire_emb[(size_t)fidx*EDIM + col];
          xout[(size_t)row*EDIM + col] = val;
        }
      }
    }
  }
}

// ------- full-row GEMM + residual + LayerNorm epilogue ------------------------
// C[64 rows, 384 cols] per block, 256 thr (4 waves: wr=wave>>1 rows, wc=wave&1
// cols). x += A@Wt^T + bias; h = LN(x)*g+b (bf16). writeH==0 skips h.
__global__ __launch_bounds__(256, 2) void gemm_row_ln(
    const unsigned short* __restrict__ A, const unsigned short* __restrict__ Wt,
    const float* __restrict__ bias, float* __restrict__ x,
    const float* __restrict__ g, const float* __restrict__ b,
    unsigned short* __restrict__ h, int K, int writeH){
  __shared__ __align__(16) unsigned short As[64*32];    // 4 KB
  __shared__ __align__(16) unsigned short Bs[384*32];   // 24 KB
  const int tid = threadIdx.x;
  const int n0 = blockIdx.x * 64;
  const int wave = tid >> 6, lane = tid & 63;
  const int wr = wave >> 1, wc = wave & 1;
  const int lrow = lane & 15, quad = lane >> 4;
  floatx4 acc[2][12];
  #pragma unroll
  for(int i=0;i<2;i++)
    #pragma unroll
    for(int j=0;j<12;j++) acc[i][j] = (floatx4){0.f,0.f,0.f,0.f};

  for(int kk=0; kk<K; kk+=32){
    __syncthreads();
    {
      int r = tid >> 2, c = (tid & 3) * 8;
      gld_lds16(&A[(size_t)(n0+r)*K + kk + c], &As[tid*8]);
    }
    #pragma unroll
    for(int p=0;p<6;p++){
      int i = tid + p*256;
      int r = i >> 2, c = (i & 3) * 8;
      gld_lds16(&Wt[(size_t)r*K + kk + c], &Bs[i*8]);
    }
    __syncthreads();
    short8 af[2], bfv[12];
    #pragma unroll
    for(int ti=0;ti<2;ti++) af[ti]  = *(const short8*)(&As[(wr*32+ti*16+lrow)*32 + quad*8]);
    #pragma unroll
    for(int tj=0;tj<12;tj++) bfv[tj] = *(const short8*)(&Bs[(wc*192+tj*16+lrow)*32 + quad*8]);
    #pragma unroll
    for(int ti=0;ti<2;ti++)
      #pragma unroll
      for(int tj=0;tj<12;tj++)
        acc[ti][tj] = __builtin_amdgcn_mfma_f32_16x16x32_bf16(af[ti], bfv[tj], acc[ti][tj], 0,0,0);
  }
  __syncthreads();                 // all waves done reading As -> reuse as part[]
  float* part = (float*)As;        // part_s[64][2] @0, part_q[64][2] @256 floats
  // phase 1: residual add + per-wave row partials over its 192 cols
  #pragma unroll
  for(int ti=0;ti<2;ti++){
    float ps[4] = {0.f,0.f,0.f,0.f}, pq[4] = {0.f,0.f,0.f,0.f};
    #pragma unroll
    for(int tj=0;tj<12;tj++){
      const int col = wc*192 + tj*16 + lrow;
      const float bi = bias[col];
      #pragma unroll
      for(int r=0;r<4;r++){
        const int row = n0 + wr*32 + ti*16 + quad*4 + r;
        float v = acc[ti][tj][r] + bi + x[(size_t)row*EDIM + col];
        acc[ti][tj][r] = v;
        ps[r] += v; pq[r] += v*v;
      }
    }
    #pragma unroll
    for(int r=0;r<4;r++){
      #pragma unroll
      for(int m=1;m<16;m<<=1){ ps[r] += __shfl_xor(ps[r],m); pq[r] += __shfl_xor(pq[r],m); }
    }
    if(lrow == 0){
      #pragma unroll
      for(int r=0;r<4;r++){
        const int rl = wr*32 + ti*16 + quad*4 + r;
        part[rl*2 + wc]       = ps[r];
        part[256 + rl*2 + wc] = pq[r];
      }
    }
  }
  __syncthreads();
  // phase 2: finalize x + LN -> h
  #pragma unroll
  for(int ti=0;ti<2;ti++){
    #pragma unroll
    for(int r=0;r<4;r++){
      const int rl = wr*32 + ti*16 + quad*4 + r;
      const int row = n0 + rl;
      const float s = part[rl*2+0] + part[rl*2+1];
      const float q = part[256+rl*2+0] + part[256+rl*2+1];
      const float mean = s*(1.f/384.f);
      const float var  = q*(1.f/384.f) - mean*mean;
      const float rstd = rsqrtf(var + 1e-5f);
      #pragma unroll
      for(int tj=0;tj<12;tj++){
        const int col = wc*192 + tj*16 + lrow;
        const float v = acc[ti][tj][r];
        x[(size_t)row*EDIM + col] = v;
        if(writeH)
          h[(size_t)row*EDIM + col] = f2bf((v-mean)*rstd*g[col] + b[col]);
      }
    }
  }
}

// ---------------- causal attention: 4 waves/block per (b,h) -------------------
__global__ __launch_bounds__(256) void attn_kernel(const unsigned short* __restrict__ qkv,
    unsigned short* __restrict__ o){
  const int bh = blockIdx.x;
  const int b = bh / NHEAD, h = bh % NHEAD;
  const int wave = threadIdx.x >> 6, lane = threadIdx.x & 63;
  const int tid = threadIdx.x;
  __shared__ float qs[TBLK*64];
  __shared__ float ks[TBLK*65];
  __shared__ float ps[TBLK*64];
  const size_t base = (size_t)b*TBLK*QKVSTR + h*DHEAD;
  const unsigned short* qp = qkv + base;
  const unsigned short* kp = qkv + base + 384;
  const unsigned short* vp = qkv + base + 768;
  for(int i=tid; i<TBLK*64; i+=256){
    int t = i >> 6, dd = i & 63;
    qs[i]          = bf2f(qp[(size_t)t*QKVSTR + dd]);
    ks[t*65 + dd]  = bf2f(kp[(size_t)t*QKVSTR + dd]);
  }
  float vreg[TBLK];
  #pragma unroll
  for(int s2=0;s2<TBLK;s2++) vreg[s2] = bf2f(vp[(size_t)s2*QKVSTR + lane]);
  __syncthreads();
  const int krow = (lane < TBLK) ? lane : (TBLK-1);
  float kreg[64];
  #pragma unroll
  for(int dd=0;dd<64;dd++) kreg[dd] = ks[krow*65 + dd];
  const float scale = 0.125f;
  #pragma unroll
  for(int j=0;j<9;j++){
    const int t = wave + 4*j;
    float d = 0.f;
    #pragma unroll
    for(int gg=0;gg<16;gg++){
      float4 q4 = *(const float4*)&qs[t*64 + gg*4];
      d = fmaf(q4.x, kreg[gg*4+0], d);
      d = fmaf(q4.y, kreg[gg*4+1], d);
      d = fmaf(q4.z, kreg[gg*4+2], d);
      d = fmaf(q4.w, kreg[gg*4+3], d);
    }
    float val = (lane <= t) ? d*scale : -INFINITY;
    float mx = val;
    #pragma unroll
    for(int m=1;m<64;m<<=1) mx = fmaxf(mx, __shfl_xor(mx,m));
    float p = __expf(val - mx);
    float sum = p;
    #pragma unroll
    for(int m=1;m<64;m<<=1) sum += __shfl_xor(sum,m);
    ps[t*64 + lane] = p / sum;
  }
  __syncthreads();
  #pragma unroll
  for(int j=0;j<9;j++){
    const int t = wave + 4*j;
    float acc = 0.f;
    #pragma unroll
    for(int gg=0;gg<9;gg++){
      float4 p4 = *(const float4*)&ps[t*64 + gg*4];
      acc = fmaf(p4.x, vreg[gg*4+0], acc);
      acc = fmaf(p4.y, vreg[gg*4+1], acc);
      acc = fmaf(p4.z, vreg[gg*4+2], acc);
      acc = fmaf(p4.w, vreg[gg*4+3], acc);
    }
    o[(size_t)b*TBLK*EDIM + (size_t)t*EDIM + h*DHEAD + lane] = f2bf(acc);
  }
}

// ---------------- head: LNf + sigmoid(x@Wh+bh)*500 + loss partials ------------
__global__ __launch_bounds__(256) void head_kernel(const float* __restrict__ x,
    const float* __restrict__ g, const float* __restrict__ b,
    const float* __restrict__ Wh, const float* __restrict__ bh,
    const int* __restrict__ targets, float* __restrict__ out,
    float* __restrict__ accums){
  const int wave = threadIdx.x >> 6, lane = threadIdx.x & 63;
  const int row = blockIdx.x*4 + wave;
  const float* xr = x + (size_t)row*EDIM;
  float v[6]; float s=0.f, sq=0.f;
  #pragma unroll
  for(int j=0;j<6;j++){ v[j]=xr[j*64+lane]; s+=v[j]; sq+=v[j]*v[j]; }
  #pragma unroll
  for(int m=1;m<64;m<<=1){ s += __shfl_xor(s,m); sq += __shfl_xor(sq,m); }
  const float mean = s*(1.f/384.f);
  const float var  = sq*(1.f/384.f) - mean*mean;
  const float rstd = rsqrtf(var + 1e-5f);
  float dot = 0.f;
  #pragma unroll
  for(int j=0;j<6;j++){
    int e = j*64+lane;
    float hh = (v[j]-mean)*rstd*g[e] + b[e];
    dot = fmaf(hh, Wh[e], dot);
  }
  #pragma unroll
  for(int m=1;m<64;m<<=1) dot += __shfl_xor(dot,m);
  __shared__ float part[4][4];
  if(lane == 0){
    float logit = 1.f/(1.f + __expf(-(dot + bh[0])));
    float den = logit * 500.f;
    out[row] = den;
    float tgt = (float)targets[(size_t)row*2];
    float nt  = tgt * (1.f/500.f);
    part[wave][0] = (logit-nt)*(logit-nt);
    part[wave][1] = (tgt-den)*(tgt-den);
    part[wave][2] = tgt;
    part[wave][3] = tgt*tgt;
  }
  __syncthreads();
  if(threadIdx.x < 4){
    float t0 = part[0][threadIdx.x] + part[1][threadIdx.x]
             + part[2][threadIdx.x] + part[3][threadIdx.x];
    atomicAdd(&accums[threadIdx.x], t0);
  }
}

__global__ void init_acc(float* accums){ if(threadIdx.x < 4) accums[threadIdx.x] = 0.f; }

__global__ void finalize_kernel(const float* __restrict__ acc, float* __restrict__ out){
  const float n = (float)NTOK;
  out[NTOK]   = acc[0] / n;
  float denom = acc[3] - acc[2]*acc[2]/n;
  out[NTOK+1] = 1.f - acc[1]/denom;
}

// =============================================================================
extern "C" void kernel_launch(void* const* d_in, const int* in_sizes, int n_in,
                              void* d_out, int out_size, void* d_ws, size_t ws_size,
                              hipStream_t stream){
  (void)in_sizes; (void)n_in; (void)out_size; (void)ws_size;
  const int*   idx      = (const int*)  d_in[0];
  const int*   targets  = (const int*)  d_in[1];
  const int*   stn_ix   = (const int*)  d_in[3];
  const float* Wp       = (const float*)d_in[4];
  const float* bp       = (const float*)d_in[5];
  const float* stat_emb = (const float*)d_in[6];
  const float* fire_emb = (const float*)d_in[7];
  const float* ln1_g    = (const float*)d_in[8];
  const float* ln1_b    = (const float*)d_in[9];
  const float* Wq       = (const float*)d_in[10];
  const float* Wk       = (const float*)d_in[11];
  const float* Wv       = (const float*)d_in[12];
  const float* Wo       = (const float*)d_in[13];
  const float* bo       = (const float*)d_in[14];
  const float* ln2_g    = (const float*)d_in[15];
  const float* ln2_b    = (const float*)d_in[16];
  const float* W1       = (const float*)d_in[17];
  const float* b1       = (const float*)d_in[18];
  const float* W2       = (const float*)d_in[19];
  const float* b2       = (const float*)d_in[20];
  const float* lnf_g    = (const float*)d_in[21];
  const float* lnf_b    = (const float*)d_in[22];
  const float* Wh       = (const float*)d_in[23];
  const float* bh       = (const float*)d_in[24];
  float* out = (float*)d_out;

  char* ws = (char*)d_ws;
  float*          x      = (float*)         (ws + 0);
  unsigned short* h      = (unsigned short*)(ws + 56623104);
  unsigned short* qkv    = (unsigned short*)(ws + 84934656);
  unsigned short* obuf   = (unsigned short*)(ws + 169869312);
  unsigned short* ffn    = qkv;
  unsigned short* pm     = (unsigned short*)(ws + 169869312);  // aliases obuf
  int*            fire   = (int*)           (ws + 186384384);
  unsigned short* wp_t   = (unsigned short*)(ws + 186531840);
  float*          pe     = (float*)         (ws + 186703872);
  unsigned short* wqkv_t = (unsigned short*)(ws + 198180864);
  unsigned short* wo_t   = (unsigned short*)(ws + 203489280);
  unsigned short* w1_t   = (unsigned short*)(ws + 205258752);
  unsigned short* w2_t   = (unsigned short*)(ws + 212336640);
  float*          accs   = (float*)         (ws + 219414528);

  const dim3 tb(32,8);
  wt_transpose<<<dim3(12,12,6), tb, 0, stream>>>(Wq, wqkv_t,          384,  384, 442368);
  wt_transpose<<<dim3(12,12,6), tb, 0, stream>>>(Wk, wqkv_t + 147456, 384,  384, 442368);
  wt_transpose<<<dim3(12,12,6), tb, 0, stream>>>(Wv, wqkv_t + 294912, 384,  384, 442368);
  wt_transpose<<<dim3(12,12,6), tb, 0, stream>>>(Wo, wo_t,            384,  384, 147456);
  wt_transpose<<<dim3(48,12,6), tb, 0, stream>>>(W1, w1_t,            384, 1536, 589824);
  wt_transpose<<<dim3(12,48,6), tb, 0, stream>>>(W2, w2_t,           1536,  384, 589824);
  wp_transpose<<<384, 256, 0, stream>>>(Wp, wp_t);
  pe_kernel<<<TBLK, 384, 0, stream>>>(pe);
  prep_pm<<<(NTOK*KPM + 255)/256, 256, 0, stream>>>(idx, pm);
  prep_fire<<<(NTOK + 255)/256, 256, 0, stream>>>(idx, stn_ix, fire);

  // embed GEMM: x = pm @ wp_t^T + (bp + stat + pe + fire_emb)
  gemm_k<2,false><<<dim3(3,288), 256, 0, stream>>>(pm, wp_t, bp, nullptr, x,
      fire, pe, stat_emb, stn_ix, fire_emb, 384, KPM);

  // layer-0 ln1
  ln_bf16<<<NTOK/4, 256, 0, stream>>>(x, ln1_g, ln1_b, h);

  const dim3 gQKV(9, 288);
  const dim3 gF(12, 288);
  for(int l=0; l<NLAYER; l++){
    gemm_k<0,false><<<gQKV, 256, 0, stream>>>(h, wqkv_t + (size_t)l*442368,
        nullptr, qkv, nullptr, nullptr, nullptr, nullptr, nullptr, nullptr, 1152, 384);
    attn_kernel<<<BSZ*NHEAD, 256, 0, stream>>>(qkv, obuf);
    // x += obuf@Wo + bo;  h = LN2(x)
    gemm_row_ln<<<NTOK/64, 256, 0, stream>>>(obuf, wo_t + (size_t)l*147456,
        bo + l*EDIM, x, ln2_g + l*EDIM, ln2_b + l*EDIM, h, 384, 1);
    gemm_k<0,true><<<gF, 256, 0, stream>>>(h, w1_t + (size_t)l*589824,
        b1 + l*1536, ffn, nullptr, nullptr, nullptr, nullptr, nullptr, nullptr, 1536, 384);
    // x += ffn@W2 + b2;  h = LN1[l+1](x)  (skip h on last layer)
    const int wh = (l < NLAYER-1) ? 1 : 0;
    const float* ng = wh ? (ln1_g + (l+1)*EDIM) : lnf_g;
    const float* nb = wh ? (ln1_b + (l+1)*EDIM) : lnf_b;
    gemm_row_ln<<<NTOK/64, 256, 0, stream>>>(ffn, w2_t + (size_t)l*589824,
        b2 + l*EDIM, x, ng, nb, h, 1536, wh);
  }

  init_acc<<<1, 64, 0, stream>>>(accs);
  head_kernel<<<NTOK/4, 256, 0, stream>>>(x, lnf_g, lnf_b, Wh, bh, targets, out, accs);
  finalize_kernel<<<1, 1, 0, stream>>>(accs, out);
}

// Round 4
// 2901.859 us; speedup vs baseline: 1.5922x; 1.0552x over previous
//
#include <hip/hip_runtime.h>
#include <stdint.h>

// PM25 transformer forward, MI355X/gfx950. Round 4:
//   - gemm_row_ln v2: 512 thr (8 waves), double-buffered LDS, single barrier
//     per K-step with prefetch-in-shadow (stage s+1 right after barrier).
//   - gemm_k: same dbuf single-barrier K-loop (LDS 32 KB).
// ws layout unchanged from Round 3.

#define EDIM   384
#define NHEAD  6
#define DHEAD  64
#define NLAYER 6
#define TBLK   36
#define SNUM   210
#define BSZ    1024
#define NTOK   (BSZ*TBLK)
#define QKVSTR 1152
#define KPM    224

typedef __attribute__((ext_vector_type(8))) short short8;
typedef __attribute__((ext_vector_type(4))) float floatx4;

static __device__ __forceinline__ unsigned short f2bf(float f){
  union { float fv; unsigned int u; } v; v.fv = f;
  unsigned int r = v.u + 0x7FFFu + ((v.u >> 16) & 1u);
  return (unsigned short)(r >> 16);
}
static __device__ __forceinline__ float bf2f(unsigned short u){
  union { unsigned int u; float fv; } v; v.u = ((unsigned int)u) << 16;
  return v.fv;
}
static __device__ __forceinline__ void gld_lds16(const void* g, void* l){
  __builtin_amdgcn_global_load_lds(
      (const __attribute__((address_space(1))) void*)g,
      (__attribute__((address_space(3))) void*)l, 16, 0, 0);
}

// ---------------- weight transpose + bf16 cast: out[m][k] = bf16(in[k][m]) ----
__global__ __launch_bounds__(256) void wt_transpose(const float* __restrict__ in,
    unsigned short* __restrict__ out, int K, int M, long outStride){
  __shared__ float tile[32][33];
  const int mat = blockIdx.z;
  const float* src = in + (size_t)mat*K*M;
  unsigned short* dst = out + (size_t)mat*outStride;
  const int m0 = blockIdx.x*32, k0 = blockIdx.y*32;
  const int tx = threadIdx.x, ty = threadIdx.y;
  for(int i=ty;i<32;i+=8) tile[i][tx] = src[(size_t)(k0+i)*M + m0+tx];
  __syncthreads();
  for(int i=ty;i<32;i+=8) dst[(size_t)(m0+i)*K + k0+tx] = f2bf(tile[tx][i]);
}

// Wp [210,384] -> wp_t bf16 [384,224] (K zero-padded 210->224)
__global__ __launch_bounds__(256) void wp_transpose(const float* __restrict__ Wp,
    unsigned short* __restrict__ wp_t){
  const int m = blockIdx.x, k = threadIdx.x;
  if(k < KPM)
    wp_t[(size_t)m*KPM + k] = (k < SNUM) ? f2bf(Wp[(size_t)k*EDIM + m]) : 0;
}

__global__ __launch_bounds__(256) void prep_pm(const int* __restrict__ idx,
    unsigned short* __restrict__ pm){
  const int i = blockIdx.x*256 + threadIdx.x;
  if(i >= NTOK*KPM) return;
  const int row = i / KPM, s = i - row*KPM;
  float v = 0.f;
  if(s < SNUM) v = (float)idx[((size_t)row*SNUM + s)*2] * (1.f/500.f);
  pm[i] = f2bf(v);
}

__global__ __launch_bounds__(256) void prep_fire(const int* __restrict__ idx,
    const int* __restrict__ stn_p, int* __restrict__ fire){
  const int row = blockIdx.x*256 + threadIdx.x;
  if(row < NTOK) fire[row] = idx[((size_t)row*SNUM + stn_p[0])*2 + 1];
}

__global__ __launch_bounds__(384) void pe_kernel(float* __restrict__ pe){
  const int t = blockIdx.x, e = threadIdx.x;
  const float freq = __expf(-(float)(2*(e>>1)) * (9.210340371976184f/384.f));
  const float ang = (float)t * freq;
  pe[t*EDIM + e] = (e & 1) ? __cosf(ang) : __sinf(ang);
}

// ---------------- layernorm fp32 -> bf16 (layer-0 ln1 only) -------------------
__global__ __launch_bounds__(256) void ln_bf16(const float* __restrict__ x,
    const float* __restrict__ g, const float* __restrict__ b,
    unsigned short* __restrict__ out){
  const int wave = threadIdx.x >> 6, lane = threadIdx.x & 63;
  const int row = blockIdx.x*4 + wave;
  const float* xr = x + (size_t)row*EDIM;
  float v[6]; float s=0.f, sq=0.f;
  #pragma unroll
  for(int j=0;j<6;j++){ v[j]=xr[j*64+lane]; s+=v[j]; sq+=v[j]*v[j]; }
  #pragma unroll
  for(int m=1;m<64;m<<=1){ s += __shfl_xor(s,m); sq += __shfl_xor(sq,m); }
  const float mean = s*(1.f/384.f);
  const float var  = sq*(1.f/384.f) - mean*mean;
  const float rstd = rsqrtf(var + 1e-5f);
  unsigned short* orow = out + (size_t)row*EDIM;
  #pragma unroll
  for(int j=0;j<6;j++){
    int e = j*64+lane;
    orow[e] = f2bf((v[j]-mean)*rstd*g[e] + b[e]);
  }
}

// ---------------- bf16 MFMA GEMM, dbuf single-barrier K-loop ------------------
// MODE 0: write bf16 (bias opt, RELU opt).  MODE 2: embed epilogue -> fp32 x.
template<int MODE, bool RELU>
__global__ __launch_bounds__(256) void gemm_k(const unsigned short* __restrict__ A,
    const unsigned short* __restrict__ Wt, const float* __restrict__ bias,
    unsigned short* __restrict__ outb, float* __restrict__ xout,
    const int* __restrict__ fire, const float* __restrict__ pe,
    const float* __restrict__ stat_emb, const int* __restrict__ stn_p,
    const float* __restrict__ fire_emb, int M, int K){
  __shared__ __align__(16) unsigned short As[2][128*32];
  __shared__ __align__(16) unsigned short Bs[2][128*32];
  const int tid  = threadIdx.x;
  const int m0   = blockIdx.x * 128;
  const int n0   = blockIdx.y * 128;
  const int wave = tid >> 6, lane = tid & 63;
  const int wr = wave >> 1, wc = wave & 1;
  const int lrow = lane & 15, quad = lane >> 4;
  floatx4 acc[4][4];
  #pragma unroll
  for(int i=0;i<4;i++)
    #pragma unroll
    for(int j=0;j<4;j++) acc[i][j] = (floatx4){0.f,0.f,0.f,0.f};

  const int S = K >> 5;
  // stage step s into buffer bi
  auto stage = [&](int s, int bi){
    const int kk = s*32;
    #pragma unroll
    for(int p=0;p<2;p++){
      int i = tid + p*256;
      int r = i >> 2, c = (i & 3) * 8;
      gld_lds16(&A [(size_t)(n0+r)*K + kk + c], &As[bi][i*8]);
      gld_lds16(&Wt[(size_t)(m0+r)*K + kk + c], &Bs[bi][i*8]);
    }
  };
  stage(0, 0);
  for(int s=0; s<S; s++){
    const int bi = s & 1;
    __syncthreads();                    // drains stage(s); frees buf bi^1
    if(s+1 < S) stage(s+1, bi^1);       // prefetch in the shadow of compute
    short8 af[4], bfv[4];
    #pragma unroll
    for(int ti=0;ti<4;ti++) af[ti]  = *(const short8*)(&As[bi][(wr*64+ti*16+lrow)*32 + quad*8]);
    #pragma unroll
    for(int tj=0;tj<4;tj++) bfv[tj] = *(const short8*)(&Bs[bi][(wc*64+tj*16+lrow)*32 + quad*8]);
    #pragma unroll
    for(int ti=0;ti<4;ti++)
      #pragma unroll
      for(int tj=0;tj<4;tj++)
        acc[ti][tj] = __builtin_amdgcn_mfma_f32_16x16x32_bf16(af[ti], bfv[tj], acc[ti][tj], 0,0,0);
  }
  const int stn = (MODE==2) ? stn_p[0] : 0;
  #pragma unroll
  for(int ti=0;ti<4;ti++){
    #pragma unroll
    for(int r=0;r<4;r++){
      int row = n0 + wr*64 + ti*16 + quad*4 + r;
      int fidx = 0, trow = 0;
      if(MODE==2){ fidx = fire[row]; trow = row % TBLK; }
      #pragma unroll
      for(int tj=0;tj<4;tj++){
        int col = m0 + wc*64 + tj*16 + lrow;
        float val = acc[ti][tj][r];
        if(MODE==0){
          if(bias) val += bias[col];
          if(RELU) val = fmaxf(val, 0.f);
          outb[(size_t)row*M + col] = f2bf(val);
        } else {
          val += bias[col] + stat_emb[(size_t)stn*EDIM + col]
               + pe[trow*EDIM + col] + fire_emb[(size_t)fidx*EDIM + col];
          xout[(size_t)row*EDIM + col] = val;
        }
      }
    }
  }
}

// ------- full-row GEMM + residual + LayerNorm epilogue, v2 --------------------
// 512 thr (8 waves): wave = rw*2+cw, rw in [0,4) 16-row group, cw in [0,2)
// 192-col half. C[64,384] per block. Double-buffered LDS, 1 barrier/K-step.
__global__ __launch_bounds__(512, 4) void gemm_row_ln(
    const unsigned short* __restrict__ A, const unsigned short* __restrict__ Wt,
    const float* __restrict__ bias, float* __restrict__ x,
    const float* __restrict__ g, const float* __restrict__ b,
    unsigned short* __restrict__ h, int K, int writeH){
  __shared__ __align__(16) unsigned short As[2][64*32];    // 2x4 KB
  __shared__ __align__(16) unsigned short Bs[2][384*32];   // 2x24 KB
  const int tid = threadIdx.x;
  const int n0 = blockIdx.x * 64;
  const int wave = tid >> 6, lane = tid & 63;
  const int rw = wave >> 1, cw = wave & 1;
  const int lrow = lane & 15, quad = lane >> 4;
  floatx4 acc[12];
  #pragma unroll
  for(int j=0;j<12;j++) acc[j] = (floatx4){0.f,0.f,0.f,0.f};

  const int S = K >> 5;
  auto stage = [&](int s, int bi){
    const int kk = s*32;
    if(tid < 256){                       // waves 0-3: A tile (wave-uniform branch)
      int r = tid >> 2, c = (tid & 3) * 8;
      gld_lds16(&A[(size_t)(n0+r)*K + kk + c], &As[bi][tid*8]);
    }
    #pragma unroll
    for(int p=0;p<3;p++){
      int i = tid + p*512;
      int r = i >> 2, c = (i & 3) * 8;
      gld_lds16(&Wt[(size_t)r*K + kk + c], &Bs[bi][i*8]);
    }
  };
  stage(0, 0);
  for(int s=0; s<S; s++){
    const int bi = s & 1;
    __syncthreads();
    if(s+1 < S) stage(s+1, bi^1);
    short8 af = *(const short8*)(&As[bi][(rw*16+lrow)*32 + quad*8]);
    short8 bfv[12];
    #pragma unroll
    for(int tj=0;tj<12;tj++) bfv[tj] = *(const short8*)(&Bs[bi][(cw*192+tj*16+lrow)*32 + quad*8]);
    #pragma unroll
    for(int tj=0;tj<12;tj++)
      acc[tj] = __builtin_amdgcn_mfma_f32_16x16x32_bf16(af, bfv[tj], acc[tj], 0,0,0);
  }
  __syncthreads();                 // safe to reuse As as partials
  float* part = (float*)&As[0][0]; // sums [64][2] @0, squares @128
  // phase 1: residual add + per-wave row partials over its 192 cols
  {
    float ps[4] = {0.f,0.f,0.f,0.f}, pq[4] = {0.f,0.f,0.f,0.f};
    #pragma unroll
    for(int tj=0;tj<12;tj++){
      const int col = cw*192 + tj*16 + lrow;
      const float bi = bias[col];
      #pragma unroll
      for(int r=0;r<4;r++){
        const int row = n0 + rw*16 + quad*4 + r;
        float v = acc[tj][r] + bi + x[(size_t)row*EDIM + col];
        acc[tj][r] = v;
        ps[r] += v; pq[r] += v*v;
      }
    }
    #pragma unroll
    for(int r=0;r<4;r++){
      #pragma unroll
      for(int m=1;m<16;m<<=1){ ps[r] += __shfl_xor(ps[r],m); pq[r] += __shfl_xor(pq[r],m); }
    }
    if(lrow == 0){
      #pragma unroll
      for(int r=0;r<4;r++){
        const int rl = rw*16 + quad*4 + r;
        part[rl*2 + cw]       = ps[r];
        part[128 + rl*2 + cw] = pq[r];
      }
    }
  }
  __syncthreads();
  // phase 2: finalize x + LN -> h
  #pragma unroll
  for(int r=0;r<4;r++){
    const int rl = rw*16 + quad*4 + r;
    const int row = n0 + rl;
    const float s = part[rl*2+0] + part[rl*2+1];
    const float q = part[128+rl*2+0] + part[128+rl*2+1];
    const float mean = s*(1.f/384.f);
    const float var  = q*(1.f/384.f) - mean*mean;
    const float rstd = rsqrtf(var + 1e-5f);
    #pragma unroll
    for(int tj=0;tj<12;tj++){
      const int col = cw*192 + tj*16 + lrow;
      const float v = acc[tj][r];
      x[(size_t)row*EDIM + col] = v;
      if(writeH)
        h[(size_t)row*EDIM + col] = f2bf((v-mean)*rstd*g[col] + b[col]);
    }
  }
}

// ---------------- causal attention: 4 waves/block per (b,h) -------------------
__global__ __launch_bounds__(256) void attn_kernel(const unsigned short* __restrict__ qkv,
    unsigned short* __restrict__ o){
  const int bh = blockIdx.x;
  const int b = bh / NHEAD, h = bh % NHEAD;
  const int wave = threadIdx.x >> 6, lane = threadIdx.x & 63;
  const int tid = threadIdx.x;
  __shared__ float qs[TBLK*64];
  __shared__ float ks[TBLK*65];
  __shared__ float ps[TBLK*64];
  const size_t base = (size_t)b*TBLK*QKVSTR + h*DHEAD;
  const unsigned short* qp = qkv + base;
  const unsigned short* kp = qkv + base + 384;
  const unsigned short* vp = qkv + base + 768;
  for(int i=tid; i<TBLK*64; i+=256){
    int t = i >> 6, dd = i & 63;
    qs[i]          = bf2f(qp[(size_t)t*QKVSTR + dd]);
    ks[t*65 + dd]  = bf2f(kp[(size_t)t*QKVSTR + dd]);
  }
  float vreg[TBLK];
  #pragma unroll
  for(int s2=0;s2<TBLK;s2++) vreg[s2] = bf2f(vp[(size_t)s2*QKVSTR + lane]);
  __syncthreads();
  const int krow = (lane < TBLK) ? lane : (TBLK-1);
  float kreg[64];
  #pragma unroll
  for(int dd=0;dd<64;dd++) kreg[dd] = ks[krow*65 + dd];
  const float scale = 0.125f;
  #pragma unroll
  for(int j=0;j<9;j++){
    const int t = wave + 4*j;
    float d = 0.f;
    #pragma unroll
    for(int gg=0;gg<16;gg++){
      float4 q4 = *(const float4*)&qs[t*64 + gg*4];
      d = fmaf(q4.x, kreg[gg*4+0], d);
      d = fmaf(q4.y, kreg[gg*4+1], d);
      d = fmaf(q4.z, kreg[gg*4+2], d);
      d = fmaf(q4.w, kreg[gg*4+3], d);
    }
    float val = (lane <= t) ? d*scale : -INFINITY;
    float mx = val;
    #pragma unroll
    for(int m=1;m<64;m<<=1) mx = fmaxf(mx, __shfl_xor(mx,m));
    float p = __expf(val - mx);
    float sum = p;
    #pragma unroll
    for(int m=1;m<64;m<<=1) sum += __shfl_xor(sum,m);
    ps[t*64 + lane] = p / sum;
  }
  __syncthreads();
  #pragma unroll
  for(int j=0;j<9;j++){
    const int t = wave + 4*j;
    float acc = 0.f;
    #pragma unroll
    for(int gg=0;gg<9;gg++){
      float4 p4 = *(const float4*)&ps[t*64 + gg*4];
      acc = fmaf(p4.x, vreg[gg*4+0], acc);
      acc = fmaf(p4.y, vreg[gg*4+1], acc);
      acc = fmaf(p4.z, vreg[gg*4+2], acc);
      acc = fmaf(p4.w, vreg[gg*4+3], acc);
    }
    o[(size_t)b*TBLK*EDIM + (size_t)t*EDIM + h*DHEAD + lane] = f2bf(acc);
  }
}

// ---------------- head: LNf + sigmoid(x@Wh+bh)*500 + loss partials ------------
__global__ __launch_bounds__(256) void head_kernel(const float* __restrict__ x,
    const float* __restrict__ g, const float* __restrict__ b,
    const float* __restrict__ Wh, const float* __restrict__ bh,
    const int* __restrict__ targets, float* __restrict__ out,
    float* __restrict__ accums){
  const int wave = threadIdx.x >> 6, lane = threadIdx.x & 63;
  const int row = blockIdx.x*4 + wave;
  const float* xr = x + (size_t)row*EDIM;
  float v[6]; float s=0.f, sq=0.f;
  #pragma unroll
  for(int j=0;j<6;j++){ v[j]=xr[j*64+lane]; s+=v[j]; sq+=v[j]*v[j]; }
  #pragma unroll
  for(int m=1;m<64;m<<=1){ s += __shfl_xor(s,m); sq += __shfl_xor(sq,m); }
  const float mean = s*(1.f/384.f);
  const float var  = sq*(1.f/384.f) - mean*mean;
  const float rstd = rsqrtf(var + 1e-5f);
  float dot = 0.f;
  #pragma unroll
  for(int j=0;j<6;j++){
    int e = j*64+lane;
    float hh = (v[j]-mean)*rstd*g[e] + b[e];
    dot = fmaf(hh, Wh[e], dot);
  }
  #pragma unroll
  for(int m=1;m<64;m<<=1) dot += __shfl_xor(dot,m);
  __shared__ float part[4][4];
  if(lane == 0){
    float logit = 1.f/(1.f + __expf(-(dot + bh[0])));
    float den = logit * 500.f;
    out[row] = den;
    float tgt = (float)targets[(size_t)row*2];
    float nt  = tgt * (1.f/500.f);
    part[wave][0] = (logit-nt)*(logit-nt);
    part[wave][1] = (tgt-den)*(tgt-den);
    part[wave][2] = tgt;
    part[wave][3] = tgt*tgt;
  }
  __syncthreads();
  if(threadIdx.x < 4){
    float t0 = part[0][threadIdx.x] + part[1][threadIdx.x]
             + part[2][threadIdx.x] + part[3][threadIdx.x];
    atomicAdd(&accums[threadIdx.x], t0);
  }
}

__global__ void init_acc(float* accums){ if(threadIdx.x < 4) accums[threadIdx.x] = 0.f; }

__global__ void finalize_kernel(const float* __restrict__ acc, float* __restrict__ out){
  const float n = (float)NTOK;
  out[NTOK]   = acc[0] / n;
  float denom = acc[3] - acc[2]*acc[2]/n;
  out[NTOK+1] = 1.f - acc[1]/denom;
}

// =============================================================================
extern "C" void kernel_launch(void* const* d_in, const int* in_sizes, int n_in,
                              void* d_out, int out_size, void* d_ws, size_t ws_size,
                              hipStream_t stream){
  (void)in_sizes; (void)n_in; (void)out_size; (void)ws_size;
  const int*   idx      = (const int*)  d_in[0];
  const int*   targets  = (const int*)  d_in[1];
  const int*   stn_ix   = (const int*)  d_in[3];
  const float* Wp       = (const float*)d_in[4];
  const float* bp       = (const float*)d_in[5];
  const float* stat_emb = (const float*)d_in[6];
  const float* fire_emb = (const float*)d_in[7];
  const float* ln1_g    = (const float*)d_in[8];
  const float* ln1_b    = (const float*)d_in[9];
  const float* Wq       = (const float*)d_in[10];
  const float* Wk       = (const float*)d_in[11];
  const float* Wv       = (const float*)d_in[12];
  const float* Wo       = (const float*)d_in[13];
  const float* bo       = (const float*)d_in[14];
  const float* ln2_g    = (const float*)d_in[15];
  const float* ln2_b    = (const float*)d_in[16];
  const float* W1       = (const float*)d_in[17];
  const float* b1       = (const float*)d_in[18];
  const float* W2       = (const float*)d_in[19];
  const float* b2       = (const float*)d_in[20];
  const float* lnf_g    = (const float*)d_in[21];
  const float* lnf_b    = (const float*)d_in[22];
  const float* Wh       = (const float*)d_in[23];
  const float* bh       = (const float*)d_in[24];
  float* out = (float*)d_out;

  char* ws = (char*)d_ws;
  float*          x      = (float*)         (ws + 0);
  unsigned short* h      = (unsigned short*)(ws + 56623104);
  unsigned short* qkv    = (unsigned short*)(ws + 84934656);
  unsigned short* obuf   = (unsigned short*)(ws + 169869312);
  unsigned short* ffn    = qkv;
  unsigned short* pm     = (unsigned short*)(ws + 169869312);  // aliases obuf
  int*            fire   = (int*)           (ws + 186384384);
  unsigned short* wp_t   = (unsigned short*)(ws + 186531840);
  float*          pe     = (float*)         (ws + 186703872);
  unsigned short* wqkv_t = (unsigned short*)(ws + 198180864);
  unsigned short* wo_t   = (unsigned short*)(ws + 203489280);
  unsigned short* w1_t   = (unsigned short*)(ws + 205258752);
  unsigned short* w2_t   = (unsigned short*)(ws + 212336640);
  float*          accs   = (float*)         (ws + 219414528);

  const dim3 tb(32,8);
  wt_transpose<<<dim3(12,12,6), tb, 0, stream>>>(Wq, wqkv_t,          384,  384, 442368);
  wt_transpose<<<dim3(12,12,6), tb, 0, stream>>>(Wk, wqkv_t + 147456, 384,  384, 442368);
  wt_transpose<<<dim3(12,12,6), tb, 0, stream>>>(Wv, wqkv_t + 294912, 384,  384, 442368);
  wt_transpose<<<dim3(12,12,6), tb, 0, stream>>>(Wo, wo_t,            384,  384, 147456);
  wt_transpose<<<dim3(48,12,6), tb, 0, stream>>>(W1, w1_t,            384, 1536, 589824);
  wt_transpose<<<dim3(12,48,6), tb, 0, stream>>>(W2, w2_t,           1536,  384, 589824);
  wp_transpose<<<384, 256, 0, stream>>>(Wp, wp_t);
  pe_kernel<<<TBLK, 384, 0, stream>>>(pe);
  prep_pm<<<(NTOK*KPM + 255)/256, 256, 0, stream>>>(idx, pm);
  prep_fire<<<(NTOK + 255)/256, 256, 0, stream>>>(idx, stn_ix, fire);

  // embed GEMM: x = pm @ wp_t^T + (bp + stat + pe + fire_emb)
  gemm_k<2,false><<<dim3(3,288), 256, 0, stream>>>(pm, wp_t, bp, nullptr, x,
      fire, pe, stat_emb, stn_ix, fire_emb, 384, KPM);

  // layer-0 ln1
  ln_bf16<<<NTOK/4, 256, 0, stream>>>(x, ln1_g, ln1_b, h);

  const dim3 gQKV(9, 288);
  const dim3 gF(12, 288);
  for(int l=0; l<NLAYER; l++){
    gemm_k<0,false><<<gQKV, 256, 0, stream>>>(h, wqkv_t + (size_t)l*442368,
        nullptr, qkv, nullptr, nullptr, nullptr, nullptr, nullptr, nullptr, 1152, 384);
    attn_kernel<<<BSZ*NHEAD, 256, 0, stream>>>(qkv, obuf);
    // x += obuf@Wo + bo;  h = LN2(x)
    gemm_row_ln<<<NTOK/64, 512, 0, stream>>>(obuf, wo_t + (size_t)l*147456,
        bo + l*EDIM, x, ln2_g + l*EDIM, ln2_b + l*EDIM, h, 384, 1);
    gemm_k<0,true><<<gF, 256, 0, stream>>>(h, w1_t + (size_t)l*589824,
        b1 + l*1536, ffn, nullptr, nullptr, nullptr, nullptr, nullptr, nullptr, 1536, 384);
    // x += ffn@W2 + b2;  h = LN1[l+1](x)  (skip h on last layer)
    const int wh = (l < NLAYER-1) ? 1 : 0;
    const float* ng = wh ? (ln1_g + (l+1)*EDIM) : lnf_g;
    const float* nb = wh ? (ln1_b + (l+1)*EDIM) : lnf_b;
    gemm_row_ln<<<NTOK/64, 512, 0, stream>>>(ffn, w2_t + (size_t)l*589824,
        b2 + l*EDIM, x, ng, nb, h, 1536, wh);
  }

  init_acc<<<1, 64, 0, stream>>>(accs);
  head_kernel<<<NTOK/4, 256, 0, stream>>>(x, lnf_g, lnf_b, Wh, bh, targets, out, accs);
  finalize_kernel<<<1, 1, 0, stream>>>(accs, out);
}

// Round 5
// 2790.399 us; speedup vs baseline: 1.6558x; 1.0399x over previous
//
#include <hip/hip_runtime.h>
#include <stdint.h>

// PM25 transformer forward, MI355X/gfx950. Round 5:
//   - W2 GEMM back to proven m97 128x128 shape (gemm_k, dbuf, 16 MFMA/wave/step)
//     with fp32 residual epilogue; standalone ln_bf16 after it (skipped on last
//     layer). gemm_row_ln (512-thr dbuf) retained for Wo only (K=384, a wash).
// ws layout unchanged from Round 3/4.

#define EDIM   384
#define NHEAD  6
#define DHEAD  64
#define NLAYER 6
#define TBLK   36
#define SNUM   210
#define BSZ    1024
#define NTOK   (BSZ*TBLK)
#define QKVSTR 1152
#define KPM    224

typedef __attribute__((ext_vector_type(8))) short short8;
typedef __attribute__((ext_vector_type(4))) float floatx4;

static __device__ __forceinline__ unsigned short f2bf(float f){
  union { float fv; unsigned int u; } v; v.fv = f;
  unsigned int r = v.u + 0x7FFFu + ((v.u >> 16) & 1u);
  return (unsigned short)(r >> 16);
}
static __device__ __forceinline__ float bf2f(unsigned short u){
  union { unsigned int u; float fv; } v; v.u = ((unsigned int)u) << 16;
  return v.fv;
}
static __device__ __forceinline__ void gld_lds16(const void* g, void* l){
  __builtin_amdgcn_global_load_lds(
      (const __attribute__((address_space(1))) void*)g,
      (__attribute__((address_space(3))) void*)l, 16, 0, 0);
}

// ---------------- weight transpose + bf16 cast: out[m][k] = bf16(in[k][m]) ----
__global__ __launch_bounds__(256) void wt_transpose(const float* __restrict__ in,
    unsigned short* __restrict__ out, int K, int M, long outStride){
  __shared__ float tile[32][33];
  const int mat = blockIdx.z;
  const float* src = in + (size_t)mat*K*M;
  unsigned short* dst = out + (size_t)mat*outStride;
  const int m0 = blockIdx.x*32, k0 = blockIdx.y*32;
  const int tx = threadIdx.x, ty = threadIdx.y;
  for(int i=ty;i<32;i+=8) tile[i][tx] = src[(size_t)(k0+i)*M + m0+tx];
  __syncthreads();
  for(int i=ty;i<32;i+=8) dst[(size_t)(m0+i)*K + k0+tx] = f2bf(tile[tx][i]);
}

// Wp [210,384] -> wp_t bf16 [384,224] (K zero-padded 210->224)
__global__ __launch_bounds__(256) void wp_transpose(const float* __restrict__ Wp,
    unsigned short* __restrict__ wp_t){
  const int m = blockIdx.x, k = threadIdx.x;
  if(k < KPM)
    wp_t[(size_t)m*KPM + k] = (k < SNUM) ? f2bf(Wp[(size_t)k*EDIM + m]) : 0;
}

__global__ __launch_bounds__(256) void prep_pm(const int* __restrict__ idx,
    unsigned short* __restrict__ pm){
  const int i = blockIdx.x*256 + threadIdx.x;
  if(i >= NTOK*KPM) return;
  const int row = i / KPM, s = i - row*KPM;
  float v = 0.f;
  if(s < SNUM) v = (float)idx[((size_t)row*SNUM + s)*2] * (1.f/500.f);
  pm[i] = f2bf(v);
}

__global__ __launch_bounds__(256) void prep_fire(const int* __restrict__ idx,
    const int* __restrict__ stn_p, int* __restrict__ fire){
  const int row = blockIdx.x*256 + threadIdx.x;
  if(row < NTOK) fire[row] = idx[((size_t)row*SNUM + stn_p[0])*2 + 1];
}

__global__ __launch_bounds__(384) void pe_kernel(float* __restrict__ pe){
  const int t = blockIdx.x, e = threadIdx.x;
  const float freq = __expf(-(float)(2*(e>>1)) * (9.210340371976184f/384.f));
  const float ang = (float)t * freq;
  pe[t*EDIM + e] = (e & 1) ? __cosf(ang) : __sinf(ang);
}

// ---------------- layernorm fp32 -> bf16, one wave per row --------------------
__global__ __launch_bounds__(256) void ln_bf16(const float* __restrict__ x,
    const float* __restrict__ g, const float* __restrict__ b,
    unsigned short* __restrict__ out){
  const int wave = threadIdx.x >> 6, lane = threadIdx.x & 63;
  const int row = blockIdx.x*4 + wave;
  const float* xr = x + (size_t)row*EDIM;
  float v[6]; float s=0.f, sq=0.f;
  #pragma unroll
  for(int j=0;j<6;j++){ v[j]=xr[j*64+lane]; s+=v[j]; sq+=v[j]*v[j]; }
  #pragma unroll
  for(int m=1;m<64;m<<=1){ s += __shfl_xor(s,m); sq += __shfl_xor(sq,m); }
  const float mean = s*(1.f/384.f);
  const float var  = sq*(1.f/384.f) - mean*mean;
  const float rstd = rsqrtf(var + 1e-5f);
  unsigned short* orow = out + (size_t)row*EDIM;
  #pragma unroll
  for(int j=0;j<6;j++){
    int e = j*64+lane;
    orow[e] = f2bf((v[j]-mean)*rstd*g[e] + b[e]);
  }
}

// ---------------- bf16 MFMA GEMM, m97 128x128 shape, dbuf ---------------------
// MODE 0: write bf16 (bias opt, RELU opt).
// MODE 1: fp32 residual accumulate: x[row][col] += val + bias.
// MODE 2: embed epilogue -> fp32 x.
template<int MODE, bool RELU>
__global__ __launch_bounds__(256) void gemm_k(const unsigned short* __restrict__ A,
    const unsigned short* __restrict__ Wt, const float* __restrict__ bias,
    unsigned short* __restrict__ outb, float* __restrict__ xout,
    const int* __restrict__ fire, const float* __restrict__ pe,
    const float* __restrict__ stat_emb, const int* __restrict__ stn_p,
    const float* __restrict__ fire_emb, int M, int K){
  __shared__ __align__(16) unsigned short As[2][128*32];
  __shared__ __align__(16) unsigned short Bs[2][128*32];
  const int tid  = threadIdx.x;
  const int m0   = blockIdx.x * 128;
  const int n0   = blockIdx.y * 128;
  const int wave = tid >> 6, lane = tid & 63;
  const int wr = wave >> 1, wc = wave & 1;
  const int lrow = lane & 15, quad = lane >> 4;
  floatx4 acc[4][4];
  #pragma unroll
  for(int i=0;i<4;i++)
    #pragma unroll
    for(int j=0;j<4;j++) acc[i][j] = (floatx4){0.f,0.f,0.f,0.f};

  const int S = K >> 5;
  auto stage = [&](int s, int bi){
    const int kk = s*32;
    #pragma unroll
    for(int p=0;p<2;p++){
      int i = tid + p*256;
      int r = i >> 2, c = (i & 3) * 8;
      gld_lds16(&A [(size_t)(n0+r)*K + kk + c], &As[bi][i*8]);
      gld_lds16(&Wt[(size_t)(m0+r)*K + kk + c], &Bs[bi][i*8]);
    }
  };
  stage(0, 0);
  for(int s=0; s<S; s++){
    const int bi = s & 1;
    __syncthreads();
    if(s+1 < S) stage(s+1, bi^1);
    short8 af[4], bfv[4];
    #pragma unroll
    for(int ti=0;ti<4;ti++) af[ti]  = *(const short8*)(&As[bi][(wr*64+ti*16+lrow)*32 + quad*8]);
    #pragma unroll
    for(int tj=0;tj<4;tj++) bfv[tj] = *(const short8*)(&Bs[bi][(wc*64+tj*16+lrow)*32 + quad*8]);
    #pragma unroll
    for(int ti=0;ti<4;ti++)
      #pragma unroll
      for(int tj=0;tj<4;tj++)
        acc[ti][tj] = __builtin_amdgcn_mfma_f32_16x16x32_bf16(af[ti], bfv[tj], acc[ti][tj], 0,0,0);
  }
  const int stn = (MODE==2) ? stn_p[0] : 0;
  #pragma unroll
  for(int ti=0;ti<4;ti++){
    #pragma unroll
    for(int r=0;r<4;r++){
      int row = n0 + wr*64 + ti*16 + quad*4 + r;
      int fidx = 0, trow = 0;
      if(MODE==2){ fidx = fire[row]; trow = row % TBLK; }
      #pragma unroll
      for(int tj=0;tj<4;tj++){
        int col = m0 + wc*64 + tj*16 + lrow;
        float val = acc[ti][tj][r];
        if(MODE==0){
          if(bias) val += bias[col];
          if(RELU) val = fmaxf(val, 0.f);
          outb[(size_t)row*M + col] = f2bf(val);
        } else if(MODE==1){
          xout[(size_t)row*EDIM + col] += val + bias[col];
        } else {
          val += bias[col] + stat_emb[(size_t)stn*EDIM + col]
               + pe[trow*EDIM + col] + fire_emb[(size_t)fidx*EDIM + col];
          xout[(size_t)row*EDIM + col] = val;
        }
      }
    }
  }
}

// ------- full-row GEMM + residual + LayerNorm epilogue (Wo only, K=384) -------
// 512 thr (8 waves): rw in [0,4) 16-row group, cw in [0,2) 192-col half.
__global__ __launch_bounds__(512, 4) void gemm_row_ln(
    const unsigned short* __restrict__ A, const unsigned short* __restrict__ Wt,
    const float* __restrict__ bias, float* __restrict__ x,
    const float* __restrict__ g, const float* __restrict__ b,
    unsigned short* __restrict__ h, int K, int writeH){
  __shared__ __align__(16) unsigned short As[2][64*32];
  __shared__ __align__(16) unsigned short Bs[2][384*32];
  const int tid = threadIdx.x;
  const int n0 = blockIdx.x * 64;
  const int wave = tid >> 6, lane = tid & 63;
  const int rw = wave >> 1, cw = wave & 1;
  const int lrow = lane & 15, quad = lane >> 4;
  floatx4 acc[12];
  #pragma unroll
  for(int j=0;j<12;j++) acc[j] = (floatx4){0.f,0.f,0.f,0.f};

  const int S = K >> 5;
  auto stage = [&](int s, int bi){
    const int kk = s*32;
    if(tid < 256){
      int r = tid >> 2, c = (tid & 3) * 8;
      gld_lds16(&A[(size_t)(n0+r)*K + kk + c], &As[bi][tid*8]);
    }
    #pragma unroll
    for(int p=0;p<3;p++){
      int i = tid + p*512;
      int r = i >> 2, c = (i & 3) * 8;
      gld_lds16(&Wt[(size_t)r*K + kk + c], &Bs[bi][i*8]);
    }
  };
  stage(0, 0);
  for(int s=0; s<S; s++){
    const int bi = s & 1;
    __syncthreads();
    if(s+1 < S) stage(s+1, bi^1);
    short8 af = *(const short8*)(&As[bi][(rw*16+lrow)*32 + quad*8]);
    short8 bfv[12];
    #pragma unroll
    for(int tj=0;tj<12;tj++) bfv[tj] = *(const short8*)(&Bs[bi][(cw*192+tj*16+lrow)*32 + quad*8]);
    #pragma unroll
    for(int tj=0;tj<12;tj++)
      acc[tj] = __builtin_amdgcn_mfma_f32_16x16x32_bf16(af, bfv[tj], acc[tj], 0,0,0);
  }
  __syncthreads();
  float* part = (float*)&As[0][0];
  {
    float ps[4] = {0.f,0.f,0.f,0.f}, pq[4] = {0.f,0.f,0.f,0.f};
    #pragma unroll
    for(int tj=0;tj<12;tj++){
      const int col = cw*192 + tj*16 + lrow;
      const float bi = bias[col];
      #pragma unroll
      for(int r=0;r<4;r++){
        const int row = n0 + rw*16 + quad*4 + r;
        float v = acc[tj][r] + bi + x[(size_t)row*EDIM + col];
        acc[tj][r] = v;
        ps[r] += v; pq[r] += v*v;
      }
    }
    #pragma unroll
    for(int r=0;r<4;r++){
      #pragma unroll
      for(int m=1;m<16;m<<=1){ ps[r] += __shfl_xor(ps[r],m); pq[r] += __shfl_xor(pq[r],m); }
    }
    if(lrow == 0){
      #pragma unroll
      for(int r=0;r<4;r++){
        const int rl = rw*16 + quad*4 + r;
        part[rl*2 + cw]       = ps[r];
        part[128 + rl*2 + cw] = pq[r];
      }
    }
  }
  __syncthreads();
  #pragma unroll
  for(int r=0;r<4;r++){
    const int rl = rw*16 + quad*4 + r;
    const int row = n0 + rl;
    const float s = part[rl*2+0] + part[rl*2+1];
    const float q = part[128+rl*2+0] + part[128+rl*2+1];
    const float mean = s*(1.f/384.f);
    const float var  = q*(1.f/384.f) - mean*mean;
    const float rstd = rsqrtf(var + 1e-5f);
    #pragma unroll
    for(int tj=0;tj<12;tj++){
      const int col = cw*192 + tj*16 + lrow;
      const float v = acc[tj][r];
      x[(size_t)row*EDIM + col] = v;
      if(writeH)
        h[(size_t)row*EDIM + col] = f2bf((v-mean)*rstd*g[col] + b[col]);
    }
  }
}

// ---------------- causal attention: 4 waves/block per (b,h) -------------------
__global__ __launch_bounds__(256) void attn_kernel(const unsigned short* __restrict__ qkv,
    unsigned short* __restrict__ o){
  const int bh = blockIdx.x;
  const int b = bh / NHEAD, h = bh % NHEAD;
  const int wave = threadIdx.x >> 6, lane = threadIdx.x & 63;
  const int tid = threadIdx.x;
  __shared__ float qs[TBLK*64];
  __shared__ float ks[TBLK*65];
  __shared__ float ps[TBLK*64];
  const size_t base = (size_t)b*TBLK*QKVSTR + h*DHEAD;
  const unsigned short* qp = qkv + base;
  const unsigned short* kp = qkv + base + 384;
  const unsigned short* vp = qkv + base + 768;
  for(int i=tid; i<TBLK*64; i+=256){
    int t = i >> 6, dd = i & 63;
    qs[i]          = bf2f(qp[(size_t)t*QKVSTR + dd]);
    ks[t*65 + dd]  = bf2f(kp[(size_t)t*QKVSTR + dd]);
  }
  float vreg[TBLK];
  #pragma unroll
  for(int s2=0;s2<TBLK;s2++) vreg[s2] = bf2f(vp[(size_t)s2*QKVSTR + lane]);
  __syncthreads();
  const int krow = (lane < TBLK) ? lane : (TBLK-1);
  float kreg[64];
  #pragma unroll
  for(int dd=0;dd<64;dd++) kreg[dd] = ks[krow*65 + dd];
  const float scale = 0.125f;
  #pragma unroll
  for(int j=0;j<9;j++){
    const int t = wave + 4*j;
    float d = 0.f;
    #pragma unroll
    for(int gg=0;gg<16;gg++){
      float4 q4 = *(const float4*)&qs[t*64 + gg*4];
      d = fmaf(q4.x, kreg[gg*4+0], d);
      d = fmaf(q4.y, kreg[gg*4+1], d);
      d = fmaf(q4.z, kreg[gg*4+2], d);
      d = fmaf(q4.w, kreg[gg*4+3], d);
    }
    float val = (lane <= t) ? d*scale : -INFINITY;
    float mx = val;
    #pragma unroll
    for(int m=1;m<64;m<<=1) mx = fmaxf(mx, __shfl_xor(mx,m));
    float p = __expf(val - mx);
    float sum = p;
    #pragma unroll
    for(int m=1;m<64;m<<=1) sum += __shfl_xor(sum,m);
    ps[t*64 + lane] = p / sum;
  }
  __syncthreads();
  #pragma unroll
  for(int j=0;j<9;j++){
    const int t = wave + 4*j;
    float acc = 0.f;
    #pragma unroll
    for(int gg=0;gg<9;gg++){
      float4 p4 = *(const float4*)&ps[t*64 + gg*4];
      acc = fmaf(p4.x, vreg[gg*4+0], acc);
      acc = fmaf(p4.y, vreg[gg*4+1], acc);
      acc = fmaf(p4.z, vreg[gg*4+2], acc);
      acc = fmaf(p4.w, vreg[gg*4+3], acc);
    }
    o[(size_t)b*TBLK*EDIM + (size_t)t*EDIM + h*DHEAD + lane] = f2bf(acc);
  }
}

// ---------------- head: LNf + sigmoid(x@Wh+bh)*500 + loss partials ------------
__global__ __launch_bounds__(256) void head_kernel(const float* __restrict__ x,
    const float* __restrict__ g, const float* __restrict__ b,
    const float* __restrict__ Wh, const float* __restrict__ bh,
    const int* __restrict__ targets, float* __restrict__ out,
    float* __restrict__ accums){
  const int wave = threadIdx.x >> 6, lane = threadIdx.x & 63;
  const int row = blockIdx.x*4 + wave;
  const float* xr = x + (size_t)row*EDIM;
  float v[6]; float s=0.f, sq=0.f;
  #pragma unroll
  for(int j=0;j<6;j++){ v[j]=xr[j*64+lane]; s+=v[j]; sq+=v[j]*v[j]; }
  #pragma unroll
  for(int m=1;m<64;m<<=1){ s += __shfl_xor(s,m); sq += __shfl_xor(sq,m); }
  const float mean = s*(1.f/384.f);
  const float var  = sq*(1.f/384.f) - mean*mean;
  const float rstd = rsqrtf(var + 1e-5f);
  float dot = 0.f;
  #pragma unroll
  for(int j=0;j<6;j++){
    int e = j*64+lane;
    float hh = (v[j]-mean)*rstd*g[e] + b[e];
    dot = fmaf(hh, Wh[e], dot);
  }
  #pragma unroll
  for(int m=1;m<64;m<<=1) dot += __shfl_xor(dot,m);
  __shared__ float part[4][4];
  if(lane == 0){
    float logit = 1.f/(1.f + __expf(-(dot + bh[0])));
    float den = logit * 500.f;
    out[row] = den;
    float tgt = (float)targets[(size_t)row*2];
    float nt  = tgt * (1.f/500.f);
    part[wave][0] = (logit-nt)*(logit-nt);
    part[wave][1] = (tgt-den)*(tgt-den);
    part[wave][2] = tgt;
    part[wave][3] = tgt*tgt;
  }
  __syncthreads();
  if(threadIdx.x < 4){
    float t0 = part[0][threadIdx.x] + part[1][threadIdx.x]
             + part[2][threadIdx.x] + part[3][threadIdx.x];
    atomicAdd(&accums[threadIdx.x], t0);
  }
}

__global__ void init_acc(float* accums){ if(threadIdx.x < 4) accums[threadIdx.x] = 0.f; }

__global__ void finalize_kernel(const float* __restrict__ acc, float* __restrict__ out){
  const float n = (float)NTOK;
  out[NTOK]   = acc[0] / n;
  float denom = acc[3] - acc[2]*acc[2]/n;
  out[NTOK+1] = 1.f - acc[1]/denom;
}

// =============================================================================
extern "C" void kernel_launch(void* const* d_in, const int* in_sizes, int n_in,
                              void* d_out, int out_size, void* d_ws, size_t ws_size,
                              hipStream_t stream){
  (void)in_sizes; (void)n_in; (void)out_size; (void)ws_size;
  const int*   idx      = (const int*)  d_in[0];
  const int*   targets  = (const int*)  d_in[1];
  const int*   stn_ix   = (const int*)  d_in[3];
  const float* Wp       = (const float*)d_in[4];
  const float* bp       = (const float*)d_in[5];
  const float* stat_emb = (const float*)d_in[6];
  const float* fire_emb = (const float*)d_in[7];
  const float* ln1_g    = (const float*)d_in[8];
  const float* ln1_b    = (const float*)d_in[9];
  const float* Wq       = (const float*)d_in[10];
  const float* Wk       = (const float*)d_in[11];
  const float* Wv       = (const float*)d_in[12];
  const float* Wo       = (const float*)d_in[13];
  const float* bo       = (const float*)d_in[14];
  const float* ln2_g    = (const float*)d_in[15];
  const float* ln2_b    = (const float*)d_in[16];
  const float* W1       = (const float*)d_in[17];
  const float* b1       = (const float*)d_in[18];
  const float* W2       = (const float*)d_in[19];
  const float* b2       = (const float*)d_in[20];
  const float* lnf_g    = (const float*)d_in[21];
  const float* lnf_b    = (const float*)d_in[22];
  const float* Wh       = (const float*)d_in[23];
  const float* bh       = (const float*)d_in[24];
  float* out = (float*)d_out;

  char* ws = (char*)d_ws;
  float*          x      = (float*)         (ws + 0);
  unsigned short* h      = (unsigned short*)(ws + 56623104);
  unsigned short* qkv    = (unsigned short*)(ws + 84934656);
  unsigned short* obuf   = (unsigned short*)(ws + 169869312);
  unsigned short* ffn    = qkv;
  unsigned short* pm     = (unsigned short*)(ws + 169869312);  // aliases obuf
  int*            fire   = (int*)           (ws + 186384384);
  unsigned short* wp_t   = (unsigned short*)(ws + 186531840);
  float*          pe     = (float*)         (ws + 186703872);
  unsigned short* wqkv_t = (unsigned short*)(ws + 198180864);
  unsigned short* wo_t   = (unsigned short*)(ws + 203489280);
  unsigned short* w1_t   = (unsigned short*)(ws + 205258752);
  unsigned short* w2_t   = (unsigned short*)(ws + 212336640);
  float*          accs   = (float*)         (ws + 219414528);

  const dim3 tb(32,8);
  wt_transpose<<<dim3(12,12,6), tb, 0, stream>>>(Wq, wqkv_t,          384,  384, 442368);
  wt_transpose<<<dim3(12,12,6), tb, 0, stream>>>(Wk, wqkv_t + 147456, 384,  384, 442368);
  wt_transpose<<<dim3(12,12,6), tb, 0, stream>>>(Wv, wqkv_t + 294912, 384,  384, 442368);
  wt_transpose<<<dim3(12,12,6), tb, 0, stream>>>(Wo, wo_t,            384,  384, 147456);
  wt_transpose<<<dim3(48,12,6), tb, 0, stream>>>(W1, w1_t,            384, 1536, 589824);
  wt_transpose<<<dim3(12,48,6), tb, 0, stream>>>(W2, w2_t,           1536,  384, 589824);
  wp_transpose<<<384, 256, 0, stream>>>(Wp, wp_t);
  pe_kernel<<<TBLK, 384, 0, stream>>>(pe);
  prep_pm<<<(NTOK*KPM + 255)/256, 256, 0, stream>>>(idx, pm);
  prep_fire<<<(NTOK + 255)/256, 256, 0, stream>>>(idx, stn_ix, fire);

  // embed GEMM: x = pm @ wp_t^T + (bp + stat + pe + fire_emb)
  gemm_k<2,false><<<dim3(3,288), 256, 0, stream>>>(pm, wp_t, bp, nullptr, x,
      fire, pe, stat_emb, stn_ix, fire_emb, 384, KPM);

  // layer-0 ln1
  ln_bf16<<<NTOK/4, 256, 0, stream>>>(x, ln1_g, ln1_b, h);

  const dim3 gQKV(9, 288);
  const dim3 gE(3, 288);
  const dim3 gF(12, 288);
  for(int l=0; l<NLAYER; l++){
    gemm_k<0,false><<<gQKV, 256, 0, stream>>>(h, wqkv_t + (size_t)l*442368,
        nullptr, qkv, nullptr, nullptr, nullptr, nullptr, nullptr, nullptr, 1152, 384);
    attn_kernel<<<BSZ*NHEAD, 256, 0, stream>>>(qkv, obuf);
    // x += obuf@Wo + bo;  h = LN2(x)   (fused; K=384)
    gemm_row_ln<<<NTOK/64, 512, 0, stream>>>(obuf, wo_t + (size_t)l*147456,
        bo + l*EDIM, x, ln2_g + l*EDIM, ln2_b + l*EDIM, h, 384, 1);
    gemm_k<0,true><<<gF, 256, 0, stream>>>(h, w1_t + (size_t)l*589824,
        b1 + l*1536, ffn, nullptr, nullptr, nullptr, nullptr, nullptr, nullptr, 1536, 384);
    // x += ffn@W2 + b2   (m97-shape gemm_k, fp32 residual epilogue)
    gemm_k<1,false><<<gE, 256, 0, stream>>>(ffn, w2_t + (size_t)l*589824,
        b2 + l*EDIM, nullptr, x, nullptr, nullptr, nullptr, nullptr, nullptr, 384, 1536);
    // h = LN1[l+1](x)  (skip on last layer; head does LNf itself)
    if(l < NLAYER-1)
      ln_bf16<<<NTOK/4, 256, 0, stream>>>(x, ln1_g + (l+1)*EDIM, ln1_b + (l+1)*EDIM, h);
  }

  init_acc<<<1, 64, 0, stream>>>(accs);
  head_kernel<<<NTOK/4, 256, 0, stream>>>(x, lnf_g, lnf_b, Wh, bh, targets, out, accs);
  finalize_kernel<<<1, 1, 0, stream>>>(accs, out);
}

// Round 6
// 2685.119 us; speedup vs baseline: 1.7207x; 1.0392x over previous
//
#include <hip/hip_runtime.h>
#include <stdint.h>

// PM25 transformer forward, MI355X/gfx950. Round 6:
//   - head_kernel: atomicAdd x4 to shared scalars (36864 serialized device-scope
//     atomics ~= 115 us, measured R5) replaced by per-block partials ->
//     finalize_reduce (1024-thr single block). init_acc/finalize merged away.
// ws layout unchanged; partials[4][9216] aliases obuf region (free at head time).

#define EDIM   384
#define NHEAD  6
#define DHEAD  64
#define NLAYER 6
#define TBLK   36
#define SNUM   210
#define BSZ    1024
#define NTOK   (BSZ*TBLK)
#define QKVSTR 1152
#define KPM    224
#define NHBLK  (NTOK/4)   // head blocks = 9216

typedef __attribute__((ext_vector_type(8))) short short8;
typedef __attribute__((ext_vector_type(4))) float floatx4;

static __device__ __forceinline__ unsigned short f2bf(float f){
  union { float fv; unsigned int u; } v; v.fv = f;
  unsigned int r = v.u + 0x7FFFu + ((v.u >> 16) & 1u);
  return (unsigned short)(r >> 16);
}
static __device__ __forceinline__ float bf2f(unsigned short u){
  union { unsigned int u; float fv; } v; v.u = ((unsigned int)u) << 16;
  return v.fv;
}
static __device__ __forceinline__ void gld_lds16(const void* g, void* l){
  __builtin_amdgcn_global_load_lds(
      (const __attribute__((address_space(1))) void*)g,
      (__attribute__((address_space(3))) void*)l, 16, 0, 0);
}

// ---------------- weight transpose + bf16 cast: out[m][k] = bf16(in[k][m]) ----
__global__ __launch_bounds__(256) void wt_transpose(const float* __restrict__ in,
    unsigned short* __restrict__ out, int K, int M, long outStride){
  __shared__ float tile[32][33];
  const int mat = blockIdx.z;
  const float* src = in + (size_t)mat*K*M;
  unsigned short* dst = out + (size_t)mat*outStride;
  const int m0 = blockIdx.x*32, k0 = blockIdx.y*32;
  const int tx = threadIdx.x, ty = threadIdx.y;
  for(int i=ty;i<32;i+=8) tile[i][tx] = src[(size_t)(k0+i)*M + m0+tx];
  __syncthreads();
  for(int i=ty;i<32;i+=8) dst[(size_t)(m0+i)*K + k0+tx] = f2bf(tile[tx][i]);
}

// Wp [210,384] -> wp_t bf16 [384,224] (K zero-padded 210->224)
__global__ __launch_bounds__(256) void wp_transpose(const float* __restrict__ Wp,
    unsigned short* __restrict__ wp_t){
  const int m = blockIdx.x, k = threadIdx.x;
  if(k < KPM)
    wp_t[(size_t)m*KPM + k] = (k < SNUM) ? f2bf(Wp[(size_t)k*EDIM + m]) : 0;
}

__global__ __launch_bounds__(256) void prep_pm(const int* __restrict__ idx,
    unsigned short* __restrict__ pm){
  const int i = blockIdx.x*256 + threadIdx.x;
  if(i >= NTOK*KPM) return;
  const int row = i / KPM, s = i - row*KPM;
  float v = 0.f;
  if(s < SNUM) v = (float)idx[((size_t)row*SNUM + s)*2] * (1.f/500.f);
  pm[i] = f2bf(v);
}

__global__ __launch_bounds__(256) void prep_fire(const int* __restrict__ idx,
    const int* __restrict__ stn_p, int* __restrict__ fire){
  const int row = blockIdx.x*256 + threadIdx.x;
  if(row < NTOK) fire[row] = idx[((size_t)row*SNUM + stn_p[0])*2 + 1];
}

__global__ __launch_bounds__(384) void pe_kernel(float* __restrict__ pe){
  const int t = blockIdx.x, e = threadIdx.x;
  const float freq = __expf(-(float)(2*(e>>1)) * (9.210340371976184f/384.f));
  const float ang = (float)t * freq;
  pe[t*EDIM + e] = (e & 1) ? __cosf(ang) : __sinf(ang);
}

// ---------------- layernorm fp32 -> bf16, one wave per row --------------------
__global__ __launch_bounds__(256) void ln_bf16(const float* __restrict__ x,
    const float* __restrict__ g, const float* __restrict__ b,
    unsigned short* __restrict__ out){
  const int wave = threadIdx.x >> 6, lane = threadIdx.x & 63;
  const int row = blockIdx.x*4 + wave;
  const float* xr = x + (size_t)row*EDIM;
  float v[6]; float s=0.f, sq=0.f;
  #pragma unroll
  for(int j=0;j<6;j++){ v[j]=xr[j*64+lane]; s+=v[j]; sq+=v[j]*v[j]; }
  #pragma unroll
  for(int m=1;m<64;m<<=1){ s += __shfl_xor(s,m); sq += __shfl_xor(sq,m); }
  const float mean = s*(1.f/384.f);
  const float var  = sq*(1.f/384.f) - mean*mean;
  const float rstd = rsqrtf(var + 1e-5f);
  unsigned short* orow = out + (size_t)row*EDIM;
  #pragma unroll
  for(int j=0;j<6;j++){
    int e = j*64+lane;
    orow[e] = f2bf((v[j]-mean)*rstd*g[e] + b[e]);
  }
}

// ---------------- bf16 MFMA GEMM, m97 128x128 shape, dbuf ---------------------
// MODE 0: write bf16 (bias opt, RELU opt).
// MODE 1: fp32 residual accumulate: x[row][col] += val + bias.
// MODE 2: embed epilogue -> fp32 x.
template<int MODE, bool RELU>
__global__ __launch_bounds__(256) void gemm_k(const unsigned short* __restrict__ A,
    const unsigned short* __restrict__ Wt, const float* __restrict__ bias,
    unsigned short* __restrict__ outb, float* __restrict__ xout,
    const int* __restrict__ fire, const float* __restrict__ pe,
    const float* __restrict__ stat_emb, const int* __restrict__ stn_p,
    const float* __restrict__ fire_emb, int M, int K){
  __shared__ __align__(16) unsigned short As[2][128*32];
  __shared__ __align__(16) unsigned short Bs[2][128*32];
  const int tid  = threadIdx.x;
  const int m0   = blockIdx.x * 128;
  const int n0   = blockIdx.y * 128;
  const int wave = tid >> 6, lane = tid & 63;
  const int wr = wave >> 1, wc = wave & 1;
  const int lrow = lane & 15, quad = lane >> 4;
  floatx4 acc[4][4];
  #pragma unroll
  for(int i=0;i<4;i++)
    #pragma unroll
    for(int j=0;j<4;j++) acc[i][j] = (floatx4){0.f,0.f,0.f,0.f};

  const int S = K >> 5;
  auto stage = [&](int s, int bi){
    const int kk = s*32;
    #pragma unroll
    for(int p=0;p<2;p++){
      int i = tid + p*256;
      int r = i >> 2, c = (i & 3) * 8;
      gld_lds16(&A [(size_t)(n0+r)*K + kk + c], &As[bi][i*8]);
      gld_lds16(&Wt[(size_t)(m0+r)*K + kk + c], &Bs[bi][i*8]);
    }
  };
  stage(0, 0);
  for(int s=0; s<S; s++){
    const int bi = s & 1;
    __syncthreads();
    if(s+1 < S) stage(s+1, bi^1);
    short8 af[4], bfv[4];
    #pragma unroll
    for(int ti=0;ti<4;ti++) af[ti]  = *(const short8*)(&As[bi][(wr*64+ti*16+lrow)*32 + quad*8]);
    #pragma unroll
    for(int tj=0;tj<4;tj++) bfv[tj] = *(const short8*)(&Bs[bi][(wc*64+tj*16+lrow)*32 + quad*8]);
    #pragma unroll
    for(int ti=0;ti<4;ti++)
      #pragma unroll
      for(int tj=0;tj<4;tj++)
        acc[ti][tj] = __builtin_amdgcn_mfma_f32_16x16x32_bf16(af[ti], bfv[tj], acc[ti][tj], 0,0,0);
  }
  const int stn = (MODE==2) ? stn_p[0] : 0;
  #pragma unroll
  for(int ti=0;ti<4;ti++){
    #pragma unroll
    for(int r=0;r<4;r++){
      int row = n0 + wr*64 + ti*16 + quad*4 + r;
      int fidx = 0, trow = 0;
      if(MODE==2){ fidx = fire[row]; trow = row % TBLK; }
      #pragma unroll
      for(int tj=0;tj<4;tj++){
        int col = m0 + wc*64 + tj*16 + lrow;
        float val = acc[ti][tj][r];
        if(MODE==0){
          if(bias) val += bias[col];
          if(RELU) val = fmaxf(val, 0.f);
          outb[(size_t)row*M + col] = f2bf(val);
        } else if(MODE==1){
          xout[(size_t)row*EDIM + col] += val + bias[col];
        } else {
          val += bias[col] + stat_emb[(size_t)stn*EDIM + col]
               + pe[trow*EDIM + col] + fire_emb[(size_t)fidx*EDIM + col];
          xout[(size_t)row*EDIM + col] = val;
        }
      }
    }
  }
}

// ------- full-row GEMM + residual + LayerNorm epilogue (Wo only, K=384) -------
__global__ __launch_bounds__(512, 4) void gemm_row_ln(
    const unsigned short* __restrict__ A, const unsigned short* __restrict__ Wt,
    const float* __restrict__ bias, float* __restrict__ x,
    const float* __restrict__ g, const float* __restrict__ b,
    unsigned short* __restrict__ h, int K, int writeH){
  __shared__ __align__(16) unsigned short As[2][64*32];
  __shared__ __align__(16) unsigned short Bs[2][384*32];
  const int tid = threadIdx.x;
  const int n0 = blockIdx.x * 64;
  const int wave = tid >> 6, lane = tid & 63;
  const int rw = wave >> 1, cw = wave & 1;
  const int lrow = lane & 15, quad = lane >> 4;
  floatx4 acc[12];
  #pragma unroll
  for(int j=0;j<12;j++) acc[j] = (floatx4){0.f,0.f,0.f,0.f};

  const int S = K >> 5;
  auto stage = [&](int s, int bi){
    const int kk = s*32;
    if(tid < 256){
      int r = tid >> 2, c = (tid & 3) * 8;
      gld_lds16(&A[(size_t)(n0+r)*K + kk + c], &As[bi][tid*8]);
    }
    #pragma unroll
    for(int p=0;p<3;p++){
      int i = tid + p*512;
      int r = i >> 2, c = (i & 3) * 8;
      gld_lds16(&Wt[(size_t)r*K + kk + c], &Bs[bi][i*8]);
    }
  };
  stage(0, 0);
  for(int s=0; s<S; s++){
    const int bi = s & 1;
    __syncthreads();
    if(s+1 < S) stage(s+1, bi^1);
    short8 af = *(const short8*)(&As[bi][(rw*16+lrow)*32 + quad*8]);
    short8 bfv[12];
    #pragma unroll
    for(int tj=0;tj<12;tj++) bfv[tj] = *(const short8*)(&Bs[bi][(cw*192+tj*16+lrow)*32 + quad*8]);
    #pragma unroll
    for(int tj=0;tj<12;tj++)
      acc[tj] = __builtin_amdgcn_mfma_f32_16x16x32_bf16(af, bfv[tj], acc[tj], 0,0,0);
  }
  __syncthreads();
  float* part = (float*)&As[0][0];
  {
    float ps[4] = {0.f,0.f,0.f,0.f}, pq[4] = {0.f,0.f,0.f,0.f};
    #pragma unroll
    for(int tj=0;tj<12;tj++){
      const int col = cw*192 + tj*16 + lrow;
      const float bi = bias[col];
      #pragma unroll
      for(int r=0;r<4;r++){
        const int row = n0 + rw*16 + quad*4 + r;
        float v = acc[tj][r] + bi + x[(size_t)row*EDIM + col];
        acc[tj][r] = v;
        ps[r] += v; pq[r] += v*v;
      }
    }
    #pragma unroll
    for(int r=0;r<4;r++){
      #pragma unroll
      for(int m=1;m<16;m<<=1){ ps[r] += __shfl_xor(ps[r],m); pq[r] += __shfl_xor(pq[r],m); }
    }
    if(lrow == 0){
      #pragma unroll
      for(int r=0;r<4;r++){
        const int rl = rw*16 + quad*4 + r;
        part[rl*2 + cw]       = ps[r];
        part[128 + rl*2 + cw] = pq[r];
      }
    }
  }
  __syncthreads();
  #pragma unroll
  for(int r=0;r<4;r++){
    const int rl = rw*16 + quad*4 + r;
    const int row = n0 + rl;
    const float s = part[rl*2+0] + part[rl*2+1];
    const float q = part[128+rl*2+0] + part[128+rl*2+1];
    const float mean = s*(1.f/384.f);
    const float var  = q*(1.f/384.f) - mean*mean;
    const float rstd = rsqrtf(var + 1e-5f);
    #pragma unroll
    for(int tj=0;tj<12;tj++){
      const int col = cw*192 + tj*16 + lrow;
      const float v = acc[tj][r];
      x[(size_t)row*EDIM + col] = v;
      if(writeH)
        h[(size_t)row*EDIM + col] = f2bf((v-mean)*rstd*g[col] + b[col]);
    }
  }
}

// ---------------- causal attention: 4 waves/block per (b,h) -------------------
__global__ __launch_bounds__(256) void attn_kernel(const unsigned short* __restrict__ qkv,
    unsigned short* __restrict__ o){
  const int bh = blockIdx.x;
  const int b = bh / NHEAD, h = bh % NHEAD;
  const int wave = threadIdx.x >> 6, lane = threadIdx.x & 63;
  const int tid = threadIdx.x;
  __shared__ float qs[TBLK*64];
  __shared__ float ks[TBLK*65];
  __shared__ float ps[TBLK*64];
  const size_t base = (size_t)b*TBLK*QKVSTR + h*DHEAD;
  const unsigned short* qp = qkv + base;
  const unsigned short* kp = qkv + base + 384;
  const unsigned short* vp = qkv + base + 768;
  for(int i=tid; i<TBLK*64; i+=256){
    int t = i >> 6, dd = i & 63;
    qs[i]          = bf2f(qp[(size_t)t*QKVSTR + dd]);
    ks[t*65 + dd]  = bf2f(kp[(size_t)t*QKVSTR + dd]);
  }
  float vreg[TBLK];
  #pragma unroll
  for(int s2=0;s2<TBLK;s2++) vreg[s2] = bf2f(vp[(size_t)s2*QKVSTR + lane]);
  __syncthreads();
  const int krow = (lane < TBLK) ? lane : (TBLK-1);
  float kreg[64];
  #pragma unroll
  for(int dd=0;dd<64;dd++) kreg[dd] = ks[krow*65 + dd];
  const float scale = 0.125f;
  #pragma unroll
  for(int j=0;j<9;j++){
    const int t = wave + 4*j;
    float d = 0.f;
    #pragma unroll
    for(int gg=0;gg<16;gg++){
      float4 q4 = *(const float4*)&qs[t*64 + gg*4];
      d = fmaf(q4.x, kreg[gg*4+0], d);
      d = fmaf(q4.y, kreg[gg*4+1], d);
      d = fmaf(q4.z, kreg[gg*4+2], d);
      d = fmaf(q4.w, kreg[gg*4+3], d);
    }
    float val = (lane <= t) ? d*scale : -INFINITY;
    float mx = val;
    #pragma unroll
    for(int m=1;m<64;m<<=1) mx = fmaxf(mx, __shfl_xor(mx,m));
    float p = __expf(val - mx);
    float sum = p;
    #pragma unroll
    for(int m=1;m<64;m<<=1) sum += __shfl_xor(sum,m);
    ps[t*64 + lane] = p / sum;
  }
  __syncthreads();
  #pragma unroll
  for(int j=0;j<9;j++){
    const int t = wave + 4*j;
    float acc = 0.f;
    #pragma unroll
    for(int gg=0;gg<9;gg++){
      float4 p4 = *(const float4*)&ps[t*64 + gg*4];
      acc = fmaf(p4.x, vreg[gg*4+0], acc);
      acc = fmaf(p4.y, vreg[gg*4+1], acc);
      acc = fmaf(p4.z, vreg[gg*4+2], acc);
      acc = fmaf(p4.w, vreg[gg*4+3], acc);
    }
    o[(size_t)b*TBLK*EDIM + (size_t)t*EDIM + h*DHEAD + lane] = f2bf(acc);
  }
}

// ---------------- head: LNf + sigmoid(x@Wh+bh)*500 + per-block partials -------
__global__ __launch_bounds__(256) void head_kernel(const float* __restrict__ x,
    const float* __restrict__ g, const float* __restrict__ b,
    const float* __restrict__ Wh, const float* __restrict__ bh,
    const int* __restrict__ targets, float* __restrict__ out,
    float* __restrict__ partials){
  const int wave = threadIdx.x >> 6, lane = threadIdx.x & 63;
  const int row = blockIdx.x*4 + wave;
  const float* xr = x + (size_t)row*EDIM;
  float v[6]; float s=0.f, sq=0.f;
  #pragma unroll
  for(int j=0;j<6;j++){ v[j]=xr[j*64+lane]; s+=v[j]; sq+=v[j]*v[j]; }
  #pragma unroll
  for(int m=1;m<64;m<<=1){ s += __shfl_xor(s,m); sq += __shfl_xor(sq,m); }
  const float mean = s*(1.f/384.f);
  const float var  = sq*(1.f/384.f) - mean*mean;
  const float rstd = rsqrtf(var + 1e-5f);
  float dot = 0.f;
  #pragma unroll
  for(int j=0;j<6;j++){
    int e = j*64+lane;
    float hh = (v[j]-mean)*rstd*g[e] + b[e];
    dot = fmaf(hh, Wh[e], dot);
  }
  #pragma unroll
  for(int m=1;m<64;m<<=1) dot += __shfl_xor(dot,m);
  __shared__ float part[4][4];
  if(lane == 0){
    float logit = 1.f/(1.f + __expf(-(dot + bh[0])));
    float den = logit * 500.f;
    out[row] = den;
    float tgt = (float)targets[(size_t)row*2];
    float nt  = tgt * (1.f/500.f);
    part[wave][0] = (logit-nt)*(logit-nt);   // mse numerator
    part[wave][1] = (tgt-den)*(tgt-den);     // See
    part[wave][2] = tgt;                     // Sy
    part[wave][3] = tgt*tgt;                 // Syy
  }
  __syncthreads();
  if(threadIdx.x < 4){
    float t0 = part[0][threadIdx.x] + part[1][threadIdx.x]
             + part[2][threadIdx.x] + part[3][threadIdx.x];
    partials[(size_t)threadIdx.x*NHBLK + blockIdx.x] = t0;  // no atomics
  }
}

// ---------------- final reduction: partials[4][NHBLK] -> mse, r2 --------------
__global__ __launch_bounds__(1024) void finalize_reduce(
    const float* __restrict__ partials, float* __restrict__ out){
  __shared__ float red[16];
  const int tid = threadIdx.x;
  const int c = tid >> 8, j = tid & 255;   // 256 threads per accumulator
  float s = 0.f;
  for(int i = j; i < NHBLK; i += 256) s += partials[(size_t)c*NHBLK + i];
  #pragma unroll
  for(int m=1;m<64;m<<=1) s += __shfl_xor(s,m);
  if((tid & 63) == 0) red[tid >> 6] = s;   // wave w covers acc c = w>>2
  __syncthreads();
  if(tid == 0){
    float a0 = red[0]+red[1]+red[2]+red[3];      // mse num
    float a1 = red[4]+red[5]+red[6]+red[7];      // See
    float a2 = red[8]+red[9]+red[10]+red[11];    // Sy
    float a3 = red[12]+red[13]+red[14]+red[15];  // Syy
    const float n = (float)NTOK;
    out[NTOK]   = a0 / n;
    float denom = a3 - a2*a2/n;
    out[NTOK+1] = 1.f - a1/denom;
  }
}

// =============================================================================
extern "C" void kernel_launch(void* const* d_in, const int* in_sizes, int n_in,
                              void* d_out, int out_size, void* d_ws, size_t ws_size,
                              hipStream_t stream){
  (void)in_sizes; (void)n_in; (void)out_size; (void)ws_size;
  const int*   idx      = (const int*)  d_in[0];
  const int*   targets  = (const int*)  d_in[1];
  const int*   stn_ix   = (const int*)  d_in[3];
  const float* Wp       = (const float*)d_in[4];
  const float* bp       = (const float*)d_in[5];
  const float* stat_emb = (const float*)d_in[6];
  const float* fire_emb = (const float*)d_in[7];
  const float* ln1_g    = (const float*)d_in[8];
  const float* ln1_b    = (const float*)d_in[9];
  const float* Wq       = (const float*)d_in[10];
  const float* Wk       = (const float*)d_in[11];
  const float* Wv       = (const float*)d_in[12];
  const float* Wo       = (const float*)d_in[13];
  const float* bo       = (const float*)d_in[14];
  const float* ln2_g    = (const float*)d_in[15];
  const float* ln2_b    = (const float*)d_in[16];
  const float* W1       = (const float*)d_in[17];
  const float* b1       = (const float*)d_in[18];
  const float* W2       = (const float*)d_in[19];
  const float* b2       = (const float*)d_in[20];
  const float* lnf_g    = (const float*)d_in[21];
  const float* lnf_b    = (const float*)d_in[22];
  const float* Wh       = (const float*)d_in[23];
  const float* bh       = (const float*)d_in[24];
  float* out = (float*)d_out;

  char* ws = (char*)d_ws;
  float*          x      = (float*)         (ws + 0);
  unsigned short* h      = (unsigned short*)(ws + 56623104);
  unsigned short* qkv    = (unsigned short*)(ws + 84934656);
  unsigned short* obuf   = (unsigned short*)(ws + 169869312);
  unsigned short* ffn    = qkv;
  unsigned short* pm     = (unsigned short*)(ws + 169869312);  // aliases obuf
  int*            fire   = (int*)           (ws + 186384384);
  unsigned short* wp_t   = (unsigned short*)(ws + 186531840);
  float*          pe     = (float*)         (ws + 186703872);
  float*          partials = (float*)       (ws + 169869312); // aliases obuf (free at head)
  unsigned short* wqkv_t = (unsigned short*)(ws + 198180864);
  unsigned short* wo_t   = (unsigned short*)(ws + 203489280);
  unsigned short* w1_t   = (unsigned short*)(ws + 205258752);
  unsigned short* w2_t   = (unsigned short*)(ws + 212336640);

  const dim3 tb(32,8);
  wt_transpose<<<dim3(12,12,6), tb, 0, stream>>>(Wq, wqkv_t,          384,  384, 442368);
  wt_transpose<<<dim3(12,12,6), tb, 0, stream>>>(Wk, wqkv_t + 147456, 384,  384, 442368);
  wt_transpose<<<dim3(12,12,6), tb, 0, stream>>>(Wv, wqkv_t + 294912, 384,  384, 442368);
  wt_transpose<<<dim3(12,12,6), tb, 0, stream>>>(Wo, wo_t,            384,  384, 147456);
  wt_transpose<<<dim3(48,12,6), tb, 0, stream>>>(W1, w1_t,            384, 1536, 589824);
  wt_transpose<<<dim3(12,48,6), tb, 0, stream>>>(W2, w2_t,           1536,  384, 589824);
  wp_transpose<<<384, 256, 0, stream>>>(Wp, wp_t);
  pe_kernel<<<TBLK, 384, 0, stream>>>(pe);
  prep_pm<<<(NTOK*KPM + 255)/256, 256, 0, stream>>>(idx, pm);
  prep_fire<<<(NTOK + 255)/256, 256, 0, stream>>>(idx, stn_ix, fire);

  // embed GEMM: x = pm @ wp_t^T + (bp + stat + pe + fire_emb)
  gemm_k<2,false><<<dim3(3,288), 256, 0, stream>>>(pm, wp_t, bp, nullptr, x,
      fire, pe, stat_emb, stn_ix, fire_emb, 384, KPM);

  // layer-0 ln1
  ln_bf16<<<NTOK/4, 256, 0, stream>>>(x, ln1_g, ln1_b, h);

  const dim3 gQKV(9, 288);
  const dim3 gE(3, 288);
  const dim3 gF(12, 288);
  for(int l=0; l<NLAYER; l++){
    gemm_k<0,false><<<gQKV, 256, 0, stream>>>(h, wqkv_t + (size_t)l*442368,
        nullptr, qkv, nullptr, nullptr, nullptr, nullptr, nullptr, nullptr, 1152, 384);
    attn_kernel<<<BSZ*NHEAD, 256, 0, stream>>>(qkv, obuf);
    // x += obuf@Wo + bo;  h = LN2(x)   (fused; K=384)
    gemm_row_ln<<<NTOK/64, 512, 0, stream>>>(obuf, wo_t + (size_t)l*147456,
        bo + l*EDIM, x, ln2_g + l*EDIM, ln2_b + l*EDIM, h, 384, 1);
    gemm_k<0,true><<<gF, 256, 0, stream>>>(h, w1_t + (size_t)l*589824,
        b1 + l*1536, ffn, nullptr, nullptr, nullptr, nullptr, nullptr, nullptr, 1536, 384);
    // x += ffn@W2 + b2   (m97-shape gemm_k, fp32 residual epilogue)
    gemm_k<1,false><<<gE, 256, 0, stream>>>(ffn, w2_t + (size_t)l*589824,
        b2 + l*EDIM, nullptr, x, nullptr, nullptr, nullptr, nullptr, nullptr, 384, 1536);
    // h = LN1[l+1](x)  (skip on last layer; head does LNf itself)
    if(l < NLAYER-1)
      ln_bf16<<<NTOK/4, 256, 0, stream>>>(x, ln1_g + (l+1)*EDIM, ln1_b + (l+1)*EDIM, h);
  }

  head_kernel<<<NHBLK, 256, 0, stream>>>(x, lnf_g, lnf_b, Wh, bh, targets, out, partials);
  finalize_reduce<<<1, 1024, 0, stream>>>(partials, out);
}

// Round 7
// 2493.055 us; speedup vs baseline: 1.8533x; 1.0770x over previous
//
#include <hip/hip_runtime.h>
#include <hip/hip_fp8.h>
#include <stdint.h>

// PM25 transformer forward, MI355X/gfx950. Round 7:
//   - ALL GEMM operands in fp8 e4m3 (OCP): weights, h, qkv, obuf, ffn, pm.
//     Residual x, LN stats, softmax, head remain fp32. MFMA 16x16x32_fp8_fp8
//     (same rate as bf16; gains are bytes/LDS/occupancy).
//   - LDS staging: 16 KB dbuf in gemm_k (was 32), one gld_lds16 per operand per
//     thread per K-step; XOR half-swap swizzle -> 2-way (free) ds_read_b64.
//   - pm scaled x256 into fp8 range; 1/256 folded into embed epilogue.
// ws layout (byte offsets unchanged; buffers now fp8 = half-size, still fit):
//   x fp32 @0 | h fp8 @56623104 | qkv fp8 @84934656 | obuf fp8 @169869312
//   ffn fp8 aliases qkv | pm fp8 @169869312 | fire @186384384 | wp_t @186531840
//   pe fp32 @186703872 | partials @169869312 | wqkv_t @198180864 | wo_t @203489280
//   w1_t @205258752 | w2_t @212336640

#define EDIM   384
#define NHEAD  6
#define DHEAD  64
#define NLAYER 6
#define TBLK   36
#define SNUM   210
#define BSZ    1024
#define NTOK   (BSZ*TBLK)
#define QKVSTR 1152
#define KPM    224
#define NHBLK  (NTOK/4)

typedef __attribute__((ext_vector_type(4))) float floatx4;

static __device__ __forceinline__ unsigned char f2fp8(float f){
  __hip_fp8_e4m3 t(f); return t.__x;
}
static __device__ __forceinline__ float fp82f(unsigned char u){
  __hip_fp8_e4m3 t; t.__x = u; return (float)t;
}
static __device__ __forceinline__ void gld_lds16(const void* g, void* l){
  __builtin_amdgcn_global_load_lds(
      (const __attribute__((address_space(1))) void*)g,
      (__attribute__((address_space(3))) void*)l, 16, 0, 0);
}

// ---------------- weight transpose + fp8 cast: out[m][k] = fp8(in[k][m]) ------
__global__ __launch_bounds__(256) void wt_transpose(const float* __restrict__ in,
    unsigned char* __restrict__ out, int K, int M, long outStride){
  __shared__ float tile[32][33];
  const int mat = blockIdx.z;
  const float* src = in + (size_t)mat*K*M;
  unsigned char* dst = out + (size_t)mat*outStride;
  const int m0 = blockIdx.x*32, k0 = blockIdx.y*32;
  const int tx = threadIdx.x, ty = threadIdx.y;
  for(int i=ty;i<32;i+=8) tile[i][tx] = src[(size_t)(k0+i)*M + m0+tx];
  __syncthreads();
  for(int i=ty;i<32;i+=8) dst[(size_t)(m0+i)*K + k0+tx] = f2fp8(tile[tx][i]);
}

// Wp [210,384] -> wp_t fp8 [384,224] (K zero-padded 210->224)
__global__ __launch_bounds__(256) void wp_transpose(const float* __restrict__ Wp,
    unsigned char* __restrict__ wp_t){
  const int m = blockIdx.x, k = threadIdx.x;
  if(k < KPM)
    wp_t[(size_t)m*KPM + k] = (k < SNUM) ? f2fp8(Wp[(size_t)k*EDIM + m]) : 0;
}

// pm fp8 [36864,224]: pm[row][s] = fp8(idx*256/500); x256 undone in epilogue
__global__ __launch_bounds__(256) void prep_pm(const int* __restrict__ idx,
    unsigned char* __restrict__ pm){
  const int i = blockIdx.x*256 + threadIdx.x;
  if(i >= NTOK*KPM) return;
  const int row = i / KPM, s = i - row*KPM;
  float v = 0.f;
  if(s < SNUM) v = (float)idx[((size_t)row*SNUM + s)*2] * (256.f/500.f);
  pm[i] = f2fp8(v);
}

__global__ __launch_bounds__(256) void prep_fire(const int* __restrict__ idx,
    const int* __restrict__ stn_p, int* __restrict__ fire){
  const int row = blockIdx.x*256 + threadIdx.x;
  if(row < NTOK) fire[row] = idx[((size_t)row*SNUM + stn_p[0])*2 + 1];
}

__global__ __launch_bounds__(384) void pe_kernel(float* __restrict__ pe){
  const int t = blockIdx.x, e = threadIdx.x;
  const float freq = __expf(-(float)(2*(e>>1)) * (9.210340371976184f/384.f));
  const float ang = (float)t * freq;
  pe[t*EDIM + e] = (e & 1) ? __cosf(ang) : __sinf(ang);
}

// ---------------- layernorm fp32 -> fp8, one wave per row --------------------
__global__ __launch_bounds__(256) void ln_act(const float* __restrict__ x,
    const float* __restrict__ g, const float* __restrict__ b,
    unsigned char* __restrict__ out){
  const int wave = threadIdx.x >> 6, lane = threadIdx.x & 63;
  const int row = blockIdx.x*4 + wave;
  const float* xr = x + (size_t)row*EDIM;
  float v[6]; float s=0.f, sq=0.f;
  #pragma unroll
  for(int j=0;j<6;j++){ v[j]=xr[j*64+lane]; s+=v[j]; sq+=v[j]*v[j]; }
  #pragma unroll
  for(int m=1;m<64;m<<=1){ s += __shfl_xor(s,m); sq += __shfl_xor(sq,m); }
  const float mean = s*(1.f/384.f);
  const float var  = sq*(1.f/384.f) - mean*mean;
  const float rstd = rsqrtf(var + 1e-5f);
  unsigned char* orow = out + (size_t)row*EDIM;
  #pragma unroll
  for(int j=0;j<6;j++){
    int e = j*64+lane;
    orow[e] = f2fp8((v[j]-mean)*rstd*g[e] + b[e]);
  }
}

// ---------------- fp8 MFMA GEMM, 128x128, BK=32, dbuf, swizzled ---------------
// MODE 0: write fp8 (bias opt, RELU opt).
// MODE 1: fp32 residual accumulate: x += val + bias.
// MODE 2: embed epilogue (val/256 + bp + stat + pe + fire_emb) -> fp32 x.
template<int MODE, bool RELU>
__global__ __launch_bounds__(256) void gemm_k(const unsigned char* __restrict__ A,
    const unsigned char* __restrict__ Wt, const float* __restrict__ bias,
    unsigned char* __restrict__ outb, float* __restrict__ xout,
    const int* __restrict__ fire, const float* __restrict__ pe,
    const float* __restrict__ stat_emb, const int* __restrict__ stn_p,
    const float* __restrict__ fire_emb, int M, int K){
  __shared__ __align__(16) unsigned char As[2][128*32];
  __shared__ __align__(16) unsigned char Bs[2][128*32];
  const int tid  = threadIdx.x;
  const int m0   = blockIdx.x * 128;
  const int n0   = blockIdx.y * 128;
  const int wave = tid >> 6, lane = tid & 63;
  const int wr = wave >> 1, wc = wave & 1;
  const int lrow = lane & 15, quad = lane >> 4;
  const int xsw = ((lane >> 2) & 1) << 4;   // half-swap swizzle on frag reads
  floatx4 acc[4][4];
  #pragma unroll
  for(int i=0;i<4;i++)
    #pragma unroll
    for(int j=0;j<4;j++) acc[i][j] = (floatx4){0.f,0.f,0.f,0.f};

  const int S = K >> 5;
  // stage: thread i covers row r=i>>1, fetches global half (i&1)^((r>>2)&1)
  const int sr = tid >> 1;
  const int sc = (((tid & 1) ^ ((tid >> 3) & 1))) * 16;
  auto stage = [&](int s, int bi){
    const int kk = s*32;
    gld_lds16(&A [(size_t)(n0+sr)*K + kk + sc], &As[bi][tid*16]);
    gld_lds16(&Wt[(size_t)(m0+sr)*K + kk + sc], &Bs[bi][tid*16]);
  };
  stage(0, 0);
  for(int s=0; s<S; s++){
    const int bi = s & 1;
    __syncthreads();
    if(s+1 < S) stage(s+1, bi^1);
    long af[4], bfv[4];
    #pragma unroll
    for(int ti=0;ti<4;ti++)
      af[ti]  = *(const long*)(&As[bi][(wr*64+ti*16+lrow)*32 + ((quad*8) ^ xsw)]);
    #pragma unroll
    for(int tj=0;tj<4;tj++)
      bfv[tj] = *(const long*)(&Bs[bi][(wc*64+tj*16+lrow)*32 + ((quad*8) ^ xsw)]);
    #pragma unroll
    for(int ti=0;ti<4;ti++)
      #pragma unroll
      for(int tj=0;tj<4;tj++)
        acc[ti][tj] = __builtin_amdgcn_mfma_f32_16x16x32_fp8_fp8(af[ti], bfv[tj], acc[ti][tj], 0,0,0);
  }
  const int stn = (MODE==2) ? stn_p[0] : 0;
  #pragma unroll
  for(int ti=0;ti<4;ti++){
    #pragma unroll
    for(int r=0;r<4;r++){
      int row = n0 + wr*64 + ti*16 + quad*4 + r;
      int fidx = 0, trow = 0;
      if(MODE==2){ fidx = fire[row]; trow = row % TBLK; }
      #pragma unroll
      for(int tj=0;tj<4;tj++){
        int col = m0 + wc*64 + tj*16 + lrow;
        float val = acc[ti][tj][r];
        if(MODE==0){
          if(bias) val += bias[col];
          if(RELU) val = fmaxf(val, 0.f);
          outb[(size_t)row*M + col] = f2fp8(val);
        } else if(MODE==1){
          xout[(size_t)row*EDIM + col] += val + bias[col];
        } else {
          val = val*(1.f/256.f) + bias[col] + stat_emb[(size_t)stn*EDIM + col]
              + pe[trow*EDIM + col] + fire_emb[(size_t)fidx*EDIM + col];
          xout[(size_t)row*EDIM + col] = val;
        }
      }
    }
  }
}

// ------- full-row GEMM + residual + LayerNorm epilogue (Wo only, K=384) -------
// 512 thr (8 waves): rw in [0,4) 16-row group, cw in [0,2) 192-col half.
__global__ __launch_bounds__(512, 4) void gemm_row_ln(
    const unsigned char* __restrict__ A, const unsigned char* __restrict__ Wt,
    const float* __restrict__ bias, float* __restrict__ x,
    const float* __restrict__ g, const float* __restrict__ b,
    unsigned char* __restrict__ h, int K, int writeH){
  __shared__ __align__(16) unsigned char As[2][64*32];     // 2x2 KB
  __shared__ __align__(16) unsigned char Bs[2][384*32];    // 2x12 KB
  const int tid = threadIdx.x;
  const int n0 = blockIdx.x * 64;
  const int wave = tid >> 6, lane = tid & 63;
  const int rw = wave >> 1, cw = wave & 1;
  const int lrow = lane & 15, quad = lane >> 4;
  const int xsw = ((lane >> 2) & 1) << 4;
  floatx4 acc[12];
  #pragma unroll
  for(int j=0;j<12;j++) acc[j] = (floatx4){0.f,0.f,0.f,0.f};

  const int S = K >> 5;
  auto stage = [&](int s, int bi){
    const int kk = s*32;
    if(tid < 128){                      // A: 64 rows x 32 B (waves 0-1)
      int r = tid >> 1, c = (((tid&1) ^ ((tid>>3)&1))) * 16;
      gld_lds16(&A[(size_t)(n0+r)*K + kk + c], &As[bi][tid*16]);
    }
    {                                    // B: 384 rows x 32 B = 768 x 16 B
      int i = tid;
      int r = i >> 1, c = (((i&1) ^ ((i>>3)&1))) * 16;
      gld_lds16(&Wt[(size_t)r*K + kk + c], &Bs[bi][i*16]);
    }
    if(tid < 256){
      int i = tid + 512;
      int r = i >> 1, c = (((i&1) ^ ((i>>3)&1))) * 16;
      gld_lds16(&Wt[(size_t)r*K + kk + c], &Bs[bi][i*16]);
    }
  };
  stage(0, 0);
  for(int s=0; s<S; s++){
    const int bi = s & 1;
    __syncthreads();
    if(s+1 < S) stage(s+1, bi^1);
    long af = *(const long*)(&As[bi][(rw*16+lrow)*32 + ((quad*8) ^ xsw)]);
    long bfv[12];
    #pragma unroll
    for(int tj=0;tj<12;tj++)
      bfv[tj] = *(const long*)(&Bs[bi][(cw*192+tj*16+lrow)*32 + ((quad*8) ^ xsw)]);
    #pragma unroll
    for(int tj=0;tj<12;tj++)
      acc[tj] = __builtin_amdgcn_mfma_f32_16x16x32_fp8_fp8(af, bfv[tj], acc[tj], 0,0,0);
  }
  __syncthreads();
  float* part = (float*)&As[0][0];   // 256 floats = 1 KB, fits in As[0]
  {
    float ps[4] = {0.f,0.f,0.f,0.f}, pq[4] = {0.f,0.f,0.f,0.f};
    #pragma unroll
    for(int tj=0;tj<12;tj++){
      const int col = cw*192 + tj*16 + lrow;
      const float bi = bias[col];
      #pragma unroll
      for(int r=0;r<4;r++){
        const int row = n0 + rw*16 + quad*4 + r;
        float v = acc[tj][r] + bi + x[(size_t)row*EDIM + col];
        acc[tj][r] = v;
        ps[r] += v; pq[r] += v*v;
      }
    }
    #pragma unroll
    for(int r=0;r<4;r++){
      #pragma unroll
      for(int m=1;m<16;m<<=1){ ps[r] += __shfl_xor(ps[r],m); pq[r] += __shfl_xor(pq[r],m); }
    }
    if(lrow == 0){
      #pragma unroll
      for(int r=0;r<4;r++){
        const int rl = rw*16 + quad*4 + r;
        part[rl*2 + cw]       = ps[r];
        part[128 + rl*2 + cw] = pq[r];
      }
    }
  }
  __syncthreads();
  #pragma unroll
  for(int r=0;r<4;r++){
    const int rl = rw*16 + quad*4 + r;
    const int row = n0 + rl;
    const float s = part[rl*2+0] + part[rl*2+1];
    const float q = part[128+rl*2+0] + part[128+rl*2+1];
    const float mean = s*(1.f/384.f);
    const float var  = q*(1.f/384.f) - mean*mean;
    const float rstd = rsqrtf(var + 1e-5f);
    #pragma unroll
    for(int tj=0;tj<12;tj++){
      const int col = cw*192 + tj*16 + lrow;
      const float v = acc[tj][r];
      x[(size_t)row*EDIM + col] = v;
      if(writeH)
        h[(size_t)row*EDIM + col] = f2fp8((v-mean)*rstd*g[col] + b[col]);
    }
  }
}

// ---------------- causal attention: 4 waves/block per (b,h), fp8 I/O ----------
__global__ __launch_bounds__(256) void attn_kernel(const unsigned char* __restrict__ qkv,
    unsigned char* __restrict__ o){
  const int bh = blockIdx.x;
  const int b = bh / NHEAD, h = bh % NHEAD;
  const int wave = threadIdx.x >> 6, lane = threadIdx.x & 63;
  const int tid = threadIdx.x;
  __shared__ float qs[TBLK*64];
  __shared__ float ks[TBLK*65];
  __shared__ float ps[TBLK*64];
  const size_t base = (size_t)b*TBLK*QKVSTR + h*DHEAD;
  const unsigned char* qp = qkv + base;
  const unsigned char* kp = qkv + base + 384;
  const unsigned char* vp = qkv + base + 768;
  for(int i=tid; i<TBLK*16; i+=256){
    int t = i >> 4, d4 = (i & 15) * 4;
    unsigned int rq = *(const unsigned int*)&qp[(size_t)t*QKVSTR + d4];
    unsigned int rk = *(const unsigned int*)&kp[(size_t)t*QKVSTR + d4];
    #pragma unroll
    for(int j=0;j<4;j++){
      qs[t*64 + d4 + j] = fp82f((unsigned char)(rq >> (8*j)));
      ks[t*65 + d4 + j] = fp82f((unsigned char)(rk >> (8*j)));
    }
  }
  float vreg[TBLK];
  #pragma unroll
  for(int s2=0;s2<TBLK;s2++) vreg[s2] = fp82f(vp[(size_t)s2*QKVSTR + lane]);
  __syncthreads();
  const int krow = (lane < TBLK) ? lane : (TBLK-1);
  float kreg[64];
  #pragma unroll
  for(int dd=0;dd<64;dd++) kreg[dd] = ks[krow*65 + dd];
  const float scale = 0.125f;
  #pragma unroll
  for(int j=0;j<9;j++){
    const int t = wave + 4*j;
    float d = 0.f;
    #pragma unroll
    for(int gg=0;gg<16;gg++){
      float4 q4 = *(const float4*)&qs[t*64 + gg*4];
      d = fmaf(q4.x, kreg[gg*4+0], d);
      d = fmaf(q4.y, kreg[gg*4+1], d);
      d = fmaf(q4.z, kreg[gg*4+2], d);
      d = fmaf(q4.w, kreg[gg*4+3], d);
    }
    float val = (lane <= t) ? d*scale : -INFINITY;
    float mx = val;
    #pragma unroll
    for(int m=1;m<64;m<<=1) mx = fmaxf(mx, __shfl_xor(mx,m));
    float p = __expf(val - mx);
    float sum = p;
    #pragma unroll
    for(int m=1;m<64;m<<=1) sum += __shfl_xor(sum,m);
    ps[t*64 + lane] = p / sum;
  }
  __syncthreads();
  #pragma unroll
  for(int j=0;j<9;j++){
    const int t = wave + 4*j;
    float acc = 0.f;
    #pragma unroll
    for(int gg=0;gg<9;gg++){
      float4 p4 = *(const float4*)&ps[t*64 + gg*4];
      acc = fmaf(p4.x, vreg[gg*4+0], acc);
      acc = fmaf(p4.y, vreg[gg*4+1], acc);
      acc = fmaf(p4.z, vreg[gg*4+2], acc);
      acc = fmaf(p4.w, vreg[gg*4+3], acc);
    }
    o[(size_t)b*TBLK*EDIM + (size_t)t*EDIM + h*DHEAD + lane] = f2fp8(acc);
  }
}

// ---------------- head: LNf + sigmoid(x@Wh+bh)*500 + per-block partials -------
__global__ __launch_bounds__(256) void head_kernel(const float* __restrict__ x,
    const float* __restrict__ g, const float* __restrict__ b,
    const float* __restrict__ Wh, const float* __restrict__ bh,
    const int* __restrict__ targets, float* __restrict__ out,
    float* __restrict__ partials){
  const int wave = threadIdx.x >> 6, lane = threadIdx.x & 63;
  const int row = blockIdx.x*4 + wave;
  const float* xr = x + (size_t)row*EDIM;
  float v[6]; float s=0.f, sq=0.f;
  #pragma unroll
  for(int j=0;j<6;j++){ v[j]=xr[j*64+lane]; s+=v[j]; sq+=v[j]*v[j]; }
  #pragma unroll
  for(int m=1;m<64;m<<=1){ s += __shfl_xor(s,m); sq += __shfl_xor(sq,m); }
  const float mean = s*(1.f/384.f);
  const float var  = sq*(1.f/384.f) - mean*mean;
  const float rstd = rsqrtf(var + 1e-5f);
  float dot = 0.f;
  #pragma unroll
  for(int j=0;j<6;j++){
    int e = j*64+lane;
    float hh = (v[j]-mean)*rstd*g[e] + b[e];
    dot = fmaf(hh, Wh[e], dot);
  }
  #pragma unroll
  for(int m=1;m<64;m<<=1) dot += __shfl_xor(dot,m);
  __shared__ float part[4][4];
  if(lane == 0){
    float logit = 1.f/(1.f + __expf(-(dot + bh[0])));
    float den = logit * 500.f;
    out[row] = den;
    float tgt = (float)targets[(size_t)row*2];
    float nt  = tgt * (1.f/500.f);
    part[wave][0] = (logit-nt)*(logit-nt);
    part[wave][1] = (tgt-den)*(tgt-den);
    part[wave][2] = tgt;
    part[wave][3] = tgt*tgt;
  }
  __syncthreads();
  if(threadIdx.x < 4){
    float t0 = part[0][threadIdx.x] + part[1][threadIdx.x]
             + part[2][threadIdx.x] + part[3][threadIdx.x];
    partials[(size_t)threadIdx.x*NHBLK + blockIdx.x] = t0;
  }
}

// ---------------- final reduction: partials[4][NHBLK] -> mse, r2 --------------
__global__ __launch_bounds__(1024) void finalize_reduce(
    const float* __restrict__ partials, float* __restrict__ out){
  __shared__ float red[16];
  const int tid = threadIdx.x;
  const int c = tid >> 8, j = tid & 255;
  float s = 0.f;
  for(int i = j; i < NHBLK; i += 256) s += partials[(size_t)c*NHBLK + i];
  #pragma unroll
  for(int m=1;m<64;m<<=1) s += __shfl_xor(s,m);
  if((tid & 63) == 0) red[tid >> 6] = s;
  __syncthreads();
  if(tid == 0){
    float a0 = red[0]+red[1]+red[2]+red[3];
    float a1 = red[4]+red[5]+red[6]+red[7];
    float a2 = red[8]+red[9]+red[10]+red[11];
    float a3 = red[12]+red[13]+red[14]+red[15];
    const float n = (float)NTOK;
    out[NTOK]   = a0 / n;
    float denom = a3 - a2*a2/n;
    out[NTOK+1] = 1.f - a1/denom;
  }
}

// =============================================================================
extern "C" void kernel_launch(void* const* d_in, const int* in_sizes, int n_in,
                              void* d_out, int out_size, void* d_ws, size_t ws_size,
                              hipStream_t stream){
  (void)in_sizes; (void)n_in; (void)out_size; (void)ws_size;
  const int*   idx      = (const int*)  d_in[0];
  const int*   targets  = (const int*)  d_in[1];
  const int*   stn_ix   = (const int*)  d_in[3];
  const float* Wp       = (const float*)d_in[4];
  const float* bp       = (const float*)d_in[5];
  const float* stat_emb = (const float*)d_in[6];
  const float* fire_emb = (const float*)d_in[7];
  const float* ln1_g    = (const float*)d_in[8];
  const float* ln1_b    = (const float*)d_in[9];
  const float* Wq       = (const float*)d_in[10];
  const float* Wk       = (const float*)d_in[11];
  const float* Wv       = (const float*)d_in[12];
  const float* Wo       = (const float*)d_in[13];
  const float* bo       = (const float*)d_in[14];
  const float* ln2_g    = (const float*)d_in[15];
  const float* ln2_b    = (const float*)d_in[16];
  const float* W1       = (const float*)d_in[17];
  const float* b1       = (const float*)d_in[18];
  const float* W2       = (const float*)d_in[19];
  const float* b2       = (const float*)d_in[20];
  const float* lnf_g    = (const float*)d_in[21];
  const float* lnf_b    = (const float*)d_in[22];
  const float* Wh       = (const float*)d_in[23];
  const float* bh       = (const float*)d_in[24];
  float* out = (float*)d_out;

  char* ws = (char*)d_ws;
  float*         x      = (float*)        (ws + 0);
  unsigned char* h      = (unsigned char*)(ws + 56623104);
  unsigned char* qkv    = (unsigned char*)(ws + 84934656);
  unsigned char* obuf   = (unsigned char*)(ws + 169869312);
  unsigned char* ffn    = qkv;
  unsigned char* pm     = (unsigned char*)(ws + 169869312);  // aliases obuf
  int*           fire   = (int*)          (ws + 186384384);
  unsigned char* wp_t   = (unsigned char*)(ws + 186531840);
  float*         pe     = (float*)        (ws + 186703872);
  float*         partials = (float*)      (ws + 169869312);  // aliases obuf
  unsigned char* wqkv_t = (unsigned char*)(ws + 198180864);
  unsigned char* wo_t   = (unsigned char*)(ws + 203489280);
  unsigned char* w1_t   = (unsigned char*)(ws + 205258752);
  unsigned char* w2_t   = (unsigned char*)(ws + 212336640);

  const dim3 tb(32,8);
  wt_transpose<<<dim3(12,12,6), tb, 0, stream>>>(Wq, wqkv_t,          384,  384, 442368);
  wt_transpose<<<dim3(12,12,6), tb, 0, stream>>>(Wk, wqkv_t + 147456, 384,  384, 442368);
  wt_transpose<<<dim3(12,12,6), tb, 0, stream>>>(Wv, wqkv_t + 294912, 384,  384, 442368);
  wt_transpose<<<dim3(12,12,6), tb, 0, stream>>>(Wo, wo_t,            384,  384, 147456);
  wt_transpose<<<dim3(48,12,6), tb, 0, stream>>>(W1, w1_t,            384, 1536, 589824);
  wt_transpose<<<dim3(12,48,6), tb, 0, stream>>>(W2, w2_t,           1536,  384, 589824);
  wp_transpose<<<384, 256, 0, stream>>>(Wp, wp_t);
  pe_kernel<<<TBLK, 384, 0, stream>>>(pe);
  prep_pm<<<(NTOK*KPM + 255)/256, 256, 0, stream>>>(idx, pm);
  prep_fire<<<(NTOK + 255)/256, 256, 0, stream>>>(idx, stn_ix, fire);

  // embed GEMM: x = (pm*256) @ wp_t^T / 256 + (bp + stat + pe + fire_emb)
  gemm_k<2,false><<<dim3(3,288), 256, 0, stream>>>(pm, wp_t, bp, nullptr, x,
      fire, pe, stat_emb, stn_ix, fire_emb, 384, KPM);

  // layer-0 ln1
  ln_act<<<NTOK/4, 256, 0, stream>>>(x, ln1_g, ln1_b, h);

  const dim3 gQKV(9, 288);
  const dim3 gE(3, 288);
  const dim3 gF(12, 288);
  for(int l=0; l<NLAYER; l++){
    gemm_k<0,false><<<gQKV, 256, 0, stream>>>(h, wqkv_t + (size_t)l*442368,
        nullptr, qkv, nullptr, nullptr, nullptr, nullptr, nullptr, nullptr, 1152, 384);
    attn_kernel<<<BSZ*NHEAD, 256, 0, stream>>>(qkv, obuf);
    // x += obuf@Wo + bo;  h = LN2(x)   (fused; K=384)
    gemm_row_ln<<<NTOK/64, 512, 0, stream>>>(obuf, wo_t + (size_t)l*147456,
        bo + l*EDIM, x, ln2_g + l*EDIM, ln2_b + l*EDIM, h, 384, 1);
    gemm_k<0,true><<<gF, 256, 0, stream>>>(h, w1_t + (size_t)l*589824,
        b1 + l*1536, ffn, nullptr, nullptr, nullptr, nullptr, nullptr, nullptr, 1536, 384);
    // x += ffn@W2 + b2   (fp8, fp32 residual epilogue)
    gemm_k<1,false><<<gE, 256, 0, stream>>>(ffn, w2_t + (size_t)l*589824,
        b2 + l*EDIM, nullptr, x, nullptr, nullptr, nullptr, nullptr, nullptr, 384, 1536);
    // h = LN1[l+1](x)  (skip on last layer; head does LNf itself)
    if(l < NLAYER-1)
      ln_act<<<NTOK/4, 256, 0, stream>>>(x, ln1_g + (l+1)*EDIM, ln1_b + (l+1)*EDIM, h);
  }

  head_kernel<<<NHBLK, 256, 0, stream>>>(x, lnf_g, lnf_b, Wh, bh, targets, out, partials);
  finalize_reduce<<<1, 1024, 0, stream>>>(partials, out);
}

// Round 8
// 2272.608 us; speedup vs baseline: 2.0331x; 1.0970x over previous
//
#include <hip/hip_runtime.h>
#include <hip/hip_fp8.h>
#include <stdint.h>

// PM25 transformer forward, MI355X/gfx950. Round 8:
//   - gemm_k: BK=64 (6 barriers for K=384 instead of 12; 32 MFMA/wave/barrier)
//     + XOR chunk swizzle jl = jp ^ (r&3) ^ ((r>>2)&3) -> 2-way (free) LDS bank
//     pattern on b64 fragment reads (R7 had 4-way; conflict count was 5.3M).
//   - embed K padded 224 -> 256 (BK=64 divisible). Numerics bit-identical to R7.
// ws layout:
//   x fp32 @0 | h fp8 @56623104 | qkv fp8 @84934656 | obuf fp8 @169869312
//   ffn fp8 aliases qkv | pm fp8 [36864,256] @169869312 | fire @186384384
//   wp_t [384,256] @186531840 | pe fp32 @186703872 | partials @169869312
//   wqkv_t @198180864 | wo_t @203489280 | w1_t @205258752 | w2_t @212336640

#define EDIM   384
#define NHEAD  6
#define DHEAD  64
#define NLAYER 6
#define TBLK   36
#define SNUM   210
#define BSZ    1024
#define NTOK   (BSZ*TBLK)
#define QKVSTR 1152
#define KPM    256
#define NHBLK  (NTOK/4)

typedef __attribute__((ext_vector_type(4))) float floatx4;

static __device__ __forceinline__ unsigned char f2fp8(float f){
  __hip_fp8_e4m3 t(f); return t.__x;
}
static __device__ __forceinline__ float fp82f(unsigned char u){
  __hip_fp8_e4m3 t; t.__x = u; return (float)t;
}
static __device__ __forceinline__ void gld_lds16(const void* g, void* l){
  __builtin_amdgcn_global_load_lds(
      (const __attribute__((address_space(1))) void*)g,
      (__attribute__((address_space(3))) void*)l, 16, 0, 0);
}

// ---------------- weight transpose + fp8 cast: out[m][k] = fp8(in[k][m]) ------
__global__ __launch_bounds__(256) void wt_transpose(const float* __restrict__ in,
    unsigned char* __restrict__ out, int K, int M, long outStride){
  __shared__ float tile[32][33];
  const int mat = blockIdx.z;
  const float* src = in + (size_t)mat*K*M;
  unsigned char* dst = out + (size_t)mat*outStride;
  const int m0 = blockIdx.x*32, k0 = blockIdx.y*32;
  const int tx = threadIdx.x, ty = threadIdx.y;
  for(int i=ty;i<32;i+=8) tile[i][tx] = src[(size_t)(k0+i)*M + m0+tx];
  __syncthreads();
  for(int i=ty;i<32;i+=8) dst[(size_t)(m0+i)*K + k0+tx] = f2fp8(tile[tx][i]);
}

// Wp [210,384] -> wp_t fp8 [384,256] (K zero-padded 210->256)
__global__ __launch_bounds__(256) void wp_transpose(const float* __restrict__ Wp,
    unsigned char* __restrict__ wp_t){
  const int m = blockIdx.x, k = threadIdx.x;
  wp_t[(size_t)m*KPM + k] = (k < SNUM) ? f2fp8(Wp[(size_t)k*EDIM + m]) : 0;
}

// pm fp8 [36864,256]: pm[row][s] = fp8(idx*256/500); x256 undone in epilogue
__global__ __launch_bounds__(256) void prep_pm(const int* __restrict__ idx,
    unsigned char* __restrict__ pm){
  const long i = (long)blockIdx.x*256 + threadIdx.x;
  if(i >= (long)NTOK*KPM) return;
  const int row = i / KPM, s = i - (long)row*KPM;
  float v = 0.f;
  if(s < SNUM) v = (float)idx[((size_t)row*SNUM + s)*2] * (256.f/500.f);
  pm[i] = f2fp8(v);
}

__global__ __launch_bounds__(256) void prep_fire(const int* __restrict__ idx,
    const int* __restrict__ stn_p, int* __restrict__ fire){
  const int row = blockIdx.x*256 + threadIdx.x;
  if(row < NTOK) fire[row] = idx[((size_t)row*SNUM + stn_p[0])*2 + 1];
}

__global__ __launch_bounds__(384) void pe_kernel(float* __restrict__ pe){
  const int t = blockIdx.x, e = threadIdx.x;
  const float freq = __expf(-(float)(2*(e>>1)) * (9.210340371976184f/384.f));
  const float ang = (float)t * freq;
  pe[t*EDIM + e] = (e & 1) ? __cosf(ang) : __sinf(ang);
}

// ---------------- layernorm fp32 -> fp8, one wave per row --------------------
__global__ __launch_bounds__(256) void ln_act(const float* __restrict__ x,
    const float* __restrict__ g, const float* __restrict__ b,
    unsigned char* __restrict__ out){
  const int wave = threadIdx.x >> 6, lane = threadIdx.x & 63;
  const int row = blockIdx.x*4 + wave;
  const float* xr = x + (size_t)row*EDIM;
  float v[6]; float s=0.f, sq=0.f;
  #pragma unroll
  for(int j=0;j<6;j++){ v[j]=xr[j*64+lane]; s+=v[j]; sq+=v[j]*v[j]; }
  #pragma unroll
  for(int m=1;m<64;m<<=1){ s += __shfl_xor(s,m); sq += __shfl_xor(sq,m); }
  const float mean = s*(1.f/384.f);
  const float var  = sq*(1.f/384.f) - mean*mean;
  const float rstd = rsqrtf(var + 1e-5f);
  unsigned char* orow = out + (size_t)row*EDIM;
  #pragma unroll
  for(int j=0;j<6;j++){
    int e = j*64+lane;
    orow[e] = f2fp8((v[j]-mean)*rstd*g[e] + b[e]);
  }
}

// ---------------- fp8 MFMA GEMM, 128x128, BK=64, dbuf, XOR-swizzled -----------
// MODE 0: write fp8 (bias opt, RELU opt).
// MODE 1: fp32 residual accumulate: x += val + bias.
// MODE 2: embed epilogue (val/256 + bp + stat + pe + fire_emb) -> fp32 x.
template<int MODE, bool RELU>
__global__ __launch_bounds__(256) void gemm_k(const unsigned char* __restrict__ A,
    const unsigned char* __restrict__ Wt, const float* __restrict__ bias,
    unsigned char* __restrict__ outb, float* __restrict__ xout,
    const int* __restrict__ fire, const float* __restrict__ pe,
    const float* __restrict__ stat_emb, const int* __restrict__ stn_p,
    const float* __restrict__ fire_emb, int M, int K){
  __shared__ __align__(16) unsigned char As[2][128*64];   // 2x8 KB
  __shared__ __align__(16) unsigned char Bs[2][128*64];   // 2x8 KB
  const int tid  = threadIdx.x;
  const int m0   = blockIdx.x * 128;
  const int n0   = blockIdx.y * 128;
  const int wave = tid >> 6, lane = tid & 63;
  const int wr = wave >> 1, wc = wave & 1;
  const int lrow = lane & 15, quad = lane >> 4;
  // swizzle: logical 16B chunk j of row r lives at physical jp = j ^ sw(r),
  // sw(r) = (r&3)^((r>>2)&3). For fragment rows, sw depends only on lrow.
  const int lsw = (lrow & 3) ^ ((lrow >> 2) & 3);
  floatx4 acc[4][4];
  #pragma unroll
  for(int i=0;i<4;i++)
    #pragma unroll
    for(int j=0;j<4;j++) acc[i][j] = (floatx4){0.f,0.f,0.f,0.f};

  const int S = K >> 6;
  auto stage = [&](int s, int bi){
    const int kk = s*64;
    #pragma unroll
    for(int p=0;p<2;p++){
      int i = tid + p*256;
      int r = i >> 2, jp = i & 3;
      int jl = jp ^ (r & 3) ^ ((r >> 2) & 3);
      gld_lds16(&A [(size_t)(n0+r)*K + kk + jl*16], &As[bi][i*16]);
      gld_lds16(&Wt[(size_t)(m0+r)*K + kk + jl*16], &Bs[bi][i*16]);
    }
  };
  stage(0, 0);
  for(int s=0; s<S; s++){
    const int bi = s & 1;
    __syncthreads();
    if(s+1 < S) stage(s+1, bi^1);
    #pragma unroll
    for(int ks=0; ks<2; ks++){
      // byte offset in row: o = ks*32 + quad*8; chunk j=o>>4; within = (quad&1)*8
      const int joff = (((ks*2 + (quad>>1)) ^ lsw) << 4) + (quad & 1)*8;
      long af[4], bfv[4];
      #pragma unroll
      for(int ti=0;ti<4;ti++)
        af[ti]  = *(const long*)(&As[bi][(wr*64+ti*16+lrow)*64 + joff]);
      #pragma unroll
      for(int tj=0;tj<4;tj++)
        bfv[tj] = *(const long*)(&Bs[bi][(wc*64+tj*16+lrow)*64 + joff]);
      #pragma unroll
      for(int ti=0;ti<4;ti++)
        #pragma unroll
        for(int tj=0;tj<4;tj++)
          acc[ti][tj] = __builtin_amdgcn_mfma_f32_16x16x32_fp8_fp8(af[ti], bfv[tj], acc[ti][tj], 0,0,0);
    }
  }
  const int stn = (MODE==2) ? stn_p[0] : 0;
  #pragma unroll
  for(int ti=0;ti<4;ti++){
    #pragma unroll
    for(int r=0;r<4;r++){
      int row = n0 + wr*64 + ti*16 + quad*4 + r;
      int fidx = 0, trow = 0;
      if(MODE==2){ fidx = fire[row]; trow = row % TBLK; }
      #pragma unroll
      for(int tj=0;tj<4;tj++){
        int col = m0 + wc*64 + tj*16 + lrow;
        float val = acc[ti][tj][r];
        if(MODE==0){
          if(bias) val += bias[col];
          if(RELU) val = fmaxf(val, 0.f);
          outb[(size_t)row*M + col] = f2fp8(val);
        } else if(MODE==1){
          xout[(size_t)row*EDIM + col] += val + bias[col];
        } else {
          val = val*(1.f/256.f) + bias[col] + stat_emb[(size_t)stn*EDIM + col]
              + pe[trow*EDIM + col] + fire_emb[(size_t)fidx*EDIM + col];
          xout[(size_t)row*EDIM + col] = val;
        }
      }
    }
  }
}

// ------- full-row GEMM + residual + LayerNorm epilogue (Wo only, K=384) -------
// 512 thr (8 waves): rw in [0,4) 16-row group, cw in [0,2) 192-col half.
__global__ __launch_bounds__(512, 4) void gemm_row_ln(
    const unsigned char* __restrict__ A, const unsigned char* __restrict__ Wt,
    const float* __restrict__ bias, float* __restrict__ x,
    const float* __restrict__ g, const float* __restrict__ b,
    unsigned char* __restrict__ h, int K, int writeH){
  __shared__ __align__(16) unsigned char As[2][64*32];     // 2x2 KB
  __shared__ __align__(16) unsigned char Bs[2][384*32];    // 2x12 KB
  const int tid = threadIdx.x;
  const int n0 = blockIdx.x * 64;
  const int wave = tid >> 6, lane = tid & 63;
  const int rw = wave >> 1, cw = wave & 1;
  const int lrow = lane & 15, quad = lane >> 4;
  const int xsw = ((lane >> 2) & 1) << 4;
  floatx4 acc[12];
  #pragma unroll
  for(int j=0;j<12;j++) acc[j] = (floatx4){0.f,0.f,0.f,0.f};

  const int S = K >> 5;
  auto stage = [&](int s, int bi){
    const int kk = s*32;
    if(tid < 128){
      int r = tid >> 1, c = (((tid&1) ^ ((tid>>3)&1))) * 16;
      gld_lds16(&A[(size_t)(n0+r)*K + kk + c], &As[bi][tid*16]);
    }
    {
      int i = tid;
      int r = i >> 1, c = (((i&1) ^ ((i>>3)&1))) * 16;
      gld_lds16(&Wt[(size_t)r*K + kk + c], &Bs[bi][i*16]);
    }
    if(tid < 256){
      int i = tid + 512;
      int r = i >> 1, c = (((i&1) ^ ((i>>3)&1))) * 16;
      gld_lds16(&Wt[(size_t)r*K + kk + c], &Bs[bi][i*16]);
    }
  };
  stage(0, 0);
  for(int s=0; s<S; s++){
    const int bi = s & 1;
    __syncthreads();
    if(s+1 < S) stage(s+1, bi^1);
    long af = *(const long*)(&As[bi][(rw*16+lrow)*32 + ((quad*8) ^ xsw)]);
    long bfv[12];
    #pragma unroll
    for(int tj=0;tj<12;tj++)
      bfv[tj] = *(const long*)(&Bs[bi][(cw*192+tj*16+lrow)*32 + ((quad*8) ^ xsw)]);
    #pragma unroll
    for(int tj=0;tj<12;tj++)
      acc[tj] = __builtin_amdgcn_mfma_f32_16x16x32_fp8_fp8(af, bfv[tj], acc[tj], 0,0,0);
  }
  __syncthreads();
  float* part = (float*)&As[0][0];
  {
    float ps[4] = {0.f,0.f,0.f,0.f}, pq[4] = {0.f,0.f,0.f,0.f};
    #pragma unroll
    for(int tj=0;tj<12;tj++){
      const int col = cw*192 + tj*16 + lrow;
      const float bi = bias[col];
      #pragma unroll
      for(int r=0;r<4;r++){
        const int row = n0 + rw*16 + quad*4 + r;
        float v = acc[tj][r] + bi + x[(size_t)row*EDIM + col];
        acc[tj][r] = v;
        ps[r] += v; pq[r] += v*v;
      }
    }
    #pragma unroll
    for(int r=0;r<4;r++){
      #pragma unroll
      for(int m=1;m<16;m<<=1){ ps[r] += __shfl_xor(ps[r],m); pq[r] += __shfl_xor(pq[r],m); }
    }
    if(lrow == 0){
      #pragma unroll
      for(int r=0;r<4;r++){
        const int rl = rw*16 + quad*4 + r;
        part[rl*2 + cw]       = ps[r];
        part[128 + rl*2 + cw] = pq[r];
      }
    }
  }
  __syncthreads();
  #pragma unroll
  for(int r=0;r<4;r++){
    const int rl = rw*16 + quad*4 + r;
    const int row = n0 + rl;
    const float s = part[rl*2+0] + part[rl*2+1];
    const float q = part[128+rl*2+0] + part[128+rl*2+1];
    const float mean = s*(1.f/384.f);
    const float var  = q*(1.f/384.f) - mean*mean;
    const float rstd = rsqrtf(var + 1e-5f);
    #pragma unroll
    for(int tj=0;tj<12;tj++){
      const int col = cw*192 + tj*16 + lrow;
      const float v = acc[tj][r];
      x[(size_t)row*EDIM + col] = v;
      if(writeH)
        h[(size_t)row*EDIM + col] = f2fp8((v-mean)*rstd*g[col] + b[col]);
    }
  }
}

// ---------------- causal attention: 4 waves/block per (b,h), fp8 I/O ----------
__global__ __launch_bounds__(256) void attn_kernel(const unsigned char* __restrict__ qkv,
    unsigned char* __restrict__ o){
  const int bh = blockIdx.x;
  const int b = bh / NHEAD, h = bh % NHEAD;
  const int wave = threadIdx.x >> 6, lane = threadIdx.x & 63;
  const int tid = threadIdx.x;
  __shared__ float qs[TBLK*64];
  __shared__ float ks[TBLK*65];
  __shared__ float ps[TBLK*64];
  const size_t base = (size_t)b*TBLK*QKVSTR + h*DHEAD;
  const unsigned char* qp = qkv + base;
  const unsigned char* kp = qkv + base + 384;
  const unsigned char* vp = qkv + base + 768;
  for(int i=tid; i<TBLK*16; i+=256){
    int t = i >> 4, d4 = (i & 15) * 4;
    unsigned int rq = *(const unsigned int*)&qp[(size_t)t*QKVSTR + d4];
    unsigned int rk = *(const unsigned int*)&kp[(size_t)t*QKVSTR + d4];
    #pragma unroll
    for(int j=0;j<4;j++){
      qs[t*64 + d4 + j] = fp82f((unsigned char)(rq >> (8*j)));
      ks[t*65 + d4 + j] = fp82f((unsigned char)(rk >> (8*j)));
    }
  }
  float vreg[TBLK];
  #pragma unroll
  for(int s2=0;s2<TBLK;s2++) vreg[s2] = fp82f(vp[(size_t)s2*QKVSTR + lane]);
  __syncthreads();
  const int krow = (lane < TBLK) ? lane : (TBLK-1);
  float kreg[64];
  #pragma unroll
  for(int dd=0;dd<64;dd++) kreg[dd] = ks[krow*65 + dd];
  const float scale = 0.125f;
  #pragma unroll
  for(int j=0;j<9;j++){
    const int t = wave + 4*j;
    float d = 0.f;
    #pragma unroll
    for(int gg=0;gg<16;gg++){
      float4 q4 = *(const float4*)&qs[t*64 + gg*4];
      d = fmaf(q4.x, kreg[gg*4+0], d);
      d = fmaf(q4.y, kreg[gg*4+1], d);
      d = fmaf(q4.z, kreg[gg*4+2], d);
      d = fmaf(q4.w, kreg[gg*4+3], d);
    }
    float val = (lane <= t) ? d*scale : -INFINITY;
    float mx = val;
    #pragma unroll
    for(int m=1;m<64;m<<=1) mx = fmaxf(mx, __shfl_xor(mx,m));
    float p = __expf(val - mx);
    float sum = p;
    #pragma unroll
    for(int m=1;m<64;m<<=1) sum += __shfl_xor(sum,m);
    ps[t*64 + lane] = p / sum;
  }
  __syncthreads();
  #pragma unroll
  for(int j=0;j<9;j++){
    const int t = wave + 4*j;
    float acc = 0.f;
    #pragma unroll
    for(int gg=0;gg<9;gg++){
      float4 p4 = *(const float4*)&ps[t*64 + gg*4];
      acc = fmaf(p4.x, vreg[gg*4+0], acc);
      acc = fmaf(p4.y, vreg[gg*4+1], acc);
      acc = fmaf(p4.z, vreg[gg*4+2], acc);
      acc = fmaf(p4.w, vreg[gg*4+3], acc);
    }
    o[(size_t)b*TBLK*EDIM + (size_t)t*EDIM + h*DHEAD + lane] = f2fp8(acc);
  }
}

// ---------------- head: LNf + sigmoid(x@Wh+bh)*500 + per-block partials -------
__global__ __launch_bounds__(256) void head_kernel(const float* __restrict__ x,
    const float* __restrict__ g, const float* __restrict__ b,
    const float* __restrict__ Wh, const float* __restrict__ bh,
    const int* __restrict__ targets, float* __restrict__ out,
    float* __restrict__ partials){
  const int wave = threadIdx.x >> 6, lane = threadIdx.x & 63;
  const int row = blockIdx.x*4 + wave;
  const float* xr = x + (size_t)row*EDIM;
  float v[6]; float s=0.f, sq=0.f;
  #pragma unroll
  for(int j=0;j<6;j++){ v[j]=xr[j*64+lane]; s+=v[j]; sq+=v[j]*v[j]; }
  #pragma unroll
  for(int m=1;m<64;m<<=1){ s += __shfl_xor(s,m); sq += __shfl_xor(sq,m); }
  const float mean = s*(1.f/384.f);
  const float var  = sq*(1.f/384.f) - mean*mean;
  const float rstd = rsqrtf(var + 1e-5f);
  float dot = 0.f;
  #pragma unroll
  for(int j=0;j<6;j++){
    int e = j*64+lane;
    float hh = (v[j]-mean)*rstd*g[e] + b[e];
    dot = fmaf(hh, Wh[e], dot);
  }
  #pragma unroll
  for(int m=1;m<64;m<<=1) dot += __shfl_xor(dot,m);
  __shared__ float part[4][4];
  if(lane == 0){
    float logit = 1.f/(1.f + __expf(-(dot + bh[0])));
    float den = logit * 500.f;
    out[row] = den;
    float tgt = (float)targets[(size_t)row*2];
    float nt  = tgt * (1.f/500.f);
    part[wave][0] = (logit-nt)*(logit-nt);
    part[wave][1] = (tgt-den)*(tgt-den);
    part[wave][2] = tgt;
    part[wave][3] = tgt*tgt;
  }
  __syncthreads();
  if(threadIdx.x < 4){
    float t0 = part[0][threadIdx.x] + part[1][threadIdx.x]
             + part[2][threadIdx.x] + part[3][threadIdx.x];
    partials[(size_t)threadIdx.x*NHBLK + blockIdx.x] = t0;
  }
}

// ---------------- final reduction: partials[4][NHBLK] -> mse, r2 --------------
__global__ __launch_bounds__(1024) void finalize_reduce(
    const float* __restrict__ partials, float* __restrict__ out){
  __shared__ float red[16];
  const int tid = threadIdx.x;
  const int c = tid >> 8, j = tid & 255;
  float s = 0.f;
  for(int i = j; i < NHBLK; i += 256) s += partials[(size_t)c*NHBLK + i];
  #pragma unroll
  for(int m=1;m<64;m<<=1) s += __shfl_xor(s,m);
  if((tid & 63) == 0) red[tid >> 6] = s;
  __syncthreads();
  if(tid == 0){
    float a0 = red[0]+red[1]+red[2]+red[3];
    float a1 = red[4]+red[5]+red[6]+red[7];
    float a2 = red[8]+red[9]+red[10]+red[11];
    float a3 = red[12]+red[13]+red[14]+red[15];
    const float n = (float)NTOK;
    out[NTOK]   = a0 / n;
    float denom = a3 - a2*a2/n;
    out[NTOK+1] = 1.f - a1/denom;
  }
}

// =============================================================================
extern "C" void kernel_launch(void* const* d_in, const int* in_sizes, int n_in,
                              void* d_out, int out_size, void* d_ws, size_t ws_size,
                              hipStream_t stream){
  (void)in_sizes; (void)n_in; (void)out_size; (void)ws_size;
  const int*   idx      = (const int*)  d_in[0];
  const int*   targets  = (const int*)  d_in[1];
  const int*   stn_ix   = (const int*)  d_in[3];
  const float* Wp       = (const float*)d_in[4];
  const float* bp       = (const float*)d_in[5];
  const float* stat_emb = (const float*)d_in[6];
  const float* fire_emb = (const float*)d_in[7];
  const float* ln1_g    = (const float*)d_in[8];
  const float* ln1_b    = (const float*)d_in[9];
  const float* Wq       = (const float*)d_in[10];
  const float* Wk       = (const float*)d_in[11];
  const float* Wv       = (const float*)d_in[12];
  const float* Wo       = (const float*)d_in[13];
  const float* bo       = (const float*)d_in[14];
  const float* ln2_g    = (const float*)d_in[15];
  const float* ln2_b    = (const float*)d_in[16];
  const float* W1       = (const float*)d_in[17];
  const float* b1       = (const float*)d_in[18];
  const float* W2       = (const float*)d_in[19];
  const float* b2       = (const float*)d_in[20];
  const float* lnf_g    = (const float*)d_in[21];
  const float* lnf_b    = (const float*)d_in[22];
  const float* Wh       = (const float*)d_in[23];
  const float* bh       = (const float*)d_in[24];
  float* out = (float*)d_out;

  char* ws = (char*)d_ws;
  float*         x      = (float*)        (ws + 0);
  unsigned char* h      = (unsigned char*)(ws + 56623104);
  unsigned char* qkv    = (unsigned char*)(ws + 84934656);
  unsigned char* obuf   = (unsigned char*)(ws + 169869312);
  unsigned char* ffn    = qkv;
  unsigned char* pm     = (unsigned char*)(ws + 169869312);  // aliases obuf
  int*           fire   = (int*)          (ws + 186384384);
  unsigned char* wp_t   = (unsigned char*)(ws + 186531840);
  float*         pe     = (float*)        (ws + 186703872);
  float*         partials = (float*)      (ws + 169869312);  // aliases obuf
  unsigned char* wqkv_t = (unsigned char*)(ws + 198180864);
  unsigned char* wo_t   = (unsigned char*)(ws + 203489280);
  unsigned char* w1_t   = (unsigned char*)(ws + 205258752);
  unsigned char* w2_t   = (unsigned char*)(ws + 212336640);

  const dim3 tb(32,8);
  wt_transpose<<<dim3(12,12,6), tb, 0, stream>>>(Wq, wqkv_t,          384,  384, 442368);
  wt_transpose<<<dim3(12,12,6), tb, 0, stream>>>(Wk, wqkv_t + 147456, 384,  384, 442368);
  wt_transpose<<<dim3(12,12,6), tb, 0, stream>>>(Wv, wqkv_t + 294912, 384,  384, 442368);
  wt_transpose<<<dim3(12,12,6), tb, 0, stream>>>(Wo, wo_t,            384,  384, 147456);
  wt_transpose<<<dim3(48,12,6), tb, 0, stream>>>(W1, w1_t,            384, 1536, 589824);
  wt_transpose<<<dim3(12,48,6), tb, 0, stream>>>(W2, w2_t,           1536,  384, 589824);
  wp_transpose<<<384, 256, 0, stream>>>(Wp, wp_t);
  pe_kernel<<<TBLK, 384, 0, stream>>>(pe);
  prep_pm<<<(NTOK*KPM + 255)/256, 256, 0, stream>>>(idx, pm);
  prep_fire<<<(NTOK + 255)/256, 256, 0, stream>>>(idx, stn_ix, fire);

  // embed GEMM: x = (pm*256) @ wp_t^T / 256 + (bp + stat + pe + fire_emb)
  gemm_k<2,false><<<dim3(3,288), 256, 0, stream>>>(pm, wp_t, bp, nullptr, x,
      fire, pe, stat_emb, stn_ix, fire_emb, 384, KPM);

  // layer-0 ln1
  ln_act<<<NTOK/4, 256, 0, stream>>>(x, ln1_g, ln1_b, h);

  const dim3 gQKV(9, 288);
  const dim3 gE(3, 288);
  const dim3 gF(12, 288);
  for(int l=0; l<NLAYER; l++){
    gemm_k<0,false><<<gQKV, 256, 0, stream>>>(h, wqkv_t + (size_t)l*442368,
        nullptr, qkv, nullptr, nullptr, nullptr, nullptr, nullptr, nullptr, 1152, 384);
    attn_kernel<<<BSZ*NHEAD, 256, 0, stream>>>(qkv, obuf);
    // x += obuf@Wo + bo;  h = LN2(x)   (fused; K=384)
    gemm_row_ln<<<NTOK/64, 512, 0, stream>>>(obuf, wo_t + (size_t)l*147456,
        bo + l*EDIM, x, ln2_g + l*EDIM, ln2_b + l*EDIM, h, 384, 1);
    gemm_k<0,true><<<gF, 256, 0, stream>>>(h, w1_t + (size_t)l*589824,
        b1 + l*1536, ffn, nullptr, nullptr, nullptr, nullptr, nullptr, nullptr, 1536, 384);
    // x += ffn@W2 + b2   (fp8, fp32 residual epilogue)
    gemm_k<1,false><<<gE, 256, 0, stream>>>(ffn, w2_t + (size_t)l*589824,
        b2 + l*EDIM, nullptr, x, nullptr, nullptr, nullptr, nullptr, nullptr, 384, 1536);
    // h = LN1[l+1](x)  (skip on last layer; head does LNf itself)
    if(l < NLAYER-1)
      ln_act<<<NTOK/4, 256, 0, stream>>>(x, ln1_g + (l+1)*EDIM, ln1_b + (l+1)*EDIM, h);
  }

  head_kernel<<<NHBLK, 256, 0, stream>>>(x, lnf_g, lnf_b, Wh, bh, targets, out, partials);
  finalize_reduce<<<1, 1024, 0, stream>>>(partials, out);
}

// Round 9
// 2077.847 us; speedup vs baseline: 2.2236x; 1.0937x over previous
//
#include <hip/hip_runtime.h>
#include <hip/hip_fp8.h>
#include <stdint.h>

// PM25 transformer forward, MI355X/gfx950. Round 9:
//   - gemm_k MODE 0 epilogue: LDS repack (Cs[128][128] fp8 reusing As) +
//     coalesced dwordx4 stores (was 64 per-value global byte-stores/wave,
//     64 B/instr in 4 scattered segments -> now 1024 B/instr).
//   - NOTE: SQ_LDS_BANK_CONFLICT==5308416 across R6/R7/R8 (3 different layouts)
//     = 96 frag reads/wave x 4 = counter tallies inherent 64-lane/32-bank
//     2-way phases (time-free, m136). Not a real conflict; ignore.
//   - everything else bit-identical to R8.

#define EDIM   384
#define NHEAD  6
#define DHEAD  64
#define NLAYER 6
#define TBLK   36
#define SNUM   210
#define BSZ    1024
#define NTOK   (BSZ*TBLK)
#define QKVSTR 1152
#define KPM    256
#define NHBLK  (NTOK/4)

typedef __attribute__((ext_vector_type(4))) float floatx4;
typedef __attribute__((ext_vector_type(4))) unsigned int uintx4;

static __device__ __forceinline__ unsigned char f2fp8(float f){
  __hip_fp8_e4m3 t(f); return t.__x;
}
static __device__ __forceinline__ float fp82f(unsigned char u){
  __hip_fp8_e4m3 t; t.__x = u; return (float)t;
}
static __device__ __forceinline__ void gld_lds16(const void* g, void* l){
  __builtin_amdgcn_global_load_lds(
      (const __attribute__((address_space(1))) void*)g,
      (__attribute__((address_space(3))) void*)l, 16, 0, 0);
}

// ---------------- weight transpose + fp8 cast: out[m][k] = fp8(in[k][m]) ------
__global__ __launch_bounds__(256) void wt_transpose(const float* __restrict__ in,
    unsigned char* __restrict__ out, int K, int M, long outStride){
  __shared__ float tile[32][33];
  const int mat = blockIdx.z;
  const float* src = in + (size_t)mat*K*M;
  unsigned char* dst = out + (size_t)mat*outStride;
  const int m0 = blockIdx.x*32, k0 = blockIdx.y*32;
  const int tx = threadIdx.x, ty = threadIdx.y;
  for(int i=ty;i<32;i+=8) tile[i][tx] = src[(size_t)(k0+i)*M + m0+tx];
  __syncthreads();
  for(int i=ty;i<32;i+=8) dst[(size_t)(m0+i)*K + k0+tx] = f2fp8(tile[tx][i]);
}

// Wp [210,384] -> wp_t fp8 [384,256] (K zero-padded 210->256)
__global__ __launch_bounds__(256) void wp_transpose(const float* __restrict__ Wp,
    unsigned char* __restrict__ wp_t){
  const int m = blockIdx.x, k = threadIdx.x;
  wp_t[(size_t)m*KPM + k] = (k < SNUM) ? f2fp8(Wp[(size_t)k*EDIM + m]) : 0;
}

// pm fp8 [36864,256]: pm[row][s] = fp8(idx*256/500); x256 undone in epilogue
__global__ __launch_bounds__(256) void prep_pm(const int* __restrict__ idx,
    unsigned char* __restrict__ pm){
  const long i = (long)blockIdx.x*256 + threadIdx.x;
  if(i >= (long)NTOK*KPM) return;
  const int row = i / KPM, s = i - (long)row*KPM;
  float v = 0.f;
  if(s < SNUM) v = (float)idx[((size_t)row*SNUM + s)*2] * (256.f/500.f);
  pm[i] = f2fp8(v);
}

__global__ __launch_bounds__(256) void prep_fire(const int* __restrict__ idx,
    const int* __restrict__ stn_p, int* __restrict__ fire){
  const int row = blockIdx.x*256 + threadIdx.x;
  if(row < NTOK) fire[row] = idx[((size_t)row*SNUM + stn_p[0])*2 + 1];
}

__global__ __launch_bounds__(384) void pe_kernel(float* __restrict__ pe){
  const int t = blockIdx.x, e = threadIdx.x;
  const float freq = __expf(-(float)(2*(e>>1)) * (9.210340371976184f/384.f));
  const float ang = (float)t * freq;
  pe[t*EDIM + e] = (e & 1) ? __cosf(ang) : __sinf(ang);
}

// ---------------- layernorm fp32 -> fp8, one wave per row --------------------
__global__ __launch_bounds__(256) void ln_act(const float* __restrict__ x,
    const float* __restrict__ g, const float* __restrict__ b,
    unsigned char* __restrict__ out){
  const int wave = threadIdx.x >> 6, lane = threadIdx.x & 63;
  const int row = blockIdx.x*4 + wave;
  const float* xr = x + (size_t)row*EDIM;
  float v[6]; float s=0.f, sq=0.f;
  #pragma unroll
  for(int j=0;j<6;j++){ v[j]=xr[j*64+lane]; s+=v[j]; sq+=v[j]*v[j]; }
  #pragma unroll
  for(int m=1;m<64;m<<=1){ s += __shfl_xor(s,m); sq += __shfl_xor(sq,m); }
  const float mean = s*(1.f/384.f);
  const float var  = sq*(1.f/384.f) - mean*mean;
  const float rstd = rsqrtf(var + 1e-5f);
  unsigned char* orow = out + (size_t)row*EDIM;
  #pragma unroll
  for(int j=0;j<6;j++){
    int e = j*64+lane;
    orow[e] = f2fp8((v[j]-mean)*rstd*g[e] + b[e]);
  }
}

// ---------------- fp8 MFMA GEMM, 128x128, BK=64, dbuf, XOR-swizzled -----------
// MODE 0: write fp8 via LDS repack + dwordx4 (bias opt, RELU opt).
// MODE 1: fp32 residual accumulate: x += val + bias.
// MODE 2: embed epilogue (val/256 + bp + stat + pe + fire_emb) -> fp32 x.
template<int MODE, bool RELU>
__global__ __launch_bounds__(256) void gemm_k(const unsigned char* __restrict__ A,
    const unsigned char* __restrict__ Wt, const float* __restrict__ bias,
    unsigned char* __restrict__ outb, float* __restrict__ xout,
    const int* __restrict__ fire, const float* __restrict__ pe,
    const float* __restrict__ stat_emb, const int* __restrict__ stn_p,
    const float* __restrict__ fire_emb, int M, int K){
  __shared__ __align__(16) unsigned char As[2][128*64];   // 2x8 KB
  __shared__ __align__(16) unsigned char Bs[2][128*64];   // 2x8 KB
  const int tid  = threadIdx.x;
  const int m0   = blockIdx.x * 128;
  const int n0   = blockIdx.y * 128;
  const int wave = tid >> 6, lane = tid & 63;
  const int wr = wave >> 1, wc = wave & 1;
  const int lrow = lane & 15, quad = lane >> 4;
  const int lsw = (lrow & 3) ^ ((lrow >> 2) & 3);
  floatx4 acc[4][4];
  #pragma unroll
  for(int i=0;i<4;i++)
    #pragma unroll
    for(int j=0;j<4;j++) acc[i][j] = (floatx4){0.f,0.f,0.f,0.f};

  const int S = K >> 6;
  auto stage = [&](int s, int bi){
    const int kk = s*64;
    #pragma unroll
    for(int p=0;p<2;p++){
      int i = tid + p*256;
      int r = i >> 2, jp = i & 3;
      int jl = jp ^ (r & 3) ^ ((r >> 2) & 3);
      gld_lds16(&A [(size_t)(n0+r)*K + kk + jl*16], &As[bi][i*16]);
      gld_lds16(&Wt[(size_t)(m0+r)*K + kk + jl*16], &Bs[bi][i*16]);
    }
  };
  stage(0, 0);
  for(int s=0; s<S; s++){
    const int bi = s & 1;
    __syncthreads();
    if(s+1 < S) stage(s+1, bi^1);
    #pragma unroll
    for(int ks=0; ks<2; ks++){
      const int joff = (((ks*2 + (quad>>1)) ^ lsw) << 4) + (quad & 1)*8;
      long af[4], bfv[4];
      #pragma unroll
      for(int ti=0;ti<4;ti++)
        af[ti]  = *(const long*)(&As[bi][(wr*64+ti*16+lrow)*64 + joff]);
      #pragma unroll
      for(int tj=0;tj<4;tj++)
        bfv[tj] = *(const long*)(&Bs[bi][(wc*64+tj*16+lrow)*64 + joff]);
      #pragma unroll
      for(int ti=0;ti<4;ti++)
        #pragma unroll
        for(int tj=0;tj<4;tj++)
          acc[ti][tj] = __builtin_amdgcn_mfma_f32_16x16x32_fp8_fp8(af[ti], bfv[tj], acc[ti][tj], 0,0,0);
    }
  }
  if(MODE==0){
    // LDS repack: convert in-register, byte-write to Cs, coalesced dwordx4 out
    __syncthreads();                       // all waves done reading As
    unsigned char* Cs = (unsigned char*)&As[0][0];   // 16 KB == sizeof(As)
    #pragma unroll
    for(int ti=0;ti<4;ti++){
      #pragma unroll
      for(int tj=0;tj<4;tj++){
        const int col = wc*64 + tj*16 + lrow;
        const float bi = bias ? bias[m0+col] : 0.f;
        #pragma unroll
        for(int r=0;r<4;r++){
          const int row = wr*64 + ti*16 + quad*4 + r;
          float val = acc[ti][tj][r] + bi;
          if(RELU) val = fmaxf(val, 0.f);
          Cs[row*128 + col] = f2fp8(val);
        }
      }
    }
    __syncthreads();
    #pragma unroll
    for(int p=0;p<4;p++){
      const int q = tid + p*256;
      const int row = q >> 3, c16 = (q & 7)*16;
      *(uintx4*)(&outb[(size_t)(n0+row)*M + m0 + c16]) =
          *(const uintx4*)(&Cs[row*128 + c16]);
    }
  } else {
    const int stn = (MODE==2) ? stn_p[0] : 0;
    #pragma unroll
    for(int ti=0;ti<4;ti++){
      #pragma unroll
      for(int r=0;r<4;r++){
        int row = n0 + wr*64 + ti*16 + quad*4 + r;
        int fidx = 0, trow = 0;
        if(MODE==2){ fidx = fire[row]; trow = row % TBLK; }
        #pragma unroll
        for(int tj=0;tj<4;tj++){
          int col = m0 + wc*64 + tj*16 + lrow;
          float val = acc[ti][tj][r];
          if(MODE==1){
            xout[(size_t)row*EDIM + col] += val + bias[col];
          } else {
            val = val*(1.f/256.f) + bias[col] + stat_emb[(size_t)stn*EDIM + col]
                + pe[trow*EDIM + col] + fire_emb[(size_t)fidx*EDIM + col];
            xout[(size_t)row*EDIM + col] = val;
          }
        }
      }
    }
  }
}

// ------- full-row GEMM + residual + LayerNorm epilogue (Wo only, K=384) -------
__global__ __launch_bounds__(512, 4) void gemm_row_ln(
    const unsigned char* __restrict__ A, const unsigned char* __restrict__ Wt,
    const float* __restrict__ bias, float* __restrict__ x,
    const float* __restrict__ g, const float* __restrict__ b,
    unsigned char* __restrict__ h, int K, int writeH){
  __shared__ __align__(16) unsigned char As[2][64*32];     // 2x2 KB
  __shared__ __align__(16) unsigned char Bs[2][384*32];    // 2x12 KB
  const int tid = threadIdx.x;
  const int n0 = blockIdx.x * 64;
  const int wave = tid >> 6, lane = tid & 63;
  const int rw = wave >> 1, cw = wave & 1;
  const int lrow = lane & 15, quad = lane >> 4;
  const int xsw = ((lane >> 2) & 1) << 4;
  floatx4 acc[12];
  #pragma unroll
  for(int j=0;j<12;j++) acc[j] = (floatx4){0.f,0.f,0.f,0.f};

  const int S = K >> 5;
  auto stage = [&](int s, int bi){
    const int kk = s*32;
    if(tid < 128){
      int r = tid >> 1, c = (((tid&1) ^ ((tid>>3)&1))) * 16;
      gld_lds16(&A[(size_t)(n0+r)*K + kk + c], &As[bi][tid*16]);
    }
    {
      int i = tid;
      int r = i >> 1, c = (((i&1) ^ ((i>>3)&1))) * 16;
      gld_lds16(&Wt[(size_t)r*K + kk + c], &Bs[bi][i*16]);
    }
    if(tid < 256){
      int i = tid + 512;
      int r = i >> 1, c = (((i&1) ^ ((i>>3)&1))) * 16;
      gld_lds16(&Wt[(size_t)r*K + kk + c], &Bs[bi][i*16]);
    }
  };
  stage(0, 0);
  for(int s=0; s<S; s++){
    const int bi = s & 1;
    __syncthreads();
    if(s+1 < S) stage(s+1, bi^1);
    long af = *(const long*)(&As[bi][(rw*16+lrow)*32 + ((quad*8) ^ xsw)]);
    long bfv[12];
    #pragma unroll
    for(int tj=0;tj<12;tj++)
      bfv[tj] = *(const long*)(&Bs[bi][(cw*192+tj*16+lrow)*32 + ((quad*8) ^ xsw)]);
    #pragma unroll
    for(int tj=0;tj<12;tj++)
      acc[tj] = __builtin_amdgcn_mfma_f32_16x16x32_fp8_fp8(af, bfv[tj], acc[tj], 0,0,0);
  }
  __syncthreads();
  float* part = (float*)&As[0][0];
  {
    float ps[4] = {0.f,0.f,0.f,0.f}, pq[4] = {0.f,0.f,0.f,0.f};
    #pragma unroll
    for(int tj=0;tj<12;tj++){
      const int col = cw*192 + tj*16 + lrow;
      const float bi = bias[col];
      #pragma unroll
      for(int r=0;r<4;r++){
        const int row = n0 + rw*16 + quad*4 + r;
        float v = acc[tj][r] + bi + x[(size_t)row*EDIM + col];
        acc[tj][r] = v;
        ps[r] += v; pq[r] += v*v;
      }
    }
    #pragma unroll
    for(int r=0;r<4;r++){
      #pragma unroll
      for(int m=1;m<16;m<<=1){ ps[r] += __shfl_xor(ps[r],m); pq[r] += __shfl_xor(pq[r],m); }
    }
    if(lrow == 0){
      #pragma unroll
      for(int r=0;r<4;r++){
        const int rl = rw*16 + quad*4 + r;
        part[rl*2 + cw]       = ps[r];
        part[128 + rl*2 + cw] = pq[r];
      }
    }
  }
  __syncthreads();
  #pragma unroll
  for(int r=0;r<4;r++){
    const int rl = rw*16 + quad*4 + r;
    const int row = n0 + rl;
    const float s = part[rl*2+0] + part[rl*2+1];
    const float q = part[128+rl*2+0] + part[128+rl*2+1];
    const float mean = s*(1.f/384.f);
    const float var  = q*(1.f/384.f) - mean*mean;
    const float rstd = rsqrtf(var + 1e-5f);
    #pragma unroll
    for(int tj=0;tj<12;tj++){
      const int col = cw*192 + tj*16 + lrow;
      const float v = acc[tj][r];
      x[(size_t)row*EDIM + col] = v;
      if(writeH)
        h[(size_t)row*EDIM + col] = f2fp8((v-mean)*rstd*g[col] + b[col]);
    }
  }
}

// ---------------- causal attention: 4 waves/block per (b,h), fp8 I/O ----------
__global__ __launch_bounds__(256) void attn_kernel(const unsigned char* __restrict__ qkv,
    unsigned char* __restrict__ o){
  const int bh = blockIdx.x;
  const int b = bh / NHEAD, h = bh % NHEAD;
  const int wave = threadIdx.x >> 6, lane = threadIdx.x & 63;
  const int tid = threadIdx.x;
  __shared__ float qs[TBLK*64];
  __shared__ float ks[TBLK*65];
  __shared__ float ps[TBLK*64];
  const size_t base = (size_t)b*TBLK*QKVSTR + h*DHEAD;
  const unsigned char* qp = qkv + base;
  const unsigned char* kp = qkv + base + 384;
  const unsigned char* vp = qkv + base + 768;
  for(int i=tid; i<TBLK*16; i+=256){
    int t = i >> 4, d4 = (i & 15) * 4;
    unsigned int rq = *(const unsigned int*)&qp[(size_t)t*QKVSTR + d4];
    unsigned int rk = *(const unsigned int*)&kp[(size_t)t*QKVSTR + d4];
    #pragma unroll
    for(int j=0;j<4;j++){
      qs[t*64 + d4 + j] = fp82f((unsigned char)(rq >> (8*j)));
      ks[t*65 + d4 + j] = fp82f((unsigned char)(rk >> (8*j)));
    }
  }
  float vreg[TBLK];
  #pragma unroll
  for(int s2=0;s2<TBLK;s2++) vreg[s2] = fp82f(vp[(size_t)s2*QKVSTR + lane]);
  __syncthreads();
  const int krow = (lane < TBLK) ? lane : (TBLK-1);
  float kreg[64];
  #pragma unroll
  for(int dd=0;dd<64;dd++) kreg[dd] = ks[krow*65 + dd];
  const float scale = 0.125f;
  #pragma unroll
  for(int j=0;j<9;j++){
    const int t = wave + 4*j;
    float d = 0.f;
    #pragma unroll
    for(int gg=0;gg<16;gg++){
      float4 q4 = *(const float4*)&qs[t*64 + gg*4];
      d = fmaf(q4.x, kreg[gg*4+0], d);
      d = fmaf(q4.y, kreg[gg*4+1], d);
      d = fmaf(q4.z, kreg[gg*4+2], d);
      d = fmaf(q4.w, kreg[gg*4+3], d);
    }
    float val = (lane <= t) ? d*scale : -INFINITY;
    float mx = val;
    #pragma unroll
    for(int m=1;m<64;m<<=1) mx = fmaxf(mx, __shfl_xor(mx,m));
    float p = __expf(val - mx);
    float sum = p;
    #pragma unroll
    for(int m=1;m<64;m<<=1) sum += __shfl_xor(sum,m);
    ps[t*64 + lane] = p / sum;
  }
  __syncthreads();
  #pragma unroll
  for(int j=0;j<9;j++){
    const int t = wave + 4*j;
    float acc = 0.f;
    #pragma unroll
    for(int gg=0;gg<9;gg++){
      float4 p4 = *(const float4*)&ps[t*64 + gg*4];
      acc = fmaf(p4.x, vreg[gg*4+0], acc);
      acc = fmaf(p4.y, vreg[gg*4+1], acc);
      acc = fmaf(p4.z, vreg[gg*4+2], acc);
      acc = fmaf(p4.w, vreg[gg*4+3], acc);
    }
    o[(size_t)b*TBLK*EDIM + (size_t)t*EDIM + h*DHEAD + lane] = f2fp8(acc);
  }
}

// ---------------- head: LNf + sigmoid(x@Wh+bh)*500 + per-block partials -------
__global__ __launch_bounds__(256) void head_kernel(const float* __restrict__ x,
    const float* __restrict__ g, const float* __restrict__ b,
    const float* __restrict__ Wh, const float* __restrict__ bh,
    const int* __restrict__ targets, float* __restrict__ out,
    float* __restrict__ partials){
  const int wave = threadIdx.x >> 6, lane = threadIdx.x & 63;
  const int row = blockIdx.x*4 + wave;
  const float* xr = x + (size_t)row*EDIM;
  float v[6]; float s=0.f, sq=0.f;
  #pragma unroll
  for(int j=0;j<6;j++){ v[j]=xr[j*64+lane]; s+=v[j]; sq+=v[j]*v[j]; }
  #pragma unroll
  for(int m=1;m<64;m<<=1){ s += __shfl_xor(s,m); sq += __shfl_xor(sq,m); }
  const float mean = s*(1.f/384.f);
  const float var  = sq*(1.f/384.f) - mean*mean;
  const float rstd = rsqrtf(var + 1e-5f);
  float dot = 0.f;
  #pragma unroll
  for(int j=0;j<6;j++){
    int e = j*64+lane;
    float hh = (v[j]-mean)*rstd*g[e] + b[e];
    dot = fmaf(hh, Wh[e], dot);
  }
  #pragma unroll
  for(int m=1;m<64;m<<=1) dot += __shfl_xor(dot,m);
  __shared__ float part[4][4];
  if(lane == 0){
    float logit = 1.f/(1.f + __expf(-(dot + bh[0])));
    float den = logit * 500.f;
    out[row] = den;
    float tgt = (float)targets[(size_t)row*2];
    float nt  = tgt * (1.f/500.f);
    part[wave][0] = (logit-nt)*(logit-nt);
    part[wave][1] = (tgt-den)*(tgt-den);
    part[wave][2] = tgt;
    part[wave][3] = tgt*tgt;
  }
  __syncthreads();
  if(threadIdx.x < 4){
    float t0 = part[0][threadIdx.x] + part[1][threadIdx.x]
             + part[2][threadIdx.x] + part[3][threadIdx.x];
    partials[(size_t)threadIdx.x*NHBLK + blockIdx.x] = t0;
  }
}

// ---------------- final reduction: partials[4][NHBLK] -> mse, r2 --------------
__global__ __launch_bounds__(1024) void finalize_reduce(
    const float* __restrict__ partials, float* __restrict__ out){
  __shared__ float red[16];
  const int tid = threadIdx.x;
  const int c = tid >> 8, j = tid & 255;
  float s = 0.f;
  for(int i = j; i < NHBLK; i += 256) s += partials[(size_t)c*NHBLK + i];
  #pragma unroll
  for(int m=1;m<64;m<<=1) s += __shfl_xor(s,m);
  if((tid & 63) == 0) red[tid >> 6] = s;
  __syncthreads();
  if(tid == 0){
    float a0 = red[0]+red[1]+red[2]+red[3];
    float a1 = red[4]+red[5]+red[6]+red[7];
    float a2 = red[8]+red[9]+red[10]+red[11];
    float a3 = red[12]+red[13]+red[14]+red[15];
    const float n = (float)NTOK;
    out[NTOK]   = a0 / n;
    float denom = a3 - a2*a2/n;
    out[NTOK+1] = 1.f - a1/denom;
  }
}

// =============================================================================
extern "C" void kernel_launch(void* const* d_in, const int* in_sizes, int n_in,
                              void* d_out, int out_size, void* d_ws, size_t ws_size,
                              hipStream_t stream){
  (void)in_sizes; (void)n_in; (void)out_size; (void)ws_size;
  const int*   idx      = (const int*)  d_in[0];
  const int*   targets  = (const int*)  d_in[1];
  const int*   stn_ix   = (const int*)  d_in[3];
  const float* Wp       = (const float*)d_in[4];
  const float* bp       = (const float*)d_in[5];
  const float* stat_emb = (const float*)d_in[6];
  const float* fire_emb = (const float*)d_in[7];
  const float* ln1_g    = (const float*)d_in[8];
  const float* ln1_b    = (const float*)d_in[9];
  const float* Wq       = (const float*)d_in[10];
  const float* Wk       = (const float*)d_in[11];
  const float* Wv       = (const float*)d_in[12];
  const float* Wo       = (const float*)d_in[13];
  const float* bo       = (const float*)d_in[14];
  const float* ln2_g    = (const float*)d_in[15];
  const float* ln2_b    = (const float*)d_in[16];
  const float* W1       = (const float*)d_in[17];
  const float* b1       = (const float*)d_in[18];
  const float* W2       = (const float*)d_in[19];
  const float* b2       = (const float*)d_in[20];
  const float* lnf_g    = (const float*)d_in[21];
  const float* lnf_b    = (const float*)d_in[22];
  const float* Wh       = (const float*)d_in[23];
  const float* bh       = (const float*)d_in[24];
  float* out = (float*)d_out;

  char* ws = (char*)d_ws;
  float*         x      = (float*)        (ws + 0);
  unsigned char* h      = (unsigned char*)(ws + 56623104);
  unsigned char* qkv    = (unsigned char*)(ws + 84934656);
  unsigned char* obuf   = (unsigned char*)(ws + 169869312);
  unsigned char* ffn    = qkv;
  unsigned char* pm     = (unsigned char*)(ws + 169869312);  // aliases obuf
  int*           fire   = (int*)          (ws + 186384384);
  unsigned char* wp_t   = (unsigned char*)(ws + 186531840);
  float*         pe     = (float*)        (ws + 186703872);
  float*         partials = (float*)      (ws + 169869312);  // aliases obuf
  unsigned char* wqkv_t = (unsigned char*)(ws + 198180864);
  unsigned char* wo_t   = (unsigned char*)(ws + 203489280);
  unsigned char* w1_t   = (unsigned char*)(ws + 205258752);
  unsigned char* w2_t   = (unsigned char*)(ws + 212336640);

  const dim3 tb(32,8);
  wt_transpose<<<dim3(12,12,6), tb, 0, stream>>>(Wq, wqkv_t,          384,  384, 442368);
  wt_transpose<<<dim3(12,12,6), tb, 0, stream>>>(Wk, wqkv_t + 147456, 384,  384, 442368);
  wt_transpose<<<dim3(12,12,6), tb, 0, stream>>>(Wv, wqkv_t + 294912, 384,  384, 442368);
  wt_transpose<<<dim3(12,12,6), tb, 0, stream>>>(Wo, wo_t,            384,  384, 147456);
  wt_transpose<<<dim3(48,12,6), tb, 0, stream>>>(W1, w1_t,            384, 1536, 589824);
  wt_transpose<<<dim3(12,48,6), tb, 0, stream>>>(W2, w2_t,           1536,  384, 589824);
  wp_transpose<<<384, 256, 0, stream>>>(Wp, wp_t);
  pe_kernel<<<TBLK, 384, 0, stream>>>(pe);
  prep_pm<<<(NTOK*KPM + 255)/256, 256, 0, stream>>>(idx, pm);
  prep_fire<<<(NTOK + 255)/256, 256, 0, stream>>>(idx, stn_ix, fire);

  // embed GEMM: x = (pm*256) @ wp_t^T / 256 + (bp + stat + pe + fire_emb)
  gemm_k<2,false><<<dim3(3,288), 256, 0, stream>>>(pm, wp_t, bp, nullptr, x,
      fire, pe, stat_emb, stn_ix, fire_emb, 384, KPM);

  // layer-0 ln1
  ln_act<<<NTOK/4, 256, 0, stream>>>(x, ln1_g, ln1_b, h);

  const dim3 gQKV(9, 288);
  const dim3 gE(3, 288);
  const dim3 gF(12, 288);
  for(int l=0; l<NLAYER; l++){
    gemm_k<0,false><<<gQKV, 256, 0, stream>>>(h, wqkv_t + (size_t)l*442368,
        nullptr, qkv, nullptr, nullptr, nullptr, nullptr, nullptr, nullptr, 1152, 384);
    attn_kernel<<<BSZ*NHEAD, 256, 0, stream>>>(qkv, obuf);
    // x += obuf@Wo + bo;  h = LN2(x)   (fused; K=384)
    gemm_row_ln<<<NTOK/64, 512, 0, stream>>>(obuf, wo_t + (size_t)l*147456,
        bo + l*EDIM, x, ln2_g + l*EDIM, ln2_b + l*EDIM, h, 384, 1);
    gemm_k<0,true><<<gF, 256, 0, stream>>>(h, w1_t + (size_t)l*589824,
        b1 + l*1536, ffn, nullptr, nullptr, nullptr, nullptr, nullptr, nullptr, 1536, 384);
    // x += ffn@W2 + b2   (fp8, fp32 residual epilogue)
    gemm_k<1,false><<<gE, 256, 0, stream>>>(ffn, w2_t + (size_t)l*589824,
        b2 + l*EDIM, nullptr, x, nullptr, nullptr, nullptr, nullptr, nullptr, 384, 1536);
    // h = LN1[l+1](x)  (skip on last layer; head does LNf itself)
    if(l < NLAYER-1)
      ln_act<<<NTOK/4, 256, 0, stream>>>(x, ln1_g + (l+1)*EDIM, ln1_b + (l+1)*EDIM, h);
  }

  head_kernel<<<NHBLK, 256, 0, stream>>>(x, lnf_g, lnf_b, Wh, bh, targets, out, partials);
  finalize_reduce<<<1, 1024, 0, stream>>>(partials, out);
}

// Round 10
// 1890.155 us; speedup vs baseline: 2.4444x; 1.0993x over previous
//
#include <hip/hip_runtime.h>
#include <hip/hip_fp8.h>
#include <stdint.h>

// PM25 transformer forward, MI355X/gfx950. Round 10:
//   - attn_kernel v3: MFMA attention, one wave per (b,h), no cross-wave sync.
//     QK^T: fp8 16x16x32 MFMA, A/B frags read DIRECTLY from global (layout
//     matches row-major Q,K at D=64). Softmax in C-layout regs (quad-local
//     shfl). PV: P->LDS bf16 (A-layout re-entry), V^T->LDS bf16, bf16 MFMA.
//     O via LDS repack -> coalesced dwordx4. 42 MFMA/wave vs ~3900 scalar fmaf.
//   - everything else bit-identical to R9.
// (SQ_LDS_BANK_CONFLICT==5308416 on gemm_k is the structural 2-way phase tally
//  of wide LDS reads, time-free per m136 — ignore.)

#define EDIM   384
#define NHEAD  6
#define DHEAD  64
#define NLAYER 6
#define TBLK   36
#define SNUM   210
#define BSZ    1024
#define NTOK   (BSZ*TBLK)
#define QKVSTR 1152
#define KPM    256
#define NHBLK  (NTOK/4)

typedef __attribute__((ext_vector_type(4))) float floatx4;
typedef __attribute__((ext_vector_type(4))) unsigned int uintx4;
typedef __attribute__((ext_vector_type(8))) short short8;

static __device__ __forceinline__ unsigned char f2fp8(float f){
  __hip_fp8_e4m3 t(f); return t.__x;
}
static __device__ __forceinline__ float fp82f(unsigned char u){
  __hip_fp8_e4m3 t; t.__x = u; return (float)t;
}
static __device__ __forceinline__ unsigned short f2bf(float f){
  union { float fv; unsigned int u; } v; v.fv = f;
  unsigned int r = v.u + 0x7FFFu + ((v.u >> 16) & 1u);
  return (unsigned short)(r >> 16);
}
static __device__ __forceinline__ void gld_lds16(const void* g, void* l){
  __builtin_amdgcn_global_load_lds(
      (const __attribute__((address_space(1))) void*)g,
      (__attribute__((address_space(3))) void*)l, 16, 0, 0);
}

// ---------------- weight transpose + fp8 cast: out[m][k] = fp8(in[k][m]) ------
__global__ __launch_bounds__(256) void wt_transpose(const float* __restrict__ in,
    unsigned char* __restrict__ out, int K, int M, long outStride){
  __shared__ float tile[32][33];
  const int mat = blockIdx.z;
  const float* src = in + (size_t)mat*K*M;
  unsigned char* dst = out + (size_t)mat*outStride;
  const int m0 = blockIdx.x*32, k0 = blockIdx.y*32;
  const int tx = threadIdx.x, ty = threadIdx.y;
  for(int i=ty;i<32;i+=8) tile[i][tx] = src[(size_t)(k0+i)*M + m0+tx];
  __syncthreads();
  for(int i=ty;i<32;i+=8) dst[(size_t)(m0+i)*K + k0+tx] = f2fp8(tile[tx][i]);
}

// Wp [210,384] -> wp_t fp8 [384,256] (K zero-padded 210->256)
__global__ __launch_bounds__(256) void wp_transpose(const float* __restrict__ Wp,
    unsigned char* __restrict__ wp_t){
  const int m = blockIdx.x, k = threadIdx.x;
  wp_t[(size_t)m*KPM + k] = (k < SNUM) ? f2fp8(Wp[(size_t)k*EDIM + m]) : 0;
}

// pm fp8 [36864,256]: pm[row][s] = fp8(idx*256/500); x256 undone in epilogue
__global__ __launch_bounds__(256) void prep_pm(const int* __restrict__ idx,
    unsigned char* __restrict__ pm){
  const long i = (long)blockIdx.x*256 + threadIdx.x;
  if(i >= (long)NTOK*KPM) return;
  const int row = i / KPM, s = i - (long)row*KPM;
  float v = 0.f;
  if(s < SNUM) v = (float)idx[((size_t)row*SNUM + s)*2] * (256.f/500.f);
  pm[i] = f2fp8(v);
}

__global__ __launch_bounds__(256) void prep_fire(const int* __restrict__ idx,
    const int* __restrict__ stn_p, int* __restrict__ fire){
  const int row = blockIdx.x*256 + threadIdx.x;
  if(row < NTOK) fire[row] = idx[((size_t)row*SNUM + stn_p[0])*2 + 1];
}

__global__ __launch_bounds__(384) void pe_kernel(float* __restrict__ pe){
  const int t = blockIdx.x, e = threadIdx.x;
  const float freq = __expf(-(float)(2*(e>>1)) * (9.210340371976184f/384.f));
  const float ang = (float)t * freq;
  pe[t*EDIM + e] = (e & 1) ? __cosf(ang) : __sinf(ang);
}

// ---------------- layernorm fp32 -> fp8, one wave per row --------------------
__global__ __launch_bounds__(256) void ln_act(const float* __restrict__ x,
    const float* __restrict__ g, const float* __restrict__ b,
    unsigned char* __restrict__ out){
  const int wave = threadIdx.x >> 6, lane = threadIdx.x & 63;
  const int row = blockIdx.x*4 + wave;
  const float* xr = x + (size_t)row*EDIM;
  float v[6]; float s=0.f, sq=0.f;
  #pragma unroll
  for(int j=0;j<6;j++){ v[j]=xr[j*64+lane]; s+=v[j]; sq+=v[j]*v[j]; }
  #pragma unroll
  for(int m=1;m<64;m<<=1){ s += __shfl_xor(s,m); sq += __shfl_xor(sq,m); }
  const float mean = s*(1.f/384.f);
  const float var  = sq*(1.f/384.f) - mean*mean;
  const float rstd = rsqrtf(var + 1e-5f);
  unsigned char* orow = out + (size_t)row*EDIM;
  #pragma unroll
  for(int j=0;j<6;j++){
    int e = j*64+lane;
    orow[e] = f2fp8((v[j]-mean)*rstd*g[e] + b[e]);
  }
}

// ---------------- fp8 MFMA GEMM, 128x128, BK=64, dbuf, XOR-swizzled -----------
// MODE 0: write fp8 via LDS repack + dwordx4 (bias opt, RELU opt).
// MODE 1: fp32 residual accumulate: x += val + bias.
// MODE 2: embed epilogue (val/256 + bp + stat + pe + fire_emb) -> fp32 x.
template<int MODE, bool RELU>
__global__ __launch_bounds__(256) void gemm_k(const unsigned char* __restrict__ A,
    const unsigned char* __restrict__ Wt, const float* __restrict__ bias,
    unsigned char* __restrict__ outb, float* __restrict__ xout,
    const int* __restrict__ fire, const float* __restrict__ pe,
    const float* __restrict__ stat_emb, const int* __restrict__ stn_p,
    const float* __restrict__ fire_emb, int M, int K){
  __shared__ __align__(16) unsigned char As[2][128*64];   // 2x8 KB
  __shared__ __align__(16) unsigned char Bs[2][128*64];   // 2x8 KB
  const int tid  = threadIdx.x;
  const int m0   = blockIdx.x * 128;
  const int n0   = blockIdx.y * 128;
  const int wave = tid >> 6, lane = tid & 63;
  const int wr = wave >> 1, wc = wave & 1;
  const int lrow = lane & 15, quad = lane >> 4;
  const int lsw = (lrow & 3) ^ ((lrow >> 2) & 3);
  floatx4 acc[4][4];
  #pragma unroll
  for(int i=0;i<4;i++)
    #pragma unroll
    for(int j=0;j<4;j++) acc[i][j] = (floatx4){0.f,0.f,0.f,0.f};

  const int S = K >> 6;
  auto stage = [&](int s, int bi){
    const int kk = s*64;
    #pragma unroll
    for(int p=0;p<2;p++){
      int i = tid + p*256;
      int r = i >> 2, jp = i & 3;
      int jl = jp ^ (r & 3) ^ ((r >> 2) & 3);
      gld_lds16(&A [(size_t)(n0+r)*K + kk + jl*16], &As[bi][i*16]);
      gld_lds16(&Wt[(size_t)(m0+r)*K + kk + jl*16], &Bs[bi][i*16]);
    }
  };
  stage(0, 0);
  for(int s=0; s<S; s++){
    const int bi = s & 1;
    __syncthreads();
    if(s+1 < S) stage(s+1, bi^1);
    #pragma unroll
    for(int ks=0; ks<2; ks++){
      const int joff = (((ks*2 + (quad>>1)) ^ lsw) << 4) + (quad & 1)*8;
      long af[4], bfv[4];
      #pragma unroll
      for(int ti=0;ti<4;ti++)
        af[ti]  = *(const long*)(&As[bi][(wr*64+ti*16+lrow)*64 + joff]);
      #pragma unroll
      for(int tj=0;tj<4;tj++)
        bfv[tj] = *(const long*)(&Bs[bi][(wc*64+tj*16+lrow)*64 + joff]);
      #pragma unroll
      for(int ti=0;ti<4;ti++)
        #pragma unroll
        for(int tj=0;tj<4;tj++)
          acc[ti][tj] = __builtin_amdgcn_mfma_f32_16x16x32_fp8_fp8(af[ti], bfv[tj], acc[ti][tj], 0,0,0);
    }
  }
  if(MODE==0){
    __syncthreads();
    unsigned char* Cs = (unsigned char*)&As[0][0];   // 16 KB == sizeof(As)
    #pragma unroll
    for(int ti=0;ti<4;ti++){
      #pragma unroll
      for(int tj=0;tj<4;tj++){
        const int col = wc*64 + tj*16 + lrow;
        const float bi = bias ? bias[m0+col] : 0.f;
        #pragma unroll
        for(int r=0;r<4;r++){
          const int row = wr*64 + ti*16 + quad*4 + r;
          float val = acc[ti][tj][r] + bi;
          if(RELU) val = fmaxf(val, 0.f);
          Cs[row*128 + col] = f2fp8(val);
        }
      }
    }
    __syncthreads();
    #pragma unroll
    for(int p=0;p<4;p++){
      const int q = tid + p*256;
      const int row = q >> 3, c16 = (q & 7)*16;
      *(uintx4*)(&outb[(size_t)(n0+row)*M + m0 + c16]) =
          *(const uintx4*)(&Cs[row*128 + c16]);
    }
  } else {
    const int stn = (MODE==2) ? stn_p[0] : 0;
    #pragma unroll
    for(int ti=0;ti<4;ti++){
      #pragma unroll
      for(int r=0;r<4;r++){
        int row = n0 + wr*64 + ti*16 + quad*4 + r;
        int fidx = 0, trow = 0;
        if(MODE==2){ fidx = fire[row]; trow = row % TBLK; }
        #pragma unroll
        for(int tj=0;tj<4;tj++){
          int col = m0 + wc*64 + tj*16 + lrow;
          float val = acc[ti][tj][r];
          if(MODE==1){
            xout[(size_t)row*EDIM + col] += val + bias[col];
          } else {
            val = val*(1.f/256.f) + bias[col] + stat_emb[(size_t)stn*EDIM + col]
                + pe[trow*EDIM + col] + fire_emb[(size_t)fidx*EDIM + col];
            xout[(size_t)row*EDIM + col] = val;
          }
        }
      }
    }
  }
}

// ------- full-row GEMM + residual + LayerNorm epilogue (Wo only, K=384) -------
__global__ __launch_bounds__(512, 4) void gemm_row_ln(
    const unsigned char* __restrict__ A, const unsigned char* __restrict__ Wt,
    const float* __restrict__ bias, float* __restrict__ x,
    const float* __restrict__ g, const float* __restrict__ b,
    unsigned char* __restrict__ h, int K, int writeH){
  __shared__ __align__(16) unsigned char As[2][64*32];     // 2x2 KB
  __shared__ __align__(16) unsigned char Bs[2][384*32];    // 2x12 KB
  const int tid = threadIdx.x;
  const int n0 = blockIdx.x * 64;
  const int wave = tid >> 6, lane = tid & 63;
  const int rw = wave >> 1, cw = wave & 1;
  const int lrow = lane & 15, quad = lane >> 4;
  const int xsw = ((lane >> 2) & 1) << 4;
  floatx4 acc[12];
  #pragma unroll
  for(int j=0;j<12;j++) acc[j] = (floatx4){0.f,0.f,0.f,0.f};

  const int S = K >> 5;
  auto stage = [&](int s, int bi){
    const int kk = s*32;
    if(tid < 128){
      int r = tid >> 1, c = (((tid&1) ^ ((tid>>3)&1))) * 16;
      gld_lds16(&A[(size_t)(n0+r)*K + kk + c], &As[bi][tid*16]);
    }
    {
      int i = tid;
      int r = i >> 1, c = (((i&1) ^ ((i>>3)&1))) * 16;
      gld_lds16(&Wt[(size_t)r*K + kk + c], &Bs[bi][i*16]);
    }
    if(tid < 256){
      int i = tid + 512;
      int r = i >> 1, c = (((i&1) ^ ((i>>3)&1))) * 16;
      gld_lds16(&Wt[(size_t)r*K + kk + c], &Bs[bi][i*16]);
    }
  };
  stage(0, 0);
  for(int s=0; s<S; s++){
    const int bi = s & 1;
    __syncthreads();
    if(s+1 < S) stage(s+1, bi^1);
    long af = *(const long*)(&As[bi][(rw*16+lrow)*32 + ((quad*8) ^ xsw)]);
    long bfv[12];
    #pragma unroll
    for(int tj=0;tj<12;tj++)
      bfv[tj] = *(const long*)(&Bs[bi][(cw*192+tj*16+lrow)*32 + ((quad*8) ^ xsw)]);
    #pragma unroll
    for(int tj=0;tj<12;tj++)
      acc[tj] = __builtin_amdgcn_mfma_f32_16x16x32_fp8_fp8(af, bfv[tj], acc[tj], 0,0,0);
  }
  __syncthreads();
  float* part = (float*)&As[0][0];
  {
    float ps[4] = {0.f,0.f,0.f,0.f}, pq[4] = {0.f,0.f,0.f,0.f};
    #pragma unroll
    for(int tj=0;tj<12;tj++){
      const int col = cw*192 + tj*16 + lrow;
      const float bi = bias[col];
      #pragma unroll
      for(int r=0;r<4;r++){
        const int row = n0 + rw*16 + quad*4 + r;
        float v = acc[tj][r] + bi + x[(size_t)row*EDIM + col];
        acc[tj][r] = v;
        ps[r] += v; pq[r] += v*v;
      }
    }
    #pragma unroll
    for(int r=0;r<4;r++){
      #pragma unroll
      for(int m=1;m<16;m<<=1){ ps[r] += __shfl_xor(ps[r],m); pq[r] += __shfl_xor(pq[r],m); }
    }
    if(lrow == 0){
      #pragma unroll
      for(int r=0;r<4;r++){
        const int rl = rw*16 + quad*4 + r;
        part[rl*2 + cw]       = ps[r];
        part[128 + rl*2 + cw] = pq[r];
      }
    }
  }
  __syncthreads();
  #pragma unroll
  for(int r=0;r<4;r++){
    const int rl = rw*16 + quad*4 + r;
    const int row = n0 + rl;
    const float s = part[rl*2+0] + part[rl*2+1];
    const float q = part[128+rl*2+0] + part[128+rl*2+1];
    const float mean = s*(1.f/384.f);
    const float var  = q*(1.f/384.f) - mean*mean;
    const float rstd = rsqrtf(var + 1e-5f);
    #pragma unroll
    for(int tj=0;tj<12;tj++){
      const int col = cw*192 + tj*16 + lrow;
      const float v = acc[tj][r];
      x[(size_t)row*EDIM + col] = v;
      if(writeH)
        h[(size_t)row*EDIM + col] = f2fp8((v-mean)*rstd*g[col] + b[col]);
    }
  }
}

// ---------------- MFMA attention: one wave per (b,h), no cross-wave sync ------
// Per-wave LDS: PT bf16 [48][72] (P, A-layout) + VT bf16 [64][72] (V^T,
// B-layout; reused as O fp8 [48][80] after last MFMA). 15.75 KB/wave.
__global__ __launch_bounds__(256) void attn_kernel(const unsigned char* __restrict__ qkv,
    unsigned char* __restrict__ o){
  __shared__ __align__(16) unsigned short lds[4*8064];   // 63 KB
  const int wave = threadIdx.x >> 6, lane = threadIdx.x & 63;
  const int bh = blockIdx.x*4 + wave;
  const int b = bh / NHEAD, h = bh % NHEAD;
  const int lrow = lane & 15, quad = lane >> 4;
  unsigned short* PT = lds + wave*8064;    // [48][72]
  unsigned short* VT = PT + 48*72;         // [64][72]
  const size_t base = (size_t)b*TBLK*QKVSTR + h*DHEAD;
  const unsigned char* qp = qkv + base;
  const unsigned char* kp = qkv + base + 384;
  const unsigned char* vp = qkv + base + 768;

  // stage V^T bf16 (lane = d), zero s in [36,64)
  for(int s=0;s<64;s++){
    float v = (s < TBLK) ? fp82f(vp[(size_t)s*QKVSTR + lane]) : 0.f;
    VT[lane*72 + s] = f2bf(v);
  }
  // zero PT cols 48..63 for all 48 rows
  #pragma unroll
  for(int i=lane;i<96;i+=64){
    int row = i >> 1, c = (i & 1)*8;
    *(short8*)(&PT[row*72 + 48 + c]) = (short8){0,0,0,0,0,0,0,0};
  }

  // QK^T: 3x3 tiles, fp8 MFMA, frags direct from global
  floatx4 accs[3][3];
  #pragma unroll
  for(int i=0;i<3;i++)
    #pragma unroll
    for(int j=0;j<3;j++) accs[i][j] = (floatx4){0.f,0.f,0.f,0.f};
  #pragma unroll
  for(int ks=0;ks<2;ks++){
    long aq[3], bk[3];
    #pragma unroll
    for(int ti=0;ti<3;ti++)
      aq[ti] = *(const long*)(qp + (size_t)(ti*16+lrow)*QKVSTR + ks*32 + quad*8);
    #pragma unroll
    for(int tj=0;tj<3;tj++)
      bk[tj] = *(const long*)(kp + (size_t)(tj*16+lrow)*QKVSTR + ks*32 + quad*8);
    #pragma unroll
    for(int ti=0;ti<3;ti++)
      #pragma unroll
      for(int tj=0;tj<3;tj++)
        accs[ti][tj] = __builtin_amdgcn_mfma_f32_16x16x32_fp8_fp8(aq[ti], bk[tj], accs[ti][tj], 0,0,0);
  }

  // softmax in C-layout (row t = quad-local), write P bf16 to PT
  const float scale = 0.125f;
  #pragma unroll
  for(int ti=0;ti<3;ti++){
    #pragma unroll
    for(int r=0;r<4;r++){
      const int t = ti*16 + quad*4 + r;
      float pv[3]; float mx = -INFINITY;
      #pragma unroll
      for(int tj=0;tj<3;tj++){
        const int s = tj*16 + lrow;
        pv[tj] = (s <= t) ? accs[ti][tj][r]*scale : -INFINITY;
        mx = fmaxf(mx, pv[tj]);
      }
      #pragma unroll
      for(int m=1;m<16;m<<=1) mx = fmaxf(mx, __shfl_xor(mx, m));
      float sum = 0.f;
      #pragma unroll
      for(int tj=0;tj<3;tj++){ pv[tj] = __expf(pv[tj]-mx); sum += pv[tj]; }
      #pragma unroll
      for(int m=1;m<16;m<<=1) sum += __shfl_xor(sum, m);
      const float rs = 1.f/sum;
      #pragma unroll
      for(int tj=0;tj<3;tj++)
        PT[t*72 + tj*16 + lrow] = f2bf(pv[tj]*rs);
    }
  }

  // PV: O[48][64] = P[48][64] @ V[64][64]^T^T via bf16 MFMA (K=s, 2 steps)
  floatx4 acco[3][4];
  #pragma unroll
  for(int i=0;i<3;i++)
    #pragma unroll
    for(int j=0;j<4;j++) acco[i][j] = (floatx4){0.f,0.f,0.f,0.f};
  #pragma unroll
  for(int ks=0;ks<2;ks++){
    short8 ap[3], bv[4];
    #pragma unroll
    for(int ti=0;ti<3;ti++)
      ap[ti] = *(const short8*)(&PT[(ti*16+lrow)*72 + ks*32 + quad*8]);
    #pragma unroll
    for(int td=0;td<4;td++)
      bv[td] = *(const short8*)(&VT[(td*16+lrow)*72 + ks*32 + quad*8]);
    #pragma unroll
    for(int ti=0;ti<3;ti++)
      #pragma unroll
      for(int td=0;td<4;td++)
        acco[ti][td] = __builtin_amdgcn_mfma_f32_16x16x32_bf16(ap[ti], bv[td], acco[ti][td], 0,0,0);
  }

  // O -> LDS fp8 (reuse VT region; all MFMA reads done), then coalesced stores
  unsigned char* OB = (unsigned char*)VT;    // [48][80]
  #pragma unroll
  for(int ti=0;ti<3;ti++)
    #pragma unroll
    for(int td=0;td<4;td++)
      #pragma unroll
      for(int r=0;r<4;r++)
        OB[(ti*16+quad*4+r)*80 + td*16 + lrow] = f2fp8(acco[ti][td][r]);
  for(int i=lane;i<TBLK*4;i+=64){
    const int row = i >> 2, c16 = (i & 3)*16;
    *(uintx4*)(&o[((size_t)b*TBLK+row)*EDIM + h*DHEAD + c16]) =
        *(const uintx4*)(&OB[row*80 + c16]);
  }
}

// ---------------- head: LNf + sigmoid(x@Wh+bh)*500 + per-block partials -------
__global__ __launch_bounds__(256) void head_kernel(const float* __restrict__ x,
    const float* __restrict__ g, const float* __restrict__ b,
    const float* __restrict__ Wh, const float* __restrict__ bh,
    const int* __restrict__ targets, float* __restrict__ out,
    float* __restrict__ partials){
  const int wave = threadIdx.x >> 6, lane = threadIdx.x & 63;
  const int row = blockIdx.x*4 + wave;
  const float* xr = x + (size_t)row*EDIM;
  float v[6]; float s=0.f, sq=0.f;
  #pragma unroll
  for(int j=0;j<6;j++){ v[j]=xr[j*64+lane]; s+=v[j]; sq+=v[j]*v[j]; }
  #pragma unroll
  for(int m=1;m<64;m<<=1){ s += __shfl_xor(s,m); sq += __shfl_xor(sq,m); }
  const float mean = s*(1.f/384.f);
  const float var  = sq*(1.f/384.f) - mean*mean;
  const float rstd = rsqrtf(var + 1e-5f);
  float dot = 0.f;
  #pragma unroll
  for(int j=0;j<6;j++){
    int e = j*64+lane;
    float hh = (v[j]-mean)*rstd*g[e] + b[e];
    dot = fmaf(hh, Wh[e], dot);
  }
  #pragma unroll
  for(int m=1;m<64;m<<=1) dot += __shfl_xor(dot,m);
  __shared__ float part[4][4];
  if(lane == 0){
    float logit = 1.f/(1.f + __expf(-(dot + bh[0])));
    float den = logit * 500.f;
    out[row] = den;
    float tgt = (float)targets[(size_t)row*2];
    float nt  = tgt * (1.f/500.f);
    part[wave][0] = (logit-nt)*(logit-nt);
    part[wave][1] = (tgt-den)*(tgt-den);
    part[wave][2] = tgt;
    part[wave][3] = tgt*tgt;
  }
  __syncthreads();
  if(threadIdx.x < 4){
    float t0 = part[0][threadIdx.x] + part[1][threadIdx.x]
             + part[2][threadIdx.x] + part[3][threadIdx.x];
    partials[(size_t)threadIdx.x*NHBLK + blockIdx.x] = t0;
  }
}

// ---------------- final reduction: partials[4][NHBLK] -> mse, r2 --------------
__global__ __launch_bounds__(1024) void finalize_reduce(
    const float* __restrict__ partials, float* __restrict__ out){
  __shared__ float red[16];
  const int tid = threadIdx.x;
  const int c = tid >> 8, j = tid & 255;
  float s = 0.f;
  for(int i = j; i < NHBLK; i += 256) s += partials[(size_t)c*NHBLK + i];
  #pragma unroll
  for(int m=1;m<64;m<<=1) s += __shfl_xor(s,m);
  if((tid & 63) == 0) red[tid >> 6] = s;
  __syncthreads();
  if(tid == 0){
    float a0 = red[0]+red[1]+red[2]+red[3];
    float a1 = red[4]+red[5]+red[6]+red[7];
    float a2 = red[8]+red[9]+red[10]+red[11];
    float a3 = red[12]+red[13]+red[14]+red[15];
    const float n = (float)NTOK;
    out[NTOK]   = a0 / n;
    float denom = a3 - a2*a2/n;
    out[NTOK+1] = 1.f - a1/denom;
  }
}

// =============================================================================
extern "C" void kernel_launch(void* const* d_in, const int* in_sizes, int n_in,
                              void* d_out, int out_size, void* d_ws, size_t ws_size,
                              hipStream_t stream){
  (void)in_sizes; (void)n_in; (void)out_size; (void)ws_size;
  const int*   idx      = (const int*)  d_in[0];
  const int*   targets  = (const int*)  d_in[1];
  const int*   stn_ix   = (const int*)  d_in[3];
  const float* Wp       = (const float*)d_in[4];
  const float* bp       = (const float*)d_in[5];
  const float* stat_emb = (const float*)d_in[6];
  const float* fire_emb = (const float*)d_in[7];
  const float* ln1_g    = (const float*)d_in[8];
  const float* ln1_b    = (const float*)d_in[9];
  const float* Wq       = (const float*)d_in[10];
  const float* Wk       = (const float*)d_in[11];
  const float* Wv       = (const float*)d_in[12];
  const float* Wo       = (const float*)d_in[13];
  const float* bo       = (const float*)d_in[14];
  const float* ln2_g    = (const float*)d_in[15];
  const float* ln2_b    = (const float*)d_in[16];
  const float* W1       = (const float*)d_in[17];
  const float* b1       = (const float*)d_in[18];
  const float* W2       = (const float*)d_in[19];
  const float* b2       = (const float*)d_in[20];
  const float* lnf_g    = (const float*)d_in[21];
  const float* lnf_b    = (const float*)d_in[22];
  const float* Wh       = (const float*)d_in[23];
  const float* bh       = (const float*)d_in[24];
  float* out = (float*)d_out;

  char* ws = (char*)d_ws;
  float*         x      = (float*)        (ws + 0);
  unsigned char* h      = (unsigned char*)(ws + 56623104);
  unsigned char* qkv    = (unsigned char*)(ws + 84934656);
  unsigned char* obuf   = (unsigned char*)(ws + 169869312);
  unsigned char* ffn    = qkv;
  unsigned char* pm     = (unsigned char*)(ws + 169869312);  // aliases obuf
  int*           fire   = (int*)          (ws + 186384384);
  unsigned char* wp_t   = (unsigned char*)(ws + 186531840);
  float*         pe     = (float*)        (ws + 186703872);
  float*         partials = (float*)      (ws + 169869312);  // aliases obuf
  unsigned char* wqkv_t = (unsigned char*)(ws + 198180864);
  unsigned char* wo_t   = (unsigned char*)(ws + 203489280);
  unsigned char* w1_t   = (unsigned char*)(ws + 205258752);
  unsigned char* w2_t   = (unsigned char*)(ws + 212336640);

  const dim3 tb(32,8);
  wt_transpose<<<dim3(12,12,6), tb, 0, stream>>>(Wq, wqkv_t,          384,  384, 442368);
  wt_transpose<<<dim3(12,12,6), tb, 0, stream>>>(Wk, wqkv_t + 147456, 384,  384, 442368);
  wt_transpose<<<dim3(12,12,6), tb, 0, stream>>>(Wv, wqkv_t + 294912, 384,  384, 442368);
  wt_transpose<<<dim3(12,12,6), tb, 0, stream>>>(Wo, wo_t,            384,  384, 147456);
  wt_transpose<<<dim3(48,12,6), tb, 0, stream>>>(W1, w1_t,            384, 1536, 589824);
  wt_transpose<<<dim3(12,48,6), tb, 0, stream>>>(W2, w2_t,           1536,  384, 589824);
  wp_transpose<<<384, 256, 0, stream>>>(Wp, wp_t);
  pe_kernel<<<TBLK, 384, 0, stream>>>(pe);
  prep_pm<<<(NTOK*KPM + 255)/256, 256, 0, stream>>>(idx, pm);
  prep_fire<<<(NTOK + 255)/256, 256, 0, stream>>>(idx, stn_ix, fire);

  // embed GEMM: x = (pm*256) @ wp_t^T / 256 + (bp + stat + pe + fire_emb)
  gemm_k<2,false><<<dim3(3,288), 256, 0, stream>>>(pm, wp_t, bp, nullptr, x,
      fire, pe, stat_emb, stn_ix, fire_emb, 384, KPM);

  // layer-0 ln1
  ln_act<<<NTOK/4, 256, 0, stream>>>(x, ln1_g, ln1_b, h);

  const dim3 gQKV(9, 288);
  const dim3 gE(3, 288);
  const dim3 gF(12, 288);
  for(int l=0; l<NLAYER; l++){
    gemm_k<0,false><<<gQKV, 256, 0, stream>>>(h, wqkv_t + (size_t)l*442368,
        nullptr, qkv, nullptr, nullptr, nullptr, nullptr, nullptr, nullptr, 1152, 384);
    attn_kernel<<<BSZ*NHEAD/4, 256, 0, stream>>>(qkv, obuf);
    // x += obuf@Wo + bo;  h = LN2(x)   (fused; K=384)
    gemm_row_ln<<<NTOK/64, 512, 0, stream>>>(obuf, wo_t + (size_t)l*147456,
        bo + l*EDIM, x, ln2_g + l*EDIM, ln2_b + l*EDIM, h, 384, 1);
    gemm_k<0,true><<<gF, 256, 0, stream>>>(h, w1_t + (size_t)l*589824,
        b1 + l*1536, ffn, nullptr, nullptr, nullptr, nullptr, nullptr, nullptr, 1536, 384);
    // x += ffn@W2 + b2   (fp8, fp32 residual epilogue)
    gemm_k<1,false><<<gE, 256, 0, stream>>>(ffn, w2_t + (size_t)l*589824,
        b2 + l*EDIM, nullptr, x, nullptr, nullptr, nullptr, nullptr, nullptr, 384, 1536);
    // h = LN1[l+1](x)  (skip on last layer; head does LNf itself)
    if(l < NLAYER-1)
      ln_act<<<NTOK/4, 256, 0, stream>>>(x, ln1_g + (l+1)*EDIM, ln1_b + (l+1)*EDIM, h);
  }

  head_kernel<<<NHBLK, 256, 0, stream>>>(x, lnf_g, lnf_b, Wh, bh, targets, out, partials);
  finalize_reduce<<<1, 1024, 0, stream>>>(partials, out);
}

// Round 11
// 1813.505 us; speedup vs baseline: 2.5477x; 1.0423x over previous
//
#include <hip/hip_runtime.h>
#include <hip/hip_fp8.h>
#include <stdint.h>

// PM25 transformer forward, MI355X/gfx950. Round 11:
//   - gemm_k: XCD-aware tile remap. lin = bx + ncol*by; xcd = lin&7;
//     per = lin>>3; col = per%ncol; row = (per/ncol)*8 + xcd.
//     Each row-tile owned by ONE XCD -> A-tile fetched once into that XCD's
//     private L2 (49 KB) and reused ncol times. R10 evidence: W1 FETCH=115 MB
//     vs ideal ~15 MB = 8 XCDs each refetching A (col-fastest dispatch spread
//     same-A blocks across non-coherent L2s).
//   - everything else bit-identical to R10.

#define EDIM   384
#define NHEAD  6
#define DHEAD  64
#define NLAYER 6
#define TBLK   36
#define SNUM   210
#define BSZ    1024
#define NTOK   (BSZ*TBLK)
#define QKVSTR 1152
#define KPM    256
#define NHBLK  (NTOK/4)

typedef __attribute__((ext_vector_type(4))) float floatx4;
typedef __attribute__((ext_vector_type(4))) unsigned int uintx4;
typedef __attribute__((ext_vector_type(8))) short short8;

static __device__ __forceinline__ unsigned char f2fp8(float f){
  __hip_fp8_e4m3 t(f); return t.__x;
}
static __device__ __forceinline__ float fp82f(unsigned char u){
  __hip_fp8_e4m3 t; t.__x = u; return (float)t;
}
static __device__ __forceinline__ unsigned short f2bf(float f){
  union { float fv; unsigned int u; } v; v.fv = f;
  unsigned int r = v.u + 0x7FFFu + ((v.u >> 16) & 1u);
  return (unsigned short)(r >> 16);
}
static __device__ __forceinline__ void gld_lds16(const void* g, void* l){
  __builtin_amdgcn_global_load_lds(
      (const __attribute__((address_space(1))) void*)g,
      (__attribute__((address_space(3))) void*)l, 16, 0, 0);
}

// ---------------- weight transpose + fp8 cast: out[m][k] = fp8(in[k][m]) ------
__global__ __launch_bounds__(256) void wt_transpose(const float* __restrict__ in,
    unsigned char* __restrict__ out, int K, int M, long outStride){
  __shared__ float tile[32][33];
  const int mat = blockIdx.z;
  const float* src = in + (size_t)mat*K*M;
  unsigned char* dst = out + (size_t)mat*outStride;
  const int m0 = blockIdx.x*32, k0 = blockIdx.y*32;
  const int tx = threadIdx.x, ty = threadIdx.y;
  for(int i=ty;i<32;i+=8) tile[i][tx] = src[(size_t)(k0+i)*M + m0+tx];
  __syncthreads();
  for(int i=ty;i<32;i+=8) dst[(size_t)(m0+i)*K + k0+tx] = f2fp8(tile[tx][i]);
}

// Wp [210,384] -> wp_t fp8 [384,256] (K zero-padded 210->256)
__global__ __launch_bounds__(256) void wp_transpose(const float* __restrict__ Wp,
    unsigned char* __restrict__ wp_t){
  const int m = blockIdx.x, k = threadIdx.x;
  wp_t[(size_t)m*KPM + k] = (k < SNUM) ? f2fp8(Wp[(size_t)k*EDIM + m]) : 0;
}

// pm fp8 [36864,256]: pm[row][s] = fp8(idx*256/500); x256 undone in epilogue
__global__ __launch_bounds__(256) void prep_pm(const int* __restrict__ idx,
    unsigned char* __restrict__ pm){
  const long i = (long)blockIdx.x*256 + threadIdx.x;
  if(i >= (long)NTOK*KPM) return;
  const int row = i / KPM, s = i - (long)row*KPM;
  float v = 0.f;
  if(s < SNUM) v = (float)idx[((size_t)row*SNUM + s)*2] * (256.f/500.f);
  pm[i] = f2fp8(v);
}

__global__ __launch_bounds__(256) void prep_fire(const int* __restrict__ idx,
    const int* __restrict__ stn_p, int* __restrict__ fire){
  const int row = blockIdx.x*256 + threadIdx.x;
  if(row < NTOK) fire[row] = idx[((size_t)row*SNUM + stn_p[0])*2 + 1];
}

__global__ __launch_bounds__(384) void pe_kernel(float* __restrict__ pe){
  const int t = blockIdx.x, e = threadIdx.x;
  const float freq = __expf(-(float)(2*(e>>1)) * (9.210340371976184f/384.f));
  const float ang = (float)t * freq;
  pe[t*EDIM + e] = (e & 1) ? __cosf(ang) : __sinf(ang);
}

// ---------------- layernorm fp32 -> fp8, one wave per row --------------------
__global__ __launch_bounds__(256) void ln_act(const float* __restrict__ x,
    const float* __restrict__ g, const float* __restrict__ b,
    unsigned char* __restrict__ out){
  const int wave = threadIdx.x >> 6, lane = threadIdx.x & 63;
  const int row = blockIdx.x*4 + wave;
  const float* xr = x + (size_t)row*EDIM;
  float v[6]; float s=0.f, sq=0.f;
  #pragma unroll
  for(int j=0;j<6;j++){ v[j]=xr[j*64+lane]; s+=v[j]; sq+=v[j]*v[j]; }
  #pragma unroll
  for(int m=1;m<64;m<<=1){ s += __shfl_xor(s,m); sq += __shfl_xor(sq,m); }
  const float mean = s*(1.f/384.f);
  const float var  = sq*(1.f/384.f) - mean*mean;
  const float rstd = rsqrtf(var + 1e-5f);
  unsigned char* orow = out + (size_t)row*EDIM;
  #pragma unroll
  for(int j=0;j<6;j++){
    int e = j*64+lane;
    orow[e] = f2fp8((v[j]-mean)*rstd*g[e] + b[e]);
  }
}

// ---------------- fp8 MFMA GEMM, 128x128, BK=64, dbuf, XCD-remapped -----------
// MODE 0: write fp8 via LDS repack + dwordx4 (bias opt, RELU opt).
// MODE 1: fp32 residual accumulate: x += val + bias.
// MODE 2: embed epilogue (val/256 + bp + stat + pe + fire_emb) -> fp32 x.
template<int MODE, bool RELU>
__global__ __launch_bounds__(256) void gemm_k(const unsigned char* __restrict__ A,
    const unsigned char* __restrict__ Wt, const float* __restrict__ bias,
    unsigned char* __restrict__ outb, float* __restrict__ xout,
    const int* __restrict__ fire, const float* __restrict__ pe,
    const float* __restrict__ stat_emb, const int* __restrict__ stn_p,
    const float* __restrict__ fire_emb, int M, int K){
  __shared__ __align__(16) unsigned char As[2][128*64];   // 2x8 KB
  __shared__ __align__(16) unsigned char Bs[2][128*64];   // 2x8 KB
  const int tid  = threadIdx.x;
  // XCD-aware remap: same-row col-tiles land consecutively on one XCD so the
  // A-tile is fetched once into that XCD's private L2 (R10: FETCH 115 MB->~A).
  const int ncol = gridDim.x;
  const int lin  = blockIdx.x + ncol*blockIdx.y;
  const int xcd  = lin & 7;
  const int per  = lin >> 3;
  const int m0   = (per % ncol) * 128;
  const int n0   = ((per / ncol)*8 + xcd) * 128;
  const int wave = tid >> 6, lane = tid & 63;
  const int wr = wave >> 1, wc = wave & 1;
  const int lrow = lane & 15, quad = lane >> 4;
  const int lsw = (lrow & 3) ^ ((lrow >> 2) & 3);
  floatx4 acc[4][4];
  #pragma unroll
  for(int i=0;i<4;i++)
    #pragma unroll
    for(int j=0;j<4;j++) acc[i][j] = (floatx4){0.f,0.f,0.f,0.f};

  const int S = K >> 6;
  auto stage = [&](int s, int bi){
    const int kk = s*64;
    #pragma unroll
    for(int p=0;p<2;p++){
      int i = tid + p*256;
      int r = i >> 2, jp = i & 3;
      int jl = jp ^ (r & 3) ^ ((r >> 2) & 3);
      gld_lds16(&A [(size_t)(n0+r)*K + kk + jl*16], &As[bi][i*16]);
      gld_lds16(&Wt[(size_t)(m0+r)*K + kk + jl*16], &Bs[bi][i*16]);
    }
  };
  stage(0, 0);
  for(int s=0; s<S; s++){
    const int bi = s & 1;
    __syncthreads();
    if(s+1 < S) stage(s+1, bi^1);
    #pragma unroll
    for(int ks=0; ks<2; ks++){
      const int joff = (((ks*2 + (quad>>1)) ^ lsw) << 4) + (quad & 1)*8;
      long af[4], bfv[4];
      #pragma unroll
      for(int ti=0;ti<4;ti++)
        af[ti]  = *(const long*)(&As[bi][(wr*64+ti*16+lrow)*64 + joff]);
      #pragma unroll
      for(int tj=0;tj<4;tj++)
        bfv[tj] = *(const long*)(&Bs[bi][(wc*64+tj*16+lrow)*64 + joff]);
      #pragma unroll
      for(int ti=0;ti<4;ti++)
        #pragma unroll
        for(int tj=0;tj<4;tj++)
          acc[ti][tj] = __builtin_amdgcn_mfma_f32_16x16x32_fp8_fp8(af[ti], bfv[tj], acc[ti][tj], 0,0,0);
    }
  }
  if(MODE==0){
    __syncthreads();
    unsigned char* Cs = (unsigned char*)&As[0][0];   // 16 KB == sizeof(As)
    #pragma unroll
    for(int ti=0;ti<4;ti++){
      #pragma unroll
      for(int tj=0;tj<4;tj++){
        const int col = wc*64 + tj*16 + lrow;
        const float bi = bias ? bias[m0+col] : 0.f;
        #pragma unroll
        for(int r=0;r<4;r++){
          const int row = wr*64 + ti*16 + quad*4 + r;
          float val = acc[ti][tj][r] + bi;
          if(RELU) val = fmaxf(val, 0.f);
          Cs[row*128 + col] = f2fp8(val);
        }
      }
    }
    __syncthreads();
    #pragma unroll
    for(int p=0;p<4;p++){
      const int q = tid + p*256;
      const int row = q >> 3, c16 = (q & 7)*16;
      *(uintx4*)(&outb[(size_t)(n0+row)*M + m0 + c16]) =
          *(const uintx4*)(&Cs[row*128 + c16]);
    }
  } else {
    const int stn = (MODE==2) ? stn_p[0] : 0;
    #pragma unroll
    for(int ti=0;ti<4;ti++){
      #pragma unroll
      for(int r=0;r<4;r++){
        int row = n0 + wr*64 + ti*16 + quad*4 + r;
        int fidx = 0, trow = 0;
        if(MODE==2){ fidx = fire[row]; trow = row % TBLK; }
        #pragma unroll
        for(int tj=0;tj<4;tj++){
          int col = m0 + wc*64 + tj*16 + lrow;
          float val = acc[ti][tj][r];
          if(MODE==1){
            xout[(size_t)row*EDIM + col] += val + bias[col];
          } else {
            val = val*(1.f/256.f) + bias[col] + stat_emb[(size_t)stn*EDIM + col]
                + pe[trow*EDIM + col] + fire_emb[(size_t)fidx*EDIM + col];
            xout[(size_t)row*EDIM + col] = val;
          }
        }
      }
    }
  }
}

// ------- full-row GEMM + residual + LayerNorm epilogue (Wo only, K=384) -------
__global__ __launch_bounds__(512, 4) void gemm_row_ln(
    const unsigned char* __restrict__ A, const unsigned char* __restrict__ Wt,
    const float* __restrict__ bias, float* __restrict__ x,
    const float* __restrict__ g, const float* __restrict__ b,
    unsigned char* __restrict__ h, int K, int writeH){
  __shared__ __align__(16) unsigned char As[2][64*32];     // 2x2 KB
  __shared__ __align__(16) unsigned char Bs[2][384*32];    // 2x12 KB
  const int tid = threadIdx.x;
  const int n0 = blockIdx.x * 64;
  const int wave = tid >> 6, lane = tid & 63;
  const int rw = wave >> 1, cw = wave & 1;
  const int lrow = lane & 15, quad = lane >> 4;
  const int xsw = ((lane >> 2) & 1) << 4;
  floatx4 acc[12];
  #pragma unroll
  for(int j=0;j<12;j++) acc[j] = (floatx4){0.f,0.f,0.f,0.f};

  const int S = K >> 5;
  auto stage = [&](int s, int bi){
    const int kk = s*32;
    if(tid < 128){
      int r = tid >> 1, c = (((tid&1) ^ ((tid>>3)&1))) * 16;
      gld_lds16(&A[(size_t)(n0+r)*K + kk + c], &As[bi][tid*16]);
    }
    {
      int i = tid;
      int r = i >> 1, c = (((i&1) ^ ((i>>3)&1))) * 16;
      gld_lds16(&Wt[(size_t)r*K + kk + c], &Bs[bi][i*16]);
    }
    if(tid < 256){
      int i = tid + 512;
      int r = i >> 1, c = (((i&1) ^ ((i>>3)&1))) * 16;
      gld_lds16(&Wt[(size_t)r*K + kk + c], &Bs[bi][i*16]);
    }
  };
  stage(0, 0);
  for(int s=0; s<S; s++){
    const int bi = s & 1;
    __syncthreads();
    if(s+1 < S) stage(s+1, bi^1);
    long af = *(const long*)(&As[bi][(rw*16+lrow)*32 + ((quad*8) ^ xsw)]);
    long bfv[12];
    #pragma unroll
    for(int tj=0;tj<12;tj++)
      bfv[tj] = *(const long*)(&Bs[bi][(cw*192+tj*16+lrow)*32 + ((quad*8) ^ xsw)]);
    #pragma unroll
    for(int tj=0;tj<12;tj++)
      acc[tj] = __builtin_amdgcn_mfma_f32_16x16x32_fp8_fp8(af, bfv[tj], acc[tj], 0,0,0);
  }
  __syncthreads();
  float* part = (float*)&As[0][0];
  {
    float ps[4] = {0.f,0.f,0.f,0.f}, pq[4] = {0.f,0.f,0.f,0.f};
    #pragma unroll
    for(int tj=0;tj<12;tj++){
      const int col = cw*192 + tj*16 + lrow;
      const float bi = bias[col];
      #pragma unroll
      for(int r=0;r<4;r++){
        const int row = n0 + rw*16 + quad*4 + r;
        float v = acc[tj][r] + bi + x[(size_t)row*EDIM + col];
        acc[tj][r] = v;
        ps[r] += v; pq[r] += v*v;
      }
    }
    #pragma unroll
    for(int r=0;r<4;r++){
      #pragma unroll
      for(int m=1;m<16;m<<=1){ ps[r] += __shfl_xor(ps[r],m); pq[r] += __shfl_xor(pq[r],m); }
    }
    if(lrow == 0){
      #pragma unroll
      for(int r=0;r<4;r++){
        const int rl = rw*16 + quad*4 + r;
        part[rl*2 + cw]       = ps[r];
        part[128 + rl*2 + cw] = pq[r];
      }
    }
  }
  __syncthreads();
  #pragma unroll
  for(int r=0;r<4;r++){
    const int rl = rw*16 + quad*4 + r;
    const int row = n0 + rl;
    const float s = part[rl*2+0] + part[rl*2+1];
    const float q = part[128+rl*2+0] + part[128+rl*2+1];
    const float mean = s*(1.f/384.f);
    const float var  = q*(1.f/384.f) - mean*mean;
    const float rstd = rsqrtf(var + 1e-5f);
    #pragma unroll
    for(int tj=0;tj<12;tj++){
      const int col = cw*192 + tj*16 + lrow;
      const float v = acc[tj][r];
      x[(size_t)row*EDIM + col] = v;
      if(writeH)
        h[(size_t)row*EDIM + col] = f2fp8((v-mean)*rstd*g[col] + b[col]);
    }
  }
}

// ---------------- MFMA attention: one wave per (b,h), no cross-wave sync ------
__global__ __launch_bounds__(256) void attn_kernel(const unsigned char* __restrict__ qkv,
    unsigned char* __restrict__ o){
  __shared__ __align__(16) unsigned short lds[4*8064];   // 63 KB
  const int wave = threadIdx.x >> 6, lane = threadIdx.x & 63;
  const int bh = blockIdx.x*4 + wave;
  const int b = bh / NHEAD, h = bh % NHEAD;
  const int lrow = lane & 15, quad = lane >> 4;
  unsigned short* PT = lds + wave*8064;    // [48][72]
  unsigned short* VT = PT + 48*72;         // [64][72]
  const size_t base = (size_t)b*TBLK*QKVSTR + h*DHEAD;
  const unsigned char* qp = qkv + base;
  const unsigned char* kp = qkv + base + 384;
  const unsigned char* vp = qkv + base + 768;

  for(int s=0;s<64;s++){
    float v = (s < TBLK) ? fp82f(vp[(size_t)s*QKVSTR + lane]) : 0.f;
    VT[lane*72 + s] = f2bf(v);
  }
  #pragma unroll
  for(int i=lane;i<96;i+=64){
    int row = i >> 1, c = (i & 1)*8;
    *(short8*)(&PT[row*72 + 48 + c]) = (short8){0,0,0,0,0,0,0,0};
  }

  floatx4 accs[3][3];
  #pragma unroll
  for(int i=0;i<3;i++)
    #pragma unroll
    for(int j=0;j<3;j++) accs[i][j] = (floatx4){0.f,0.f,0.f,0.f};
  #pragma unroll
  for(int ks=0;ks<2;ks++){
    long aq[3], bk[3];
    #pragma unroll
    for(int ti=0;ti<3;ti++)
      aq[ti] = *(const long*)(qp + (size_t)(ti*16+lrow)*QKVSTR + ks*32 + quad*8);
    #pragma unroll
    for(int tj=0;tj<3;tj++)
      bk[tj] = *(const long*)(kp + (size_t)(tj*16+lrow)*QKVSTR + ks*32 + quad*8);
    #pragma unroll
    for(int ti=0;ti<3;ti++)
      #pragma unroll
      for(int tj=0;tj<3;tj++)
        accs[ti][tj] = __builtin_amdgcn_mfma_f32_16x16x32_fp8_fp8(aq[ti], bk[tj], accs[ti][tj], 0,0,0);
  }

  const float scale = 0.125f;
  #pragma unroll
  for(int ti=0;ti<3;ti++){
    #pragma unroll
    for(int r=0;r<4;r++){
      const int t = ti*16 + quad*4 + r;
      float pv[3]; float mx = -INFINITY;
      #pragma unroll
      for(int tj=0;tj<3;tj++){
        const int s = tj*16 + lrow;
        pv[tj] = (s <= t) ? accs[ti][tj][r]*scale : -INFINITY;
        mx = fmaxf(mx, pv[tj]);
      }
      #pragma unroll
      for(int m=1;m<16;m<<=1) mx = fmaxf(mx, __shfl_xor(mx, m));
      float sum = 0.f;
      #pragma unroll
      for(int tj=0;tj<3;tj++){ pv[tj] = __expf(pv[tj]-mx); sum += pv[tj]; }
      #pragma unroll
      for(int m=1;m<16;m<<=1) sum += __shfl_xor(sum, m);
      const float rs = 1.f/sum;
      #pragma unroll
      for(int tj=0;tj<3;tj++)
        PT[t*72 + tj*16 + lrow] = f2bf(pv[tj]*rs);
    }
  }

  floatx4 acco[3][4];
  #pragma unroll
  for(int i=0;i<3;i++)
    #pragma unroll
    for(int j=0;j<4;j++) acco[i][j] = (floatx4){0.f,0.f,0.f,0.f};
  #pragma unroll
  for(int ks=0;ks<2;ks++){
    short8 ap[3], bv[4];
    #pragma unroll
    for(int ti=0;ti<3;ti++)
      ap[ti] = *(const short8*)(&PT[(ti*16+lrow)*72 + ks*32 + quad*8]);
    #pragma unroll
    for(int td=0;td<4;td++)
      bv[td] = *(const short8*)(&VT[(td*16+lrow)*72 + ks*32 + quad*8]);
    #pragma unroll
    for(int ti=0;ti<3;ti++)
      #pragma unroll
      for(int td=0;td<4;td++)
        acco[ti][td] = __builtin_amdgcn_mfma_f32_16x16x32_bf16(ap[ti], bv[td], acco[ti][td], 0,0,0);
  }

  unsigned char* OB = (unsigned char*)VT;    // [48][80]
  #pragma unroll
  for(int ti=0;ti<3;ti++)
    #pragma unroll
    for(int td=0;td<4;td++)
      #pragma unroll
      for(int r=0;r<4;r++)
        OB[(ti*16+quad*4+r)*80 + td*16 + lrow] = f2fp8(acco[ti][td][r]);
  for(int i=lane;i<TBLK*4;i+=64){
    const int row = i >> 2, c16 = (i & 3)*16;
    *(uintx4*)(&o[((size_t)b*TBLK+row)*EDIM + h*DHEAD + c16]) =
        *(const uintx4*)(&OB[row*80 + c16]);
  }
}

// ---------------- head: LNf + sigmoid(x@Wh+bh)*500 + per-block partials -------
__global__ __launch_bounds__(256) void head_kernel(const float* __restrict__ x,
    const float* __restrict__ g, const float* __restrict__ b,
    const float* __restrict__ Wh, const float* __restrict__ bh,
    const int* __restrict__ targets, float* __restrict__ out,
    float* __restrict__ partials){
  const int wave = threadIdx.x >> 6, lane = threadIdx.x & 63;
  const int row = blockIdx.x*4 + wave;
  const float* xr = x + (size_t)row*EDIM;
  float v[6]; float s=0.f, sq=0.f;
  #pragma unroll
  for(int j=0;j<6;j++){ v[j]=xr[j*64+lane]; s+=v[j]; sq+=v[j]*v[j]; }
  #pragma unroll
  for(int m=1;m<64;m<<=1){ s += __shfl_xor(s,m); sq += __shfl_xor(sq,m); }
  const float mean = s*(1.f/384.f);
  const float var  = sq*(1.f/384.f) - mean*mean;
  const float rstd = rsqrtf(var + 1e-5f);
  float dot = 0.f;
  #pragma unroll
  for(int j=0;j<6;j++){
    int e = j*64+lane;
    float hh = (v[j]-mean)*rstd*g[e] + b[e];
    dot = fmaf(hh, Wh[e], dot);
  }
  #pragma unroll
  for(int m=1;m<64;m<<=1) dot += __shfl_xor(dot,m);
  __shared__ float part[4][4];
  if(lane == 0){
    float logit = 1.f/(1.f + __expf(-(dot + bh[0])));
    float den = logit * 500.f;
    out[row] = den;
    float tgt = (float)targets[(size_t)row*2];
    float nt  = tgt * (1.f/500.f);
    part[wave][0] = (logit-nt)*(logit-nt);
    part[wave][1] = (tgt-den)*(tgt-den);
    part[wave][2] = tgt;
    part[wave][3] = tgt*tgt;
  }
  __syncthreads();
  if(threadIdx.x < 4){
    float t0 = part[0][threadIdx.x] + part[1][threadIdx.x]
             + part[2][threadIdx.x] + part[3][threadIdx.x];
    partials[(size_t)threadIdx.x*NHBLK + blockIdx.x] = t0;
  }
}

// ---------------- final reduction: partials[4][NHBLK] -> mse, r2 --------------
__global__ __launch_bounds__(1024) void finalize_reduce(
    const float* __restrict__ partials, float* __restrict__ out){
  __shared__ float red[16];
  const int tid = threadIdx.x;
  const int c = tid >> 8, j = tid & 255;
  float s = 0.f;
  for(int i = j; i < NHBLK; i += 256) s += partials[(size_t)c*NHBLK + i];
  #pragma unroll
  for(int m=1;m<64;m<<=1) s += __shfl_xor(s,m);
  if((tid & 63) == 0) red[tid >> 6] = s;
  __syncthreads();
  if(tid == 0){
    float a0 = red[0]+red[1]+red[2]+red[3];
    float a1 = red[4]+red[5]+red[6]+red[7];
    float a2 = red[8]+red[9]+red[10]+red[11];
    float a3 = red[12]+red[13]+red[14]+red[15];
    const float n = (float)NTOK;
    out[NTOK]   = a0 / n;
    float denom = a3 - a2*a2/n;
    out[NTOK+1] = 1.f - a1/denom;
  }
}

// =============================================================================
extern "C" void kernel_launch(void* const* d_in, const int* in_sizes, int n_in,
                              void* d_out, int out_size, void* d_ws, size_t ws_size,
                              hipStream_t stream){
  (void)in_sizes; (void)n_in; (void)out_size; (void)ws_size;
  const int*   idx      = (const int*)  d_in[0];
  const int*   targets  = (const int*)  d_in[1];
  const int*   stn_ix   = (const int*)  d_in[3];
  const float* Wp       = (const float*)d_in[4];
  const float* bp       = (const float*)d_in[5];
  const float* stat_emb = (const float*)d_in[6];
  const float* fire_emb = (const float*)d_in[7];
  const float* ln1_g    = (const float*)d_in[8];
  const float* ln1_b    = (const float*)d_in[9];
  const float* Wq       = (const float*)d_in[10];
  const float* Wk       = (const float*)d_in[11];
  const float* Wv       = (const float*)d_in[12];
  const float* Wo       = (const float*)d_in[13];
  const float* bo       = (const float*)d_in[14];
  const float* ln2_g    = (const float*)d_in[15];
  const float* ln2_b    = (const float*)d_in[16];
  const float* W1       = (const float*)d_in[17];
  const float* b1       = (const float*)d_in[18];
  const float* W2       = (const float*)d_in[19];
  const float* b2       = (const float*)d_in[20];
  const float* lnf_g    = (const float*)d_in[21];
  const float* lnf_b    = (const float*)d_in[22];
  const float* Wh       = (const float*)d_in[23];
  const float* bh       = (const float*)d_in[24];
  float* out = (float*)d_out;

  char* ws = (char*)d_ws;
  float*         x      = (float*)        (ws + 0);
  unsigned char* h      = (unsigned char*)(ws + 56623104);
  unsigned char* qkv    = (unsigned char*)(ws + 84934656);
  unsigned char* obuf   = (unsigned char*)(ws + 169869312);
  unsigned char* ffn    = qkv;
  unsigned char* pm     = (unsigned char*)(ws + 169869312);  // aliases obuf
  int*           fire   = (int*)          (ws + 186384384);
  unsigned char* wp_t   = (unsigned char*)(ws + 186531840);
  float*         pe     = (float*)        (ws + 186703872);
  float*         partials = (float*)      (ws + 169869312);  // aliases obuf
  unsigned char* wqkv_t = (unsigned char*)(ws + 198180864);
  unsigned char* wo_t   = (unsigned char*)(ws + 203489280);
  unsigned char* w1_t   = (unsigned char*)(ws + 205258752);
  unsigned char* w2_t   = (unsigned char*)(ws + 212336640);

  const dim3 tb(32,8);
  wt_transpose<<<dim3(12,12,6), tb, 0, stream>>>(Wq, wqkv_t,          384,  384, 442368);
  wt_transpose<<<dim3(12,12,6), tb, 0, stream>>>(Wk, wqkv_t + 147456, 384,  384, 442368);
  wt_transpose<<<dim3(12,12,6), tb, 0, stream>>>(Wv, wqkv_t + 294912, 384,  384, 442368);
  wt_transpose<<<dim3(12,12,6), tb, 0, stream>>>(Wo, wo_t,            384,  384, 147456);
  wt_transpose<<<dim3(48,12,6), tb, 0, stream>>>(W1, w1_t,            384, 1536, 589824);
  wt_transpose<<<dim3(12,48,6), tb, 0, stream>>>(W2, w2_t,           1536,  384, 589824);
  wp_transpose<<<384, 256, 0, stream>>>(Wp, wp_t);
  pe_kernel<<<TBLK, 384, 0, stream>>>(pe);
  prep_pm<<<(NTOK*KPM + 255)/256, 256, 0, stream>>>(idx, pm);
  prep_fire<<<(NTOK + 255)/256, 256, 0, stream>>>(idx, stn_ix, fire);

  // embed GEMM: x = (pm*256) @ wp_t^T / 256 + (bp + stat + pe + fire_emb)
  gemm_k<2,false><<<dim3(3,288), 256, 0, stream>>>(pm, wp_t, bp, nullptr, x,
      fire, pe, stat_emb, stn_ix, fire_emb, 384, KPM);

  // layer-0 ln1
  ln_act<<<NTOK/4, 256, 0, stream>>>(x, ln1_g, ln1_b, h);

  const dim3 gQKV(9, 288);
  const dim3 gE(3, 288);
  const dim3 gF(12, 288);
  for(int l=0; l<NLAYER; l++){
    gemm_k<0,false><<<gQKV, 256, 0, stream>>>(h, wqkv_t + (size_t)l*442368,
        nullptr, qkv, nullptr, nullptr, nullptr, nullptr, nullptr, nullptr, 1152, 384);
    attn_kernel<<<BSZ*NHEAD/4, 256, 0, stream>>>(qkv, obuf);
    // x += obuf@Wo + bo;  h = LN2(x)   (fused; K=384)
    gemm_row_ln<<<NTOK/64, 512, 0, stream>>>(obuf, wo_t + (size_t)l*147456,
        bo + l*EDIM, x, ln2_g + l*EDIM, ln2_b + l*EDIM, h, 384, 1);
    gemm_k<0,true><<<gF, 256, 0, stream>>>(h, w1_t + (size_t)l*589824,
        b1 + l*1536, ffn, nullptr, nullptr, nullptr, nullptr, nullptr, nullptr, 1536, 384);
    // x += ffn@W2 + b2   (fp8, fp32 residual epilogue)
    gemm_k<1,false><<<gE, 256, 0, stream>>>(ffn, w2_t + (size_t)l*589824,
        b2 + l*EDIM, nullptr, x, nullptr, nullptr, nullptr, nullptr, nullptr, 384, 1536);
    // h = LN1[l+1](x)  (skip on last layer; head does LNf itself)
    if(l < NLAYER-1)
      ln_act<<<NTOK/4, 256, 0, stream>>>(x, ln1_g + (l+1)*EDIM, ln1_b + (l+1)*EDIM, h);
  }

  head_kernel<<<NHBLK, 256, 0, stream>>>(x, lnf_g, lnf_b, Wh, bh, targets, out, partials);
  finalize_reduce<<<1, 1024, 0, stream>>>(partials, out);
}